// Round 14
// baseline (342.073 us; speedup 1.0000x reference)
//
#include <hip/hip_runtime.h>
#include <hip/hip_bf16.h>

typedef __bf16 bf16;
typedef __bf16 bf16x4v __attribute__((ext_vector_type(4)));
typedef __bf16 bf16x8v __attribute__((ext_vector_type(8)));
typedef float f32x4 __attribute__((ext_vector_type(4)));
typedef short s16x4 __attribute__((ext_vector_type(4)));

#define DEVINL static __device__ __forceinline__
#define AS1 __attribute__((address_space(1)))
#define AS3 __attribute__((address_space(3)))

DEVINL f32x4 mfma16(bf16x8v a, bf16x8v b, f32x4 c) {
  return __builtin_amdgcn_mfma_f32_16x16x32_bf16(a, b, c, 0, 0, 0);
}

DEVINL f32x4 mfma16x16(bf16x4v a, bf16x4v b, f32x4 c) {
#if __has_builtin(__builtin_amdgcn_mfma_f32_16x16x16bf16_1k)
  return __builtin_amdgcn_mfma_f32_16x16x16bf16_1k(
      __builtin_bit_cast(s16x4, a), __builtin_bit_cast(s16x4, b), c, 0, 0, 0);
#else
  f32x4 d;
  asm("v_mfma_f32_16x16x16_bf16 %0, %1, %2, %3"
      : "=v"(d) : "v"(a), "v"(b), "v"(c));
  return d;
#endif
}

// ---------------- style projections: s = style @ w_ada + b_ada (f32) --------
__global__ __launch_bounds__(256) void k_style(
    const float* __restrict__ style,
    const float* __restrict__ wa1, const float* __restrict__ ba1,
    const float* __restrict__ wa2, const float* __restrict__ ba2,
    float* __restrict__ s1, float* __restrict__ s2) {
  int bid = blockIdx.x;
  int ng = bid & 31, b = (bid >> 5) & 15, which = bid >> 9;
  int tid = threadIdx.x;
  int nl = tid & 15, kg = tid >> 4;
  int n = ng * 16 + nl;
  const float* wa = which ? wa2 : wa1;
  const float* ba = which ? ba2 : ba1;
  const float* srow = style + b * 512;
  float acc = 0.f;
  #pragma unroll 8
  for (int kk = 0; kk < 32; ++kk) {
    int k = kg + kk * 16;
    acc += srow[k] * wa[k * 512 + n];
  }
  acc += __shfl_xor(acc, 16);
  acc += __shfl_xor(acc, 32);
  __shared__ float red[4][16];
  int l = tid & 63, w = tid >> 6;
  if (l < 16) red[w][nl] = acc;
  __syncthreads();
  if (tid < 16) {
    float S = red[0][tid] + red[1][tid] + red[2][tid] + red[3][tid]
            + ba[ng * 16 + tid];
    (which ? s2 : s1)[b * 512 + ng * 16 + tid] = S;
  }
}

// ---------------- stats pass 1: per (b, row-chunk) partial sum/sumsq --------
template<int F32>
__global__ __launch_bounds__(256) void k_stats_part(
    const void* __restrict__ xv, float* __restrict__ psum,
    float* __restrict__ psq) {
  int rc = blockIdx.x, b = blockIdx.y;
  int c = threadIdx.x;
  size_t base = (size_t)b * 4096 * 256 + (size_t)rc * 256 * 256 + c;
  float sm = 0.f, q = 0.f;
  #pragma unroll 4
  for (int r = 0; r < 256; ++r) {
    float f;
    if constexpr (F32) f = ((const float*)xv)[base + (size_t)r * 256];
    else               f = (float)((const bf16*)xv)[base + (size_t)r * 256];
    sm += f; q += f * f;
  }
  int o = (b * 16 + rc) * 256 + c;
  psum[o] = sm; psq[o] = q;
}

// ---------------- stats pass 2: combine + adain scale/shift -----------------
__global__ __launch_bounds__(256) void k_stats_fin(
    const float* __restrict__ psum, const float* __restrict__ psq,
    const float* __restrict__ s,
    float* __restrict__ scale, float* __restrict__ shift) {
  int b = blockIdx.x, c = threadIdx.x;
  float S = 0.f, Q = 0.f;
  #pragma unroll
  for (int rc = 0; rc < 16; ++rc) {
    S += psum[(b * 16 + rc) * 256 + c];
    Q += psq[(b * 16 + rc) * 256 + c];
  }
  float mean = S * (1.0f/4096.0f);
  float var  = Q * (1.0f/4096.0f) - mean * mean;
  float inv  = rsqrtf(var + 1e-5f);
  float mu_s  = s[b * 512 + c];
  float std_s = s[b * 512 + 256 + c];
  float sc = std_s * inv;
  scale[b * 256 + c] = sc;
  shift[b * 256 + c] = mu_s - sc * mean;
}

// ---------------- adain apply: out_bf16 = shift + scale * in ----------------
template<int F32>
__global__ __launch_bounds__(256) void k_adain(
    const void* __restrict__ in, const float* __restrict__ scale,
    const float* __restrict__ shift, bf16* __restrict__ out) {
  int idx = blockIdx.x * 256 + threadIdx.x;
  int c8 = idx & 31, row = idx >> 5;
  int b = row >> 12, c = c8 * 8;
  const float* scp = &scale[b * 256 + c];
  const float* shp = &shift[b * 256 + c];
  f32x4 sc0 = *(const f32x4*)scp, sc1 = *(const f32x4*)(scp + 4);
  f32x4 sh0 = *(const f32x4*)shp, sh1 = *(const f32x4*)(shp + 4);
  size_t ofs = (size_t)row * 256 + c;
  float f[8];
  if constexpr (F32) {
    f32x4 v0 = *(const f32x4*)&((const float*)in)[ofs];
    f32x4 v1 = *(const f32x4*)&((const float*)in)[ofs + 4];
    f[0]=v0[0]; f[1]=v0[1]; f[2]=v0[2]; f[3]=v0[3];
    f[4]=v1[0]; f[5]=v1[1]; f[6]=v1[2]; f[7]=v1[3];
  } else {
    bf16x8v v = *(const bf16x8v*)&((const bf16*)in)[ofs];
    #pragma unroll
    for (int u = 0; u < 8; ++u) f[u] = (float)v[u];
  }
  bf16x8v o;
  o[0]=(bf16)(sh0[0]+sc0[0]*f[0]); o[1]=(bf16)(sh0[1]+sc0[1]*f[1]);
  o[2]=(bf16)(sh0[2]+sc0[2]*f[2]); o[3]=(bf16)(sh0[3]+sc0[3]*f[3]);
  o[4]=(bf16)(sh1[0]+sc1[0]*f[4]); o[5]=(bf16)(sh1[1]+sc1[1]*f[5]);
  o[6]=(bf16)(sh1[2]+sc1[2]*f[6]); o[7]=(bf16)(sh1[3]+sc1[3]*f[7]);
  *(bf16x8v*)&out[ofs] = o;
}

// ---------------- weight transpose+cvt (K x N f32) -> (N x K bf16) ----------
__global__ __launch_bounds__(256) void k_tr(
    const float* __restrict__ in, bf16* __restrict__ out, int K, int N) {
  __shared__ float t[32][33];
  int bx = blockIdx.x * 32, by = blockIdx.y * 32;
  int tx = threadIdx.x & 31, ty = threadIdx.x >> 5;
  #pragma unroll
  for (int r = 0; r < 32; r += 8)
    t[ty + r][tx] = in[(size_t)(by + ty + r) * N + bx + tx];
  __syncthreads();
  #pragma unroll
  for (int r = 0; r < 32; r += 8)
    out[(size_t)(bx + ty + r) * K + by + tx] = (bf16)t[tx][ty + r];
}

// ---------------- GEMM (8-wave 256x128): out = A@Bt^T + bias (+gelu) --------
// OUTMODE: 0 = bf16 row-major, 2 = bf16 qkv-layout [(b*3+m)*8+hh][tok][32].
// Coalesced epilogue: output tile transposed through LDS (2 halves of 128
// rows, pad stride 132) -> 16B/lane stores (fc1: 256B segments, qkv: 64B).
template<int GELU, int OUTMODE>
__global__ __launch_bounds__(512) void k_gemm(
    const bf16* __restrict__ A, const bf16* __restrict__ Bt,
    const float* __restrict__ bias,
    void* __restrict__ outv, int N, int K, int gx) {
  __shared__ bf16 smem[256 * 64 + 128 * 64];   // 48 KB
  bf16* a_sw = smem;                // 32 KB
  bf16* b_sw = smem + 256 * 64;     // 16 KB
  int tid = threadIdx.x;
  int l = tid & 63, w = tid >> 6;
  int wr = w >> 1, wc = w & 1;             // 4x2 waves, 64x64 each
  int lm = l & 15, lg = l >> 4;

  int nwg = gridDim.x;
  int lin = blockIdx.x;
  int swz = (lin & 7) * (nwg >> 3) + (lin >> 3);
  int bx = swz % gx, by = swz / gx;
  int m0 = by * 256, n0 = bx * 128;

  f32x4 acc[4][4];
  #pragma unroll
  for (int mi = 0; mi < 4; ++mi)
    #pragma unroll
    for (int ni = 0; ni < 4; ++ni)
      acc[mi][ni] = (f32x4){0.f, 0.f, 0.f, 0.f};

  for (int k0 = 0; k0 < K; k0 += 64) {
    #pragma unroll
    for (int i = 0; i < 4; ++i) {
      int slot = i * 512 + tid;
      int r = slot >> 3, cs = slot & 7;
      int c = cs ^ (r & 7);                // inverse swizzle on SOURCE
      const bf16* g = A + (size_t)(m0 + r) * K + k0 + c * 8;
      __builtin_amdgcn_global_load_lds(
          (const AS1 void*)g, (AS3 void*)(a_sw + (i * 512 + w * 64) * 8),
          16, 0, 0);
    }
    #pragma unroll
    for (int i = 0; i < 2; ++i) {
      int slot = i * 512 + tid;
      int r = slot >> 3, cs = slot & 7;
      int c = cs ^ (r & 7);
      const bf16* g = Bt + (size_t)(n0 + r) * K + k0 + c * 8;
      __builtin_amdgcn_global_load_lds(
          (const AS1 void*)g, (AS3 void*)(b_sw + (i * 512 + w * 64) * 8),
          16, 0, 0);
    }
    __syncthreads();
    #pragma unroll
    for (int kk = 0; kk < 2; ++kk) {
      bf16x8v af[4], bv[4];
      #pragma unroll
      for (int mi = 0; mi < 4; ++mi) {
        int row = wr * 64 + mi * 16 + lm;
        af[mi] = *(const bf16x8v*)&a_sw[row * 64 + (((kk * 4 + lg) ^ (row & 7)) * 8)];
      }
      #pragma unroll
      for (int ni = 0; ni < 4; ++ni) {
        int row = wc * 64 + ni * 16 + lm;
        bv[ni] = *(const bf16x8v*)&b_sw[row * 64 + (((kk * 4 + lg) ^ (row & 7)) * 8)];
      }
      #pragma unroll
      for (int mi = 0; mi < 4; ++mi)
        #pragma unroll
        for (int ni = 0; ni < 4; ++ni)
          acc[mi][ni] = mfma16(af[mi], bv[ni], acc[mi][ni]);
    }
    __syncthreads();
  }

  // coalesced epilogue via LDS transpose: 2 halves x 128 rows, stride 132
  const int TL = 132;
  bf16* t_sw = smem;                       // 128*132*2 = 33.8 KB of 48
  #pragma unroll
  for (int half = 0; half < 2; ++half) {
    if (half) __syncthreads();             // prev half stores done
    if ((wr >> 1) == half) {
      int wrh = wr & 1;
      #pragma unroll
      for (int mi = 0; mi < 4; ++mi) {
        #pragma unroll
        for (int ni = 0; ni < 4; ++ni) {
          int rrow = wrh * 64 + mi * 16 + lg * 4;
          int ccol = wc * 64 + ni * 16 + lm;
          float bv_ = bias[n0 + ccol];
          #pragma unroll
          for (int j = 0; j < 4; ++j) {
            float o = acc[mi][ni][j] + bv_;
            if constexpr (GELU) {
              float z = 1.5957691216057308f * (o + 0.044715f * o * o * o);
              o = o / (1.0f + __expf(-z));
            }
            t_sw[(rrow + j) * TL + ccol] = (bf16)o;
          }
        }
      }
    }
    __syncthreads();
    #pragma unroll
    for (int it = 0; it < 4; ++it) {
      int rrow = w * 16 + it * 4 + lg;     // 0..127
      int row = m0 + half * 128 + rrow;
      bf16x8v v = *(const bf16x8v*)&t_sw[rrow * TL + lm * 8];
      if constexpr (OUTMODE == 2) {
        int b = row >> 12, tok = row & 4095;
        int col = n0 + lm * 8;
        int m = col >> 8, c2 = col & 255;
        int hh = c2 >> 5, ch = c2 & 31;
        size_t a_ = ((size_t)((b * 3 + m) * 8 + hh) << 17) + (tok << 5) + ch;
        *(bf16x8v*)&((bf16*)outv)[a_] = v;
      } else {
        *(bf16x8v*)&((bf16*)outv)[(size_t)row * N + n0 + lm * 8] = v;
      }
    }
  }
}

// ---------------- GEMM (4-wave 128x128) — for small grids (res-fused) -------
template<int RESMODE, int GELU, int OUTF32>
__global__ __launch_bounds__(256) void k_gemm4(
    const bf16* __restrict__ A, const bf16* __restrict__ Bt,
    const float* __restrict__ bias, const void* __restrict__ resv,
    void* __restrict__ outv, int N, int K, int gx) {
  __shared__ bf16 a_sw[128 * 64];
  __shared__ bf16 b_sw[128 * 64];
  int tid = threadIdx.x;
  int l = tid & 63, w = tid >> 6;
  int wr = w >> 1, wc = w & 1;
  int lm = l & 15, lg = l >> 4;

  int nwg = gridDim.x;
  int lin = blockIdx.x;
  int swz = (lin & 7) * (nwg >> 3) + (lin >> 3);
  int bx = swz % gx, by = swz / gx;
  int m0 = by * 128, n0 = bx * 128;

  f32x4 acc[4][4];
  #pragma unroll
  for (int mi = 0; mi < 4; ++mi)
    #pragma unroll
    for (int ni = 0; ni < 4; ++ni)
      acc[mi][ni] = (f32x4){0.f, 0.f, 0.f, 0.f};

  for (int k0 = 0; k0 < K; k0 += 64) {
    #pragma unroll
    for (int i = 0; i < 4; ++i) {
      int slot = i * 256 + tid;
      int r = slot >> 3, cs = slot & 7;
      int c = cs ^ (r & 7);
      __builtin_amdgcn_global_load_lds(
          (const AS1 void*)(A + (size_t)(m0 + r) * K + k0 + c * 8),
          (AS3 void*)(a_sw + (i * 256 + w * 64) * 8), 16, 0, 0);
    }
    #pragma unroll
    for (int i = 0; i < 4; ++i) {
      int slot = i * 256 + tid;
      int r = slot >> 3, cs = slot & 7;
      int c = cs ^ (r & 7);
      __builtin_amdgcn_global_load_lds(
          (const AS1 void*)(Bt + (size_t)(n0 + r) * K + k0 + c * 8),
          (AS3 void*)(b_sw + (i * 256 + w * 64) * 8), 16, 0, 0);
    }
    __syncthreads();
    #pragma unroll
    for (int kk = 0; kk < 2; ++kk) {
      bf16x8v af[4], bv[4];
      #pragma unroll
      for (int mi = 0; mi < 4; ++mi) {
        int row = wr * 64 + mi * 16 + lm;
        af[mi] = *(const bf16x8v*)&a_sw[row * 64 + (((kk * 4 + lg) ^ (row & 7)) * 8)];
      }
      #pragma unroll
      for (int ni = 0; ni < 4; ++ni) {
        int row = wc * 64 + ni * 16 + lm;
        bv[ni] = *(const bf16x8v*)&b_sw[row * 64 + (((kk * 4 + lg) ^ (row & 7)) * 8)];
      }
      #pragma unroll
      for (int mi = 0; mi < 4; ++mi)
        #pragma unroll
        for (int ni = 0; ni < 4; ++ni)
          acc[mi][ni] = mfma16(af[mi], bv[ni], acc[mi][ni]);
    }
    __syncthreads();
  }
  #pragma unroll
  for (int mi = 0; mi < 4; ++mi) {
    #pragma unroll
    for (int ni = 0; ni < 4; ++ni) {
      int row = m0 + wr * 64 + mi * 16 + lg * 4;
      int col = n0 + wc * 64 + ni * 16 + lm;
      float bv_ = bias[col];
      #pragma unroll
      for (int j = 0; j < 4; ++j) {
        float o = acc[mi][ni][j] + bv_;
        if constexpr (RESMODE == 1)
          o += ((const float*)resv)[(size_t)(row + j) * N + col];
        if constexpr (RESMODE == 2)
          o += (float)((const bf16*)resv)[(size_t)(row + j) * N + col];
        if constexpr (GELU) {
          float z = 1.5957691216057308f * (o + 0.044715f * o * o * o);
          o = o / (1.0f + __expf(-z));
        }
        if constexpr (OUTF32)
          ((float*)outv)[(size_t)(row + j) * N + col] = o;
        else
          ((bf16*)outv)[(size_t)(row + j) * N + col] = (bf16)o;
      }
    }
  }
}

// ---------------- windowed attention (both branches) ------------------------
// qkv in attention-native layout [(b*3+m)*8+hh][tok][32]: Q/K fragments read
// contiguous 512B token-row runs; V staged coalesced into swizzled V^T.
__global__ __launch_bounds__(256) void k_attn(
    const bf16* __restrict__ qkv,
    const float* __restrict__ rpb1, const float* __restrict__ rpb2,
    bf16* __restrict__ aout) {
  __shared__ bf16 vt[128 * 72];   // V^T: [hh2*32+ch][token-swizzled(+pad)]
  __shared__ float rl[960];       // rpb: [h][dy][dx] stride 240/16/1

  int tid = threadIdx.x;
  int bx = blockIdx.x;
  int br = bx & 1, widx = (bx >> 1) & 63, b = bx >> 7;
  int wy = widx >> 3, wx = widx & 7;

  const float* rpb = br ? rpb2 : rpb1;
  #pragma unroll
  for (int t = tid; t < 960; t += 256) {
    int h0 = t / 240, r0 = t - h0 * 240, dy = r0 >> 4, dx = r0 & 15;
    rl[t] = (dx < 15) ? rpb[(dy * 15 + dx) * 4 + h0] : 0.f;
  }

  auto grow = [&](int tok) -> int {
    int y = wy * 8 + (tok >> 3), xc = wx * 8 + (tok & 7);
    if (br) { y = (y + 4) & 63; xc = (xc + 4) & 63; }
    return y * 64 + xc;                  // in-batch token index
  };

  auto plane = [&](int m, int hh2) -> size_t {
    return (size_t)((b * 3 + m) * 8 + br * 4 + hh2) << 17;
  };

  // stage V transposed: task = tok*16 + c; c = hh2*4 + ch8
  #pragma unroll
  for (int it = 0; it < 4; ++it) {
    int task = it * 256 + tid;
    int tok = task >> 4, c = task & 15;
    int hh2 = c >> 2, ch8 = c & 3;
    bf16x8v v = *(const bf16x8v*)&qkv[plane(2, hh2) + (grow(tok) << 5) + ch8 * 8];
    int tsw = tok ^ ((c & 7) << 3);      // bank-spread swizzle (involution)
    #pragma unroll
    for (int u = 0; u < 8; ++u) vt[(c * 8 + u) * 72 + tsw] = v[u];
  }

  int l = tid & 63, h = tid >> 6;
  int lm = l & 15, lg = l >> 4;

  // Q/K frags: token rows are 64B; 16 toks = 2 contiguous 512B runs
  bf16x8v kb[4], qa[4];
  size_t pq = plane(0, h), pk = plane(1, h);
  #pragma unroll
  for (int i = 0; i < 4; ++i) {
    int t = grow(i * 16 + lm);
    qa[i] = *(const bf16x8v*)&qkv[pq + (t << 5) + lg * 8];
    kb[i] = *(const bf16x8v*)&qkv[pk + (t << 5) + lg * 8];
  }
  __syncthreads();   // vt + rl ready

  bf16x4v vb[2][4];
  #pragma unroll
  for (int ni = 0; ni < 2; ++ni)
    #pragma unroll
    for (int ki = 0; ki < 4; ++ki) {
      int row = h * 32 + ni * 16 + lm;
      int col = (ki * 16 + lg * 4) ^ (((row >> 3) & 7) << 3);
      vb[ni][ki] = *(const bf16x4v*)&vt[row * 72 + col];
    }

  bool need_mask = br && (wy == 7 || wx == 7);

  int ekA[16], idkA[16];
  #pragma unroll
  for (int ki = 0; ki < 4; ++ki)
    #pragma unroll
    for (int j = 0; j < 4; ++j) {
      int ik = ki * 16 + lg * 4 + j;
      ekA[ki * 4 + j] = ik + (ik >> 3) * 8;
      int yk = wy * 8 + (ik >> 3), xk = wx * 8 + (ik & 7);
      idkA[ki * 4 + j] = (yk < 56 ? 0 : (yk < 60 ? 1 : 2)) * 3
                       + (xk < 56 ? 0 : (xk < 60 ? 1 : 2));
    }

  #pragma unroll
  for (int qi = 0; qi < 4; ++qi) {
    f32x4 s[4];
    #pragma unroll
    for (int ki = 0; ki < 4; ++ki)
      s[ki] = mfma16(kb[ki], qa[qi], (f32x4){0.f,0.f,0.f,0.f});

    int iq = qi * 16 + lm;
    int eq = iq + (iq >> 3) * 8;
    int yq = wy * 8 + (iq >> 3), xq = wx * 8 + (iq & 7);
    int idq = (yq < 56 ? 0 : (yq < 60 ? 1 : 2)) * 3
            + (xq < 56 ? 0 : (xq < 60 ? 1 : 2));
    const float* fb = &rl[h * 240 + 119 + eq];

    #pragma unroll
    for (int ki = 0; ki < 4; ++ki)
      #pragma unroll
      for (int j = 0; j < 4; ++j) {
        float val = s[ki][j] * 0.17677669529663687f + fb[-ekA[ki * 4 + j]];
        if (need_mask && idq != idkA[ki * 4 + j]) val -= 100.0f;
        s[ki][j] = val;
      }

    float mx = s[0][0];
    #pragma unroll
    for (int ki = 0; ki < 4; ++ki)
      #pragma unroll
      for (int j = 0; j < 4; ++j) mx = fmaxf(mx, s[ki][j]);
    mx = fmaxf(mx, __shfl_xor(mx, 16));
    mx = fmaxf(mx, __shfl_xor(mx, 32));
    float sum = 0.f;
    #pragma unroll
    for (int ki = 0; ki < 4; ++ki)
      #pragma unroll
      for (int j = 0; j < 4; ++j) {
        float e = __expf(s[ki][j] - mx);
        s[ki][j] = e;
        sum += e;
      }
    sum += __shfl_xor(sum, 16);
    sum += __shfl_xor(sum, 32);
    float rs = 1.0f / sum;

    bf16x4v pa[4];
    #pragma unroll
    for (int ki = 0; ki < 4; ++ki)
      #pragma unroll
      for (int j = 0; j < 4; ++j)
        pa[ki][j] = (bf16)(s[ki][j] * rs);

    f32x4 o[2] = {(f32x4){0.f,0.f,0.f,0.f}, (f32x4){0.f,0.f,0.f,0.f}};
    #pragma unroll
    for (int ki = 0; ki < 4; ++ki) {
      o[0] = mfma16x16(pa[ki], vb[0][ki], o[0]);
      o[1] = mfma16x16(pa[ki], vb[1][ki], o[1]);
    }

    #pragma unroll
    for (int ni = 0; ni < 2; ++ni)
      #pragma unroll
      for (int j = 0; j < 4; ++j) {
        int tok = qi * 16 + lg * 4 + j;
        int col = br * 128 + h * 32 + ni * 16 + lm;
        aout[((size_t)b * 4096 + grow(tok)) * 256 + col] = (bf16)o[ni][j];
      }
  }
}

// ---------------- host ------------------------------------------------------
extern "C" void kernel_launch(void* const* d_in, const int* in_sizes, int n_in,
                              void* d_out, int out_size, void* d_ws, size_t ws_size,
                              hipStream_t stream) {
  (void)in_sizes; (void)n_in; (void)out_size; (void)ws_size;
  const float* x      = (const float*)d_in[0];
  const float* style  = (const float*)d_in[1];
  const float* w_qkv  = (const float*)d_in[2];
  const float* b_qkv  = (const float*)d_in[3];
  const float* w_proj = (const float*)d_in[4];
  const float* b_proj = (const float*)d_in[5];
  const float* w_ada1 = (const float*)d_in[6];
  const float* b_ada1 = (const float*)d_in[7];
  const float* w_ada2 = (const float*)d_in[8];
  const float* b_ada2 = (const float*)d_in[9];
  const float* rpb1   = (const float*)d_in[10];
  const float* rpb2   = (const float*)d_in[11];
  const float* w_fc1  = (const float*)d_in[12];
  const float* b_fc1  = (const float*)d_in[13];
  const float* w_fc2  = (const float*)d_in[14];
  const float* b_fc2  = (const float*)d_in[15];

  char* ws = (char*)d_ws;
  float* s1     = (float*)(ws + 0);
  float* s2     = (float*)(ws + 32768);
  float* scale1 = (float*)(ws + 65536);
  float* shift1 = (float*)(ws + 81920);
  float* scale2 = (float*)(ws + 98304);
  float* shift2 = (float*)(ws + 114688);
  bf16* wtqkv   = (bf16*)(ws + 131072);            // 768x256 bf16
  bf16* wtproj  = (bf16*)(ws + 524288);            // 256x256
  bf16* wtfc1   = (bf16*)(ws + 655360);            // 1024x256
  bf16* wtfc2   = (bf16*)(ws + 1179648);           // 256x1024
  float* psum   = (float*)(ws + 1703936);          // 16*16*256 f32
  float* psq    = (float*)(ws + 1966080);
  const size_t BIG = 2228224;
  bf16* xn   = (bf16*)(ws + BIG);                  // 65536x256 bf16 (33.5MB)
  bf16* qkv  = (bf16*)(ws + BIG + 33554432);       // 384 planes x 4096 x 32
  bf16* attn = (bf16*)(ws + BIG + 134217728);      // 65536x256 bf16 (33.5MB)
  bf16* x1   = (bf16*)(ws + BIG + 33554432);       // overlays qkv head
  bf16* xn2  = xn;                                 // reuses xn slot
  bf16* g    = (bf16*)(ws + BIG + 67108864);       // 32768x1024 chunk, qkv tail

  // weight transposes (f32 -> bf16)
  k_tr<<<dim3(24, 8),  256, 0, stream>>>(w_qkv,  wtqkv,  256, 768);
  k_tr<<<dim3(8, 8),   256, 0, stream>>>(w_proj, wtproj, 256, 256);
  k_tr<<<dim3(32, 8),  256, 0, stream>>>(w_fc1,  wtfc1,  256, 1024);
  k_tr<<<dim3(8, 32),  256, 0, stream>>>(w_fc2,  wtfc2,  1024, 256);

  // style projections, adain1 params, adain1 apply
  k_style<<<1024, 256, 0, stream>>>(style, w_ada1, b_ada1, w_ada2, b_ada2, s1, s2);
  k_stats_part<1><<<dim3(16, 16), 256, 0, stream>>>(x, psum, psq);
  k_stats_fin<<<16, 256, 0, stream>>>(psum, psq, s1, scale1, shift1);
  k_adain<1><<<8192, 256, 0, stream>>>(x, scale1, shift1, xn);

  // qkv = xn @ w_qkv + b_qkv  (attention-native output layout)
  k_gemm<0,2><<<1536, 512, 0, stream>>>(
      xn, wtqkv, b_qkv, qkv, 768, 256, 6);

  // windowed attention (both branches)
  k_attn<<<2048, 256, 0, stream>>>(qkv, rpb1, rpb2, attn);

  // x1 = x + attn @ w_proj + b_proj   (128x128: 512 x 2 = 1024)
  k_gemm4<1,0,0><<<1024, 256, 0, stream>>>(
      attn, wtproj, b_proj, x, x1, 256, 256, 2);

  // adain2 params + apply
  k_stats_part<0><<<dim3(16, 16), 256, 0, stream>>>(x1, psum, psq);
  k_stats_fin<<<16, 256, 0, stream>>>(psum, psq, s2, scale2, shift2);
  k_adain<0><<<8192, 256, 0, stream>>>(x1, scale2, shift2, xn2);

  // MLP in 2 row-chunks of 32768 (g reuses dead qkv tail region)
  for (int ch = 0; ch < 2; ++ch) {
    size_t ro = (size_t)ch * 32768;
    // g = gelu(xn2 @ w_fc1 + b_fc1)   (256x128: 128 x 8 = 1024)
    k_gemm<1,0><<<1024, 512, 0, stream>>>(
        xn2 + ro * 256, wtfc1, b_fc1, g, 1024, 256, 8);
    // out = x1 + g @ w_fc2 + b_fc2    (128x128: 256 x 2 = 512)
    k_gemm4<2,0,1><<<512, 256, 0, stream>>>(
        g, wtfc2, b_fc2, x1 + ro * 256,
        (float*)d_out + ro * 256, 256, 1024, 2);
  }
}

// Round 15
// 339.099 us; speedup vs baseline: 1.0088x; 1.0088x over previous
//
#include <hip/hip_runtime.h>
#include <hip/hip_bf16.h>

typedef __bf16 bf16;
typedef __bf16 bf16x4v __attribute__((ext_vector_type(4)));
typedef __bf16 bf16x8v __attribute__((ext_vector_type(8)));
typedef float f32x4 __attribute__((ext_vector_type(4)));
typedef short s16x4 __attribute__((ext_vector_type(4)));

#define DEVINL static __device__ __forceinline__
#define AS1 __attribute__((address_space(1)))
#define AS3 __attribute__((address_space(3)))

DEVINL f32x4 mfma16(bf16x8v a, bf16x8v b, f32x4 c) {
  return __builtin_amdgcn_mfma_f32_16x16x32_bf16(a, b, c, 0, 0, 0);
}

DEVINL f32x4 mfma16x16(bf16x4v a, bf16x4v b, f32x4 c) {
#if __has_builtin(__builtin_amdgcn_mfma_f32_16x16x16bf16_1k)
  return __builtin_amdgcn_mfma_f32_16x16x16bf16_1k(
      __builtin_bit_cast(s16x4, a), __builtin_bit_cast(s16x4, b), c, 0, 0, 0);
#else
  f32x4 d;
  asm("v_mfma_f32_16x16x16_bf16 %0, %1, %2, %3"
      : "=v"(d) : "v"(a), "v"(b), "v"(c));
  return d;
#endif
}

// ---------------- style projections: s = style @ w_ada + b_ada (f32) --------
__global__ __launch_bounds__(256) void k_style(
    const float* __restrict__ style,
    const float* __restrict__ wa1, const float* __restrict__ ba1,
    const float* __restrict__ wa2, const float* __restrict__ ba2,
    float* __restrict__ s1, float* __restrict__ s2) {
  int bid = blockIdx.x;
  int ng = bid & 31, b = (bid >> 5) & 15, which = bid >> 9;
  int tid = threadIdx.x;
  int nl = tid & 15, kg = tid >> 4;
  int n = ng * 16 + nl;
  const float* wa = which ? wa2 : wa1;
  const float* ba = which ? ba2 : ba1;
  const float* srow = style + b * 512;
  float acc = 0.f;
  #pragma unroll 8
  for (int kk = 0; kk < 32; ++kk) {
    int k = kg + kk * 16;
    acc += srow[k] * wa[k * 512 + n];
  }
  acc += __shfl_xor(acc, 16);
  acc += __shfl_xor(acc, 32);
  __shared__ float red[4][16];
  int w = tid >> 6;
  if ((tid & 63) < 16) red[w][nl] = acc;
  __syncthreads();
  if (tid < 16) {
    float S = red[0][tid] + red[1][tid] + red[2][tid] + red[3][tid]
            + ba[ng * 16 + tid];
    (which ? s2 : s1)[b * 512 + ng * 16 + tid] = S;
  }
}

// ---------------- stats pass 1: per (b, row-chunk) partial sum/sumsq --------
template<int F32>
__global__ __launch_bounds__(256) void k_stats_part(
    const void* __restrict__ xv, float* __restrict__ psum,
    float* __restrict__ psq) {
  int rc = blockIdx.x, b = blockIdx.y;
  int c = threadIdx.x;
  size_t base = (size_t)b * 4096 * 256 + (size_t)rc * 256 * 256 + c;
  float sm = 0.f, q = 0.f;
  #pragma unroll 4
  for (int r = 0; r < 256; ++r) {
    float f;
    if constexpr (F32) f = ((const float*)xv)[base + (size_t)r * 256];
    else               f = (float)((const bf16*)xv)[base + (size_t)r * 256];
    sm += f; q += f * f;
  }
  int o = (b * 16 + rc) * 256 + c;
  psum[o] = sm; psq[o] = q;
}

// ---------------- stats pass 2: combine + adain scale/shift -----------------
__global__ __launch_bounds__(256) void k_stats_fin(
    const float* __restrict__ psum, const float* __restrict__ psq,
    const float* __restrict__ s,
    float* __restrict__ scale, float* __restrict__ shift) {
  int b = blockIdx.x, c = threadIdx.x;
  float S = 0.f, Q = 0.f;
  #pragma unroll
  for (int rc = 0; rc < 16; ++rc) {
    S += psum[(b * 16 + rc) * 256 + c];
    Q += psq[(b * 16 + rc) * 256 + c];
  }
  float mean = S * (1.0f/4096.0f);
  float var  = Q * (1.0f/4096.0f) - mean * mean;
  float inv  = rsqrtf(var + 1e-5f);
  float mu_s  = s[b * 512 + c];
  float std_s = s[b * 512 + 256 + c];
  float sc = std_s * inv;
  scale[b * 256 + c] = sc;
  shift[b * 256 + c] = mu_s - sc * mean;
}

// ---------------- adain apply: out_bf16 = shift + scale * in ----------------
template<int F32>
__global__ __launch_bounds__(256) void k_adain(
    const void* __restrict__ in, const float* __restrict__ scale,
    const float* __restrict__ shift, bf16* __restrict__ out) {
  int idx = blockIdx.x * 256 + threadIdx.x;
  int c8 = idx & 31, row = idx >> 5;
  int b = row >> 12, c = c8 * 8;
  const float* scp = &scale[b * 256 + c];
  const float* shp = &shift[b * 256 + c];
  f32x4 sc0 = *(const f32x4*)scp, sc1 = *(const f32x4*)(scp + 4);
  f32x4 sh0 = *(const f32x4*)shp, sh1 = *(const f32x4*)(shp + 4);
  size_t ofs = (size_t)row * 256 + c;
  float f[8];
  if constexpr (F32) {
    f32x4 v0 = *(const f32x4*)&((const float*)in)[ofs];
    f32x4 v1 = *(const f32x4*)&((const float*)in)[ofs + 4];
    f[0]=v0[0]; f[1]=v0[1]; f[2]=v0[2]; f[3]=v0[3];
    f[4]=v1[0]; f[5]=v1[1]; f[6]=v1[2]; f[7]=v1[3];
  } else {
    bf16x8v v = *(const bf16x8v*)&((const bf16*)in)[ofs];
    #pragma unroll
    for (int u = 0; u < 8; ++u) f[u] = (float)v[u];
  }
  bf16x8v o;
  o[0]=(bf16)(sh0[0]+sc0[0]*f[0]); o[1]=(bf16)(sh0[1]+sc0[1]*f[1]);
  o[2]=(bf16)(sh0[2]+sc0[2]*f[2]); o[3]=(bf16)(sh0[3]+sc0[3]*f[3]);
  o[4]=(bf16)(sh1[0]+sc1[0]*f[4]); o[5]=(bf16)(sh1[1]+sc1[1]*f[5]);
  o[6]=(bf16)(sh1[2]+sc1[2]*f[6]); o[7]=(bf16)(sh1[3]+sc1[3]*f[7]);
  *(bf16x8v*)&out[ofs] = o;
}

// ---------------- weight transpose+cvt (K x N f32) -> (N x K bf16) ----------
__global__ __launch_bounds__(256) void k_tr(
    const float* __restrict__ in, bf16* __restrict__ out, int K, int N) {
  __shared__ float t[32][33];
  int bx = blockIdx.x * 32, by = blockIdx.y * 32;
  int tx = threadIdx.x & 31, ty = threadIdx.x >> 5;
  #pragma unroll
  for (int r = 0; r < 32; r += 8)
    t[ty + r][tx] = in[(size_t)(by + ty + r) * N + bx + tx];
  __syncthreads();
  #pragma unroll
  for (int r = 0; r < 32; r += 8)
    out[(size_t)(bx + ty + r) * K + by + tx] = (bf16)t[tx][ty + r];
}

// ---------------- GEMM (8-wave 256x128): out = A@Bt^T + bias (+res,gelu) ----
// OUTMODE: 0 = bf16 row-major, 1 = f32 row-major,
//          2 = bf16 qkv-layout [(b*3+m)*8+hh][tok(4096)][32] (attention-native)
template<int RESMODE, int GELU, int OUTMODE>
__global__ __launch_bounds__(512) void k_gemm(
    const bf16* __restrict__ A, const bf16* __restrict__ Bt,
    const float* __restrict__ bias, const void* __restrict__ resv,
    void* __restrict__ outv, int N, int K, int gx) {
  __shared__ bf16 a_sw[256 * 64];   // 32 KB
  __shared__ bf16 b_sw[128 * 64];   // 16 KB
  int tid = threadIdx.x;
  int l = tid & 63, w = tid >> 6;
  int wr = w >> 1, wc = w & 1;             // 4x2 waves, 64x64 each
  int lm = l & 15, lg = l >> 4;

  int nwg = gridDim.x;
  int lin = blockIdx.x;
  int swz = (lin & 7) * (nwg >> 3) + (lin >> 3);
  int bx = swz % gx, by = swz / gx;
  int m0 = by * 256, n0 = bx * 128;

  f32x4 acc[4][4];
  #pragma unroll
  for (int mi = 0; mi < 4; ++mi)
    #pragma unroll
    for (int ni = 0; ni < 4; ++ni)
      acc[mi][ni] = (f32x4){0.f, 0.f, 0.f, 0.f};

  for (int k0 = 0; k0 < K; k0 += 64) {
    #pragma unroll
    for (int i = 0; i < 4; ++i) {
      int slot = i * 512 + tid;
      int r = slot >> 3, cs = slot & 7;
      int c = cs ^ (r & 7);                // inverse swizzle on SOURCE
      const bf16* g = A + (size_t)(m0 + r) * K + k0 + c * 8;
      __builtin_amdgcn_global_load_lds(
          (const AS1 void*)g, (AS3 void*)(a_sw + (i * 512 + w * 64) * 8),
          16, 0, 0);
    }
    #pragma unroll
    for (int i = 0; i < 2; ++i) {
      int slot = i * 512 + tid;
      int r = slot >> 3, cs = slot & 7;
      int c = cs ^ (r & 7);
      const bf16* g = Bt + (size_t)(n0 + r) * K + k0 + c * 8;
      __builtin_amdgcn_global_load_lds(
          (const AS1 void*)g, (AS3 void*)(b_sw + (i * 512 + w * 64) * 8),
          16, 0, 0);
    }
    __syncthreads();
    #pragma unroll
    for (int kk = 0; kk < 2; ++kk) {
      bf16x8v af[4], bv[4];
      #pragma unroll
      for (int mi = 0; mi < 4; ++mi) {
        int row = wr * 64 + mi * 16 + lm;
        af[mi] = *(const bf16x8v*)&a_sw[row * 64 + (((kk * 4 + lg) ^ (row & 7)) * 8)];
      }
      #pragma unroll
      for (int ni = 0; ni < 4; ++ni) {
        int row = wc * 64 + ni * 16 + lm;
        bv[ni] = *(const bf16x8v*)&b_sw[row * 64 + (((kk * 4 + lg) ^ (row & 7)) * 8)];
      }
      #pragma unroll
      for (int mi = 0; mi < 4; ++mi)
        #pragma unroll
        for (int ni = 0; ni < 4; ++ni)
          acc[mi][ni] = mfma16(af[mi], bv[ni], acc[mi][ni]);
    }
    __syncthreads();
  }
  #pragma unroll
  for (int mi = 0; mi < 4; ++mi) {
    #pragma unroll
    for (int ni = 0; ni < 4; ++ni) {
      int row = m0 + wr * 64 + mi * 16 + lg * 4;
      int col = n0 + wc * 64 + ni * 16 + lm;
      float bv_ = bias[col];
      #pragma unroll
      for (int j = 0; j < 4; ++j) {
        float o = acc[mi][ni][j] + bv_;
        if constexpr (RESMODE == 1)
          o += ((const float*)resv)[(size_t)(row + j) * N + col];
        if constexpr (RESMODE == 2)
          o += (float)((const bf16*)resv)[(size_t)(row + j) * N + col];
        if constexpr (GELU) {
          float z = 1.5957691216057308f * (o + 0.044715f * o * o * o);
          o = o / (1.0f + __expf(-z));
        }
        if constexpr (OUTMODE == 1)
          ((float*)outv)[(size_t)(row + j) * N + col] = o;
        else if constexpr (OUTMODE == 2) {
          int b  = (row + j) >> 12, tok = (row + j) & 4095;
          int m  = col >> 8, c2 = col & 255;
          int hh = c2 >> 5, ch = c2 & 31;
          size_t a_ = ((size_t)((b * 3 + m) * 8 + hh) << 17) + (tok << 5) + ch;
          ((bf16*)outv)[a_] = (bf16)o;
        } else
          ((bf16*)outv)[(size_t)(row + j) * N + col] = (bf16)o;
      }
    }
  }
}

// ---------------- GEMM (4-wave 128x128) — for small grids -------------------
template<int RESMODE, int GELU, int OUTF32>
__global__ __launch_bounds__(256) void k_gemm4(
    const bf16* __restrict__ A, const bf16* __restrict__ Bt,
    const float* __restrict__ bias, const void* __restrict__ resv,
    void* __restrict__ outv, int N, int K, int gx) {
  __shared__ bf16 a_sw[128 * 64];
  __shared__ bf16 b_sw[128 * 64];
  int tid = threadIdx.x;
  int l = tid & 63, w = tid >> 6;
  int wr = w >> 1, wc = w & 1;
  int lm = l & 15, lg = l >> 4;

  int nwg = gridDim.x;
  int lin = blockIdx.x;
  int swz = (lin & 7) * (nwg >> 3) + (lin >> 3);
  int bx = swz % gx, by = swz / gx;
  int m0 = by * 128, n0 = bx * 128;

  f32x4 acc[4][4];
  #pragma unroll
  for (int mi = 0; mi < 4; ++mi)
    #pragma unroll
    for (int ni = 0; ni < 4; ++ni)
      acc[mi][ni] = (f32x4){0.f, 0.f, 0.f, 0.f};

  for (int k0 = 0; k0 < K; k0 += 64) {
    #pragma unroll
    for (int i = 0; i < 4; ++i) {
      int slot = i * 256 + tid;
      int r = slot >> 3, cs = slot & 7;
      int c = cs ^ (r & 7);
      __builtin_amdgcn_global_load_lds(
          (const AS1 void*)(A + (size_t)(m0 + r) * K + k0 + c * 8),
          (AS3 void*)(a_sw + (i * 256 + w * 64) * 8), 16, 0, 0);
    }
    #pragma unroll
    for (int i = 0; i < 4; ++i) {
      int slot = i * 256 + tid;
      int r = slot >> 3, cs = slot & 7;
      int c = cs ^ (r & 7);
      __builtin_amdgcn_global_load_lds(
          (const AS1 void*)(Bt + (size_t)(n0 + r) * K + k0 + c * 8),
          (AS3 void*)(b_sw + (i * 256 + w * 64) * 8), 16, 0, 0);
    }
    __syncthreads();
    #pragma unroll
    for (int kk = 0; kk < 2; ++kk) {
      bf16x8v af[4], bv[4];
      #pragma unroll
      for (int mi = 0; mi < 4; ++mi) {
        int row = wr * 64 + mi * 16 + lm;
        af[mi] = *(const bf16x8v*)&a_sw[row * 64 + (((kk * 4 + lg) ^ (row & 7)) * 8)];
      }
      #pragma unroll
      for (int ni = 0; ni < 4; ++ni) {
        int row = wc * 64 + ni * 16 + lm;
        bv[ni] = *(const bf16x8v*)&b_sw[row * 64 + (((kk * 4 + lg) ^ (row & 7)) * 8)];
      }
      #pragma unroll
      for (int mi = 0; mi < 4; ++mi)
        #pragma unroll
        for (int ni = 0; ni < 4; ++ni)
          acc[mi][ni] = mfma16(af[mi], bv[ni], acc[mi][ni]);
    }
    __syncthreads();
  }
  #pragma unroll
  for (int mi = 0; mi < 4; ++mi) {
    #pragma unroll
    for (int ni = 0; ni < 4; ++ni) {
      int row = m0 + wr * 64 + mi * 16 + lg * 4;
      int col = n0 + wc * 64 + ni * 16 + lm;
      float bv_ = bias[col];
      #pragma unroll
      for (int j = 0; j < 4; ++j) {
        float o = acc[mi][ni][j] + bv_;
        if constexpr (RESMODE == 1)
          o += ((const float*)resv)[(size_t)(row + j) * N + col];
        if constexpr (RESMODE == 2)
          o += (float)((const bf16*)resv)[(size_t)(row + j) * N + col];
        if constexpr (GELU) {
          float z = 1.5957691216057308f * (o + 0.044715f * o * o * o);
          o = o / (1.0f + __expf(-z));
        }
        if constexpr (OUTF32)
          ((float*)outv)[(size_t)(row + j) * N + col] = o;
        else
          ((bf16*)outv)[(size_t)(row + j) * N + col] = (bf16)o;
      }
    }
  }
}

// ---------------- windowed attention (both branches) ------------------------
// qkv in attention-native layout [(b*3+m)*8+hh][tok][32]: Q/K fragments read
// contiguous 512B token-row runs; V staged coalesced into swizzled V^T.
__global__ __launch_bounds__(256) void k_attn(
    const bf16* __restrict__ qkv,
    const float* __restrict__ rpb1, const float* __restrict__ rpb2,
    bf16* __restrict__ aout) {
  __shared__ bf16 vt[128 * 72];   // V^T: [hh2*32+ch][token-swizzled(+pad)]
  __shared__ float rl[960];       // rpb: [h][dy][dx] stride 240/16/1

  int tid = threadIdx.x;
  int bx = blockIdx.x;
  int br = bx & 1, widx = (bx >> 1) & 63, b = bx >> 7;
  int wy = widx >> 3, wx = widx & 7;

  const float* rpb = br ? rpb2 : rpb1;
  #pragma unroll
  for (int t = tid; t < 960; t += 256) {
    int h0 = t / 240, r0 = t - h0 * 240, dy = r0 >> 4, dx = r0 & 15;
    rl[t] = (dx < 15) ? rpb[(dy * 15 + dx) * 4 + h0] : 0.f;
  }

  auto grow = [&](int tok) -> int {
    int y = wy * 8 + (tok >> 3), xc = wx * 8 + (tok & 7);
    if (br) { y = (y + 4) & 63; xc = (xc + 4) & 63; }
    return y * 64 + xc;                  // in-batch token index
  };

  auto plane = [&](int m, int hh2) -> size_t {
    return (size_t)((b * 3 + m) * 8 + br * 4 + hh2) << 17;
  };

  // stage V transposed: task = tok*16 + c; c = hh2*4 + ch8
  #pragma unroll
  for (int it = 0; it < 4; ++it) {
    int task = it * 256 + tid;
    int tok = task >> 4, c = task & 15;
    int hh2 = c >> 2, ch8 = c & 3;
    bf16x8v v = *(const bf16x8v*)&qkv[plane(2, hh2) + (grow(tok) << 5) + ch8 * 8];
    int tsw = tok ^ ((c & 7) << 3);      // bank-spread swizzle (involution)
    #pragma unroll
    for (int u = 0; u < 8; ++u) vt[(c * 8 + u) * 72 + tsw] = v[u];
  }

  int l = tid & 63, h = tid >> 6;
  int lm = l & 15, lg = l >> 4;

  // Q/K frags: token rows are 64B; 16 toks = 2 contiguous 512B runs
  bf16x8v kb[4], qa[4];
  size_t pq = plane(0, h), pk = plane(1, h);
  #pragma unroll
  for (int i = 0; i < 4; ++i) {
    int t = grow(i * 16 + lm);
    qa[i] = *(const bf16x8v*)&qkv[pq + (t << 5) + lg * 8];
    kb[i] = *(const bf16x8v*)&qkv[pk + (t << 5) + lg * 8];
  }
  __syncthreads();   // vt + rl ready

  bf16x4v vb[2][4];
  #pragma unroll
  for (int ni = 0; ni < 2; ++ni)
    #pragma unroll
    for (int ki = 0; ki < 4; ++ki) {
      int row = h * 32 + ni * 16 + lm;
      int col = (ki * 16 + lg * 4) ^ (((row >> 3) & 7) << 3);
      vb[ni][ki] = *(const bf16x4v*)&vt[row * 72 + col];
    }

  bool need_mask = br && (wy == 7 || wx == 7);

  int ekA[16], idkA[16];
  #pragma unroll
  for (int ki = 0; ki < 4; ++ki)
    #pragma unroll
    for (int j = 0; j < 4; ++j) {
      int ik = ki * 16 + lg * 4 + j;
      ekA[ki * 4 + j] = ik + (ik >> 3) * 8;
      int yk = wy * 8 + (ik >> 3), xk = wx * 8 + (ik & 7);
      idkA[ki * 4 + j] = (yk < 56 ? 0 : (yk < 60 ? 1 : 2)) * 3
                       + (xk < 56 ? 0 : (xk < 60 ? 1 : 2));
    }

  #pragma unroll
  for (int qi = 0; qi < 4; ++qi) {
    f32x4 s[4];
    #pragma unroll
    for (int ki = 0; ki < 4; ++ki)
      s[ki] = mfma16(kb[ki], qa[qi], (f32x4){0.f,0.f,0.f,0.f});

    int iq = qi * 16 + lm;
    int eq = iq + (iq >> 3) * 8;
    int yq = wy * 8 + (iq >> 3), xq = wx * 8 + (iq & 7);
    int idq = (yq < 56 ? 0 : (yq < 60 ? 1 : 2)) * 3
            + (xq < 56 ? 0 : (xq < 60 ? 1 : 2));
    const float* fb = &rl[h * 240 + 119 + eq];

    #pragma unroll
    for (int ki = 0; ki < 4; ++ki)
      #pragma unroll
      for (int j = 0; j < 4; ++j) {
        float val = s[ki][j] * 0.17677669529663687f + fb[-ekA[ki * 4 + j]];
        if (need_mask && idq != idkA[ki * 4 + j]) val -= 100.0f;
        s[ki][j] = val;
      }

    float mx = s[0][0];
    #pragma unroll
    for (int ki = 0; ki < 4; ++ki)
      #pragma unroll
      for (int j = 0; j < 4; ++j) mx = fmaxf(mx, s[ki][j]);
    mx = fmaxf(mx, __shfl_xor(mx, 16));
    mx = fmaxf(mx, __shfl_xor(mx, 32));
    float sum = 0.f;
    #pragma unroll
    for (int ki = 0; ki < 4; ++ki)
      #pragma unroll
      for (int j = 0; j < 4; ++j) {
        float e = __expf(s[ki][j] - mx);
        s[ki][j] = e;
        sum += e;
      }
    sum += __shfl_xor(sum, 16);
    sum += __shfl_xor(sum, 32);
    float rs = 1.0f / sum;

    bf16x4v pa[4];
    #pragma unroll
    for (int ki = 0; ki < 4; ++ki)
      #pragma unroll
      for (int j = 0; j < 4; ++j)
        pa[ki][j] = (bf16)(s[ki][j] * rs);

    f32x4 o[2] = {(f32x4){0.f,0.f,0.f,0.f}, (f32x4){0.f,0.f,0.f,0.f}};
    #pragma unroll
    for (int ki = 0; ki < 4; ++ki) {
      o[0] = mfma16x16(pa[ki], vb[0][ki], o[0]);
      o[1] = mfma16x16(pa[ki], vb[1][ki], o[1]);
    }

    #pragma unroll
    for (int ni = 0; ni < 2; ++ni)
      #pragma unroll
      for (int j = 0; j < 4; ++j) {
        int tok = qi * 16 + lg * 4 + j;
        int col = br * 128 + h * 32 + ni * 16 + lm;
        aout[((size_t)b * 4096 + grow(tok)) * 256 + col] = (bf16)o[ni][j];
      }
  }
}

// ---------------- host ------------------------------------------------------
extern "C" void kernel_launch(void* const* d_in, const int* in_sizes, int n_in,
                              void* d_out, int out_size, void* d_ws, size_t ws_size,
                              hipStream_t stream) {
  (void)in_sizes; (void)n_in; (void)out_size;
  const float* x      = (const float*)d_in[0];
  const float* style  = (const float*)d_in[1];
  const float* w_qkv  = (const float*)d_in[2];
  const float* b_qkv  = (const float*)d_in[3];
  const float* w_proj = (const float*)d_in[4];
  const float* b_proj = (const float*)d_in[5];
  const float* w_ada1 = (const float*)d_in[6];
  const float* b_ada1 = (const float*)d_in[7];
  const float* w_ada2 = (const float*)d_in[8];
  const float* b_ada2 = (const float*)d_in[9];
  const float* rpb1   = (const float*)d_in[10];
  const float* rpb2   = (const float*)d_in[11];
  const float* w_fc1  = (const float*)d_in[12];
  const float* b_fc1  = (const float*)d_in[13];
  const float* w_fc2  = (const float*)d_in[14];
  const float* b_fc2  = (const float*)d_in[15];

  char* ws = (char*)d_ws;
  float* s1     = (float*)(ws + 0);
  float* s2     = (float*)(ws + 32768);
  float* scale1 = (float*)(ws + 65536);
  float* shift1 = (float*)(ws + 81920);
  float* scale2 = (float*)(ws + 98304);
  float* shift2 = (float*)(ws + 114688);
  bf16* wtqkv   = (bf16*)(ws + 131072);            // 768x256 bf16
  bf16* wtproj  = (bf16*)(ws + 524288);            // 256x256
  bf16* wtfc1   = (bf16*)(ws + 655360);            // 1024x256
  bf16* wtfc2   = (bf16*)(ws + 1179648);           // 256x1024
  float* psum   = (float*)(ws + 1703936);          // 16*16*256 f32
  float* psq    = (float*)(ws + 1966080);
  const size_t BIG = 2228224;
  bf16* xn   = (bf16*)(ws + BIG);                  // 65536x256 bf16 (33.5MB)
  bf16* qkv  = (bf16*)(ws + BIG + 33554432);       // 384 planes x 4096 x 32
  bf16* attn = (bf16*)(ws + BIG + 134217728);      // 65536x256 bf16 (33.5MB)
  bf16* x1   = (bf16*)(ws + BIG + 33554432);       // overlays qkv head
  bf16* xn2  = xn;                                 // reuses xn slot
  bf16* g    = (bf16*)(ws + BIG + 67108864);       // overlays qkv tail (+attn)

  // full-M MLP needs g = 65536x1024 bf16 = 134.2MB ending at BIG+201.3MB
  bool fullM = ws_size >= (BIG + 67108864 + 134217728);

  // weight transposes (f32 -> bf16)
  k_tr<<<dim3(24, 8),  256, 0, stream>>>(w_qkv,  wtqkv,  256, 768);
  k_tr<<<dim3(8, 8),   256, 0, stream>>>(w_proj, wtproj, 256, 256);
  k_tr<<<dim3(32, 8),  256, 0, stream>>>(w_fc1,  wtfc1,  256, 1024);
  k_tr<<<dim3(8, 32),  256, 0, stream>>>(w_fc2,  wtfc2,  1024, 256);

  // style projections, adain1 params, adain1 apply
  k_style<<<1024, 256, 0, stream>>>(style, w_ada1, b_ada1, w_ada2, b_ada2, s1, s2);
  k_stats_part<1><<<dim3(16, 16), 256, 0, stream>>>(x, psum, psq);
  k_stats_fin<<<16, 256, 0, stream>>>(psum, psq, s1, scale1, shift1);
  k_adain<1><<<8192, 256, 0, stream>>>(x, scale1, shift1, xn);

  // qkv = xn @ w_qkv + b_qkv  (attention-native output layout)
  k_gemm<0,0,2><<<1536, 512, 0, stream>>>(
      xn, wtqkv, b_qkv, nullptr, qkv, 768, 256, 6);

  // windowed attention (both branches)
  k_attn<<<2048, 256, 0, stream>>>(qkv, rpb1, rpb2, attn);

  // x1 = x + attn @ w_proj + b_proj   (128x128: 512 x 2 = 1024)
  k_gemm4<1,0,0><<<1024, 256, 0, stream>>>(
      attn, wtproj, b_proj, x, x1, 256, 256, 2);

  // adain2 params + apply
  k_stats_part<0><<<dim3(16, 16), 256, 0, stream>>>(x1, psum, psq);
  k_stats_fin<<<16, 256, 0, stream>>>(psum, psq, s2, scale2, shift2);
  k_adain<0><<<8192, 256, 0, stream>>>(x1, scale2, shift2, xn2);

  if (fullM) {
    // g = gelu(xn2 @ w_fc1 + b_fc1)   (256x128: 256 x 8 = 2048)
    k_gemm<0,1,0><<<2048, 512, 0, stream>>>(
        xn2, wtfc1, b_fc1, nullptr, g, 1024, 256, 8);
    // out = x1 + g @ w_fc2 + b_fc2    (128x128: 512 x 2 = 1024)
    k_gemm4<2,0,1><<<1024, 256, 0, stream>>>(
        g, wtfc2, b_fc2, x1, (float*)d_out, 256, 1024, 2);
  } else {
    for (int ch = 0; ch < 2; ++ch) {
      size_t ro = (size_t)ch * 32768;
      k_gemm<0,1,0><<<1024, 512, 0, stream>>>(
          xn2 + ro * 256, wtfc1, b_fc1, nullptr, g, 1024, 256, 8);
      k_gemm4<2,0,1><<<512, 256, 0, stream>>>(
          g, wtfc2, b_fc2, x1 + ro * 256,
          (float*)d_out + ro * 256, 256, 1024, 2);
    }
  }
}

// Round 16
// 322.116 us; speedup vs baseline: 1.0620x; 1.0527x over previous
//
#include <hip/hip_runtime.h>
#include <hip/hip_bf16.h>

typedef __bf16 bf16;
typedef __bf16 bf16x4v __attribute__((ext_vector_type(4)));
typedef __bf16 bf16x8v __attribute__((ext_vector_type(8)));
typedef float f32x4 __attribute__((ext_vector_type(4)));
typedef short s16x4 __attribute__((ext_vector_type(4)));

#define DEVINL static __device__ __forceinline__
#define AS1 __attribute__((address_space(1)))
#define AS3 __attribute__((address_space(3)))

DEVINL f32x4 mfma16(bf16x8v a, bf16x8v b, f32x4 c) {
  return __builtin_amdgcn_mfma_f32_16x16x32_bf16(a, b, c, 0, 0, 0);
}

DEVINL f32x4 mfma16x16(bf16x4v a, bf16x4v b, f32x4 c) {
#if __has_builtin(__builtin_amdgcn_mfma_f32_16x16x16bf16_1k)
  return __builtin_amdgcn_mfma_f32_16x16x16bf16_1k(
      __builtin_bit_cast(s16x4, a), __builtin_bit_cast(s16x4, b), c, 0, 0, 0);
#else
  f32x4 d;
  asm("v_mfma_f32_16x16x16_bf16 %0, %1, %2, %3"
      : "=v"(d) : "v"(a), "v"(b), "v"(c));
  return d;
#endif
}

// ---------------- style projections: s = style @ w_ada + b_ada (f32) --------
__global__ __launch_bounds__(256) void k_style(
    const float* __restrict__ style,
    const float* __restrict__ wa1, const float* __restrict__ ba1,
    const float* __restrict__ wa2, const float* __restrict__ ba2,
    float* __restrict__ s1, float* __restrict__ s2) {
  int bid = blockIdx.x;
  int ng = bid & 31, b = (bid >> 5) & 15, which = bid >> 9;
  int tid = threadIdx.x;
  int nl = tid & 15, kg = tid >> 4;
  int n = ng * 16 + nl;
  const float* wa = which ? wa2 : wa1;
  const float* ba = which ? ba2 : ba1;
  const float* srow = style + b * 512;
  float acc = 0.f;
  #pragma unroll 8
  for (int kk = 0; kk < 32; ++kk) {
    int k = kg + kk * 16;
    acc += srow[k] * wa[k * 512 + n];
  }
  acc += __shfl_xor(acc, 16);
  acc += __shfl_xor(acc, 32);
  __shared__ float red[4][16];
  int w = tid >> 6;
  if ((tid & 63) < 16) red[w][nl] = acc;
  __syncthreads();
  if (tid < 16) {
    float S = red[0][tid] + red[1][tid] + red[2][tid] + red[3][tid]
            + ba[ng * 16 + tid];
    (which ? s2 : s1)[b * 512 + ng * 16 + tid] = S;
  }
}

// ---------------- stats pass 1: per (b, row-chunk) partial sum/sumsq --------
template<int F32>
__global__ __launch_bounds__(256) void k_stats_part(
    const void* __restrict__ xv, float* __restrict__ psum,
    float* __restrict__ psq) {
  int rc = blockIdx.x, b = blockIdx.y;
  int c = threadIdx.x;
  size_t base = (size_t)b * 4096 * 256 + (size_t)rc * 256 * 256 + c;
  float sm = 0.f, q = 0.f;
  #pragma unroll 4
  for (int r = 0; r < 256; ++r) {
    float f;
    if constexpr (F32) f = ((const float*)xv)[base + (size_t)r * 256];
    else               f = (float)((const bf16*)xv)[base + (size_t)r * 256];
    sm += f; q += f * f;
  }
  int o = (b * 16 + rc) * 256 + c;
  psum[o] = sm; psq[o] = q;
}

// ---------------- stats pass 2: combine + adain scale/shift -----------------
__global__ __launch_bounds__(256) void k_stats_fin(
    const float* __restrict__ psum, const float* __restrict__ psq,
    const float* __restrict__ s,
    float* __restrict__ scale, float* __restrict__ shift) {
  int b = blockIdx.x, c = threadIdx.x;
  float S = 0.f, Q = 0.f;
  #pragma unroll
  for (int rc = 0; rc < 16; ++rc) {
    S += psum[(b * 16 + rc) * 256 + c];
    Q += psq[(b * 16 + rc) * 256 + c];
  }
  float mean = S * (1.0f/4096.0f);
  float var  = Q * (1.0f/4096.0f) - mean * mean;
  float inv  = rsqrtf(var + 1e-5f);
  float mu_s  = s[b * 512 + c];
  float std_s = s[b * 512 + 256 + c];
  float sc = std_s * inv;
  scale[b * 256 + c] = sc;
  shift[b * 256 + c] = mu_s - sc * mean;
}

// ---------------- adain apply: out_bf16 = shift + scale * in ----------------
template<int F32>
__global__ __launch_bounds__(256) void k_adain(
    const void* __restrict__ in, const float* __restrict__ scale,
    const float* __restrict__ shift, bf16* __restrict__ out) {
  int idx = blockIdx.x * 256 + threadIdx.x;
  int c8 = idx & 31, row = idx >> 5;
  int b = row >> 12, c = c8 * 8;
  const float* scp = &scale[b * 256 + c];
  const float* shp = &shift[b * 256 + c];
  f32x4 sc0 = *(const f32x4*)scp, sc1 = *(const f32x4*)(scp + 4);
  f32x4 sh0 = *(const f32x4*)shp, sh1 = *(const f32x4*)(shp + 4);
  size_t ofs = (size_t)row * 256 + c;
  float f[8];
  if constexpr (F32) {
    f32x4 v0 = *(const f32x4*)&((const float*)in)[ofs];
    f32x4 v1 = *(const f32x4*)&((const float*)in)[ofs + 4];
    f[0]=v0[0]; f[1]=v0[1]; f[2]=v0[2]; f[3]=v0[3];
    f[4]=v1[0]; f[5]=v1[1]; f[6]=v1[2]; f[7]=v1[3];
  } else {
    bf16x8v v = *(const bf16x8v*)&((const bf16*)in)[ofs];
    #pragma unroll
    for (int u = 0; u < 8; ++u) f[u] = (float)v[u];
  }
  bf16x8v o;
  o[0]=(bf16)(sh0[0]+sc0[0]*f[0]); o[1]=(bf16)(sh0[1]+sc0[1]*f[1]);
  o[2]=(bf16)(sh0[2]+sc0[2]*f[2]); o[3]=(bf16)(sh0[3]+sc0[3]*f[3]);
  o[4]=(bf16)(sh1[0]+sc1[0]*f[4]); o[5]=(bf16)(sh1[1]+sc1[1]*f[5]);
  o[6]=(bf16)(sh1[2]+sc1[2]*f[6]); o[7]=(bf16)(sh1[3]+sc1[3]*f[7]);
  *(bf16x8v*)&out[ofs] = o;
}

// ---------------- weight transpose+cvt (K x N f32) -> (N x K bf16) ----------
__global__ __launch_bounds__(256) void k_tr(
    const float* __restrict__ in, bf16* __restrict__ out, int K, int N) {
  __shared__ float t[32][33];
  int bx = blockIdx.x * 32, by = blockIdx.y * 32;
  int tx = threadIdx.x & 31, ty = threadIdx.x >> 5;
  #pragma unroll
  for (int r = 0; r < 32; r += 8)
    t[ty + r][tx] = in[(size_t)(by + ty + r) * N + bx + tx];
  __syncthreads();
  #pragma unroll
  for (int r = 0; r < 32; r += 8)
    out[(size_t)(bx + ty + r) * K + by + tx] = (bf16)t[tx][ty + r];
}

// ---------------- GEMM (8-wave 256x128): out = A@Bt^T + bias (+res,gelu) ----
// OUTMODE: 0 = bf16 row-major, 1 = f32 row-major,
//          2 = bf16 qkv-layout [(b*3+m)*8+hh][tok(4096)][32] (attention-native)
template<int RESMODE, int GELU, int OUTMODE>
__global__ __launch_bounds__(512) void k_gemm(
    const bf16* __restrict__ A, const bf16* __restrict__ Bt,
    const float* __restrict__ bias, const void* __restrict__ resv,
    void* __restrict__ outv, int N, int K, int gx) {
  __shared__ bf16 a_sw[256 * 64];   // 32 KB
  __shared__ bf16 b_sw[128 * 64];   // 16 KB
  int tid = threadIdx.x;
  int l = tid & 63, w = tid >> 6;
  int wr = w >> 1, wc = w & 1;             // 4x2 waves, 64x64 each
  int lm = l & 15, lg = l >> 4;

  int nwg = gridDim.x;
  int lin = blockIdx.x;
  int swz = (lin & 7) * (nwg >> 3) + (lin >> 3);
  int bx = swz % gx, by = swz / gx;
  int m0 = by * 256, n0 = bx * 128;

  f32x4 acc[4][4];
  #pragma unroll
  for (int mi = 0; mi < 4; ++mi)
    #pragma unroll
    for (int ni = 0; ni < 4; ++ni)
      acc[mi][ni] = (f32x4){0.f, 0.f, 0.f, 0.f};

  for (int k0 = 0; k0 < K; k0 += 64) {
    #pragma unroll
    for (int i = 0; i < 4; ++i) {
      int slot = i * 512 + tid;
      int r = slot >> 3, cs = slot & 7;
      int c = cs ^ (r & 7);                // inverse swizzle on SOURCE
      const bf16* g = A + (size_t)(m0 + r) * K + k0 + c * 8;
      __builtin_amdgcn_global_load_lds(
          (const AS1 void*)g, (AS3 void*)(a_sw + (i * 512 + w * 64) * 8),
          16, 0, 0);
    }
    #pragma unroll
    for (int i = 0; i < 2; ++i) {
      int slot = i * 512 + tid;
      int r = slot >> 3, cs = slot & 7;
      int c = cs ^ (r & 7);
      const bf16* g = Bt + (size_t)(n0 + r) * K + k0 + c * 8;
      __builtin_amdgcn_global_load_lds(
          (const AS1 void*)g, (AS3 void*)(b_sw + (i * 512 + w * 64) * 8),
          16, 0, 0);
    }
    __syncthreads();
    #pragma unroll
    for (int kk = 0; kk < 2; ++kk) {
      bf16x8v af[4], bv[4];
      #pragma unroll
      for (int mi = 0; mi < 4; ++mi) {
        int row = wr * 64 + mi * 16 + lm;
        af[mi] = *(const bf16x8v*)&a_sw[row * 64 + (((kk * 4 + lg) ^ (row & 7)) * 8)];
      }
      #pragma unroll
      for (int ni = 0; ni < 4; ++ni) {
        int row = wc * 64 + ni * 16 + lm;
        bv[ni] = *(const bf16x8v*)&b_sw[row * 64 + (((kk * 4 + lg) ^ (row & 7)) * 8)];
      }
      #pragma unroll
      for (int mi = 0; mi < 4; ++mi)
        #pragma unroll
        for (int ni = 0; ni < 4; ++ni)
          acc[mi][ni] = mfma16(af[mi], bv[ni], acc[mi][ni]);
    }
    __syncthreads();
  }
  #pragma unroll
  for (int mi = 0; mi < 4; ++mi) {
    #pragma unroll
    for (int ni = 0; ni < 4; ++ni) {
      int row = m0 + wr * 64 + mi * 16 + lg * 4;
      int col = n0 + wc * 64 + ni * 16 + lm;
      float bv_ = bias[col];
      #pragma unroll
      for (int j = 0; j < 4; ++j) {
        float o = acc[mi][ni][j] + bv_;
        if constexpr (RESMODE == 1)
          o += ((const float*)resv)[(size_t)(row + j) * N + col];
        if constexpr (RESMODE == 2)
          o += (float)((const bf16*)resv)[(size_t)(row + j) * N + col];
        if constexpr (GELU) {
          float z = 1.5957691216057308f * (o + 0.044715f * o * o * o);
          o = o / (1.0f + __expf(-z));
        }
        if constexpr (OUTMODE == 1)
          ((float*)outv)[(size_t)(row + j) * N + col] = o;
        else if constexpr (OUTMODE == 2) {
          int b  = (row + j) >> 12, tok = (row + j) & 4095;
          int m  = col >> 8, c2 = col & 255;
          int hh = c2 >> 5, ch = c2 & 31;
          size_t a_ = ((size_t)((b * 3 + m) * 8 + hh) << 17) + (tok << 5) + ch;
          ((bf16*)outv)[a_] = (bf16)o;
        } else
          ((bf16*)outv)[(size_t)(row + j) * N + col] = (bf16)o;
      }
    }
  }
}

// ---------------- GEMM (4-wave 128x128) — for small grids -------------------
template<int RESMODE, int GELU, int OUTF32>
__global__ __launch_bounds__(256) void k_gemm4(
    const bf16* __restrict__ A, const bf16* __restrict__ Bt,
    const float* __restrict__ bias, const void* __restrict__ resv,
    void* __restrict__ outv, int N, int K, int gx) {
  __shared__ bf16 a_sw[128 * 64];
  __shared__ bf16 b_sw[128 * 64];
  int tid = threadIdx.x;
  int l = tid & 63, w = tid >> 6;
  int wr = w >> 1, wc = w & 1;
  int lm = l & 15, lg = l >> 4;

  int nwg = gridDim.x;
  int lin = blockIdx.x;
  int swz = (lin & 7) * (nwg >> 3) + (lin >> 3);
  int bx = swz % gx, by = swz / gx;
  int m0 = by * 128, n0 = bx * 128;

  f32x4 acc[4][4];
  #pragma unroll
  for (int mi = 0; mi < 4; ++mi)
    #pragma unroll
    for (int ni = 0; ni < 4; ++ni)
      acc[mi][ni] = (f32x4){0.f, 0.f, 0.f, 0.f};

  for (int k0 = 0; k0 < K; k0 += 64) {
    #pragma unroll
    for (int i = 0; i < 4; ++i) {
      int slot = i * 256 + tid;
      int r = slot >> 3, cs = slot & 7;
      int c = cs ^ (r & 7);
      __builtin_amdgcn_global_load_lds(
          (const AS1 void*)(A + (size_t)(m0 + r) * K + k0 + c * 8),
          (AS3 void*)(a_sw + (i * 256 + w * 64) * 8), 16, 0, 0);
    }
    #pragma unroll
    for (int i = 0; i < 4; ++i) {
      int slot = i * 256 + tid;
      int r = slot >> 3, cs = slot & 7;
      int c = cs ^ (r & 7);
      __builtin_amdgcn_global_load_lds(
          (const AS1 void*)(Bt + (size_t)(n0 + r) * K + k0 + c * 8),
          (AS3 void*)(b_sw + (i * 256 + w * 64) * 8), 16, 0, 0);
    }
    __syncthreads();
    #pragma unroll
    for (int kk = 0; kk < 2; ++kk) {
      bf16x8v af[4], bv[4];
      #pragma unroll
      for (int mi = 0; mi < 4; ++mi) {
        int row = wr * 64 + mi * 16 + lm;
        af[mi] = *(const bf16x8v*)&a_sw[row * 64 + (((kk * 4 + lg) ^ (row & 7)) * 8)];
      }
      #pragma unroll
      for (int ni = 0; ni < 4; ++ni) {
        int row = wc * 64 + ni * 16 + lm;
        bv[ni] = *(const bf16x8v*)&b_sw[row * 64 + (((kk * 4 + lg) ^ (row & 7)) * 8)];
      }
      #pragma unroll
      for (int mi = 0; mi < 4; ++mi)
        #pragma unroll
        for (int ni = 0; ni < 4; ++ni)
          acc[mi][ni] = mfma16(af[mi], bv[ni], acc[mi][ni]);
    }
    __syncthreads();
  }
  #pragma unroll
  for (int mi = 0; mi < 4; ++mi) {
    #pragma unroll
    for (int ni = 0; ni < 4; ++ni) {
      int row = m0 + wr * 64 + mi * 16 + lg * 4;
      int col = n0 + wc * 64 + ni * 16 + lm;
      float bv_ = bias[col];
      #pragma unroll
      for (int j = 0; j < 4; ++j) {
        float o = acc[mi][ni][j] + bv_;
        if constexpr (RESMODE == 1)
          o += ((const float*)resv)[(size_t)(row + j) * N + col];
        if constexpr (RESMODE == 2)
          o += (float)((const bf16*)resv)[(size_t)(row + j) * N + col];
        if constexpr (GELU) {
          float z = 1.5957691216057308f * (o + 0.044715f * o * o * o);
          o = o / (1.0f + __expf(-z));
        }
        if constexpr (OUTF32)
          ((float*)outv)[(size_t)(row + j) * N + col] = o;
        else
          ((bf16*)outv)[(size_t)(row + j) * N + col] = (bf16)o;
      }
    }
  }
}

// ---------------- windowed attention (both branches) ------------------------
// qkv in attention-native layout [(b*3+m)*8+hh][tok][32]: Q/K fragments read
// contiguous 512B token-row runs; V staged coalesced into swizzled V^T.
__global__ __launch_bounds__(256) void k_attn(
    const bf16* __restrict__ qkv,
    const float* __restrict__ rpb1, const float* __restrict__ rpb2,
    bf16* __restrict__ aout) {
  __shared__ bf16 vt[128 * 72];   // V^T: [hh2*32+ch][token-swizzled(+pad)]
  __shared__ float rl[960];       // rpb: [h][dy][dx] stride 240/16/1

  int tid = threadIdx.x;
  int bx = blockIdx.x;
  int br = bx & 1, widx = (bx >> 1) & 63, b = bx >> 7;
  int wy = widx >> 3, wx = widx & 7;

  const float* rpb = br ? rpb2 : rpb1;
  #pragma unroll
  for (int t = tid; t < 960; t += 256) {
    int h0 = t / 240, r0 = t - h0 * 240, dy = r0 >> 4, dx = r0 & 15;
    rl[t] = (dx < 15) ? rpb[(dy * 15 + dx) * 4 + h0] : 0.f;
  }

  auto grow = [&](int tok) -> int {
    int y = wy * 8 + (tok >> 3), xc = wx * 8 + (tok & 7);
    if (br) { y = (y + 4) & 63; xc = (xc + 4) & 63; }
    return y * 64 + xc;                  // in-batch token index
  };

  auto plane = [&](int m, int hh2) -> size_t {
    return (size_t)((b * 3 + m) * 8 + br * 4 + hh2) << 17;
  };

  // stage V transposed: task = tok*16 + c; c = hh2*4 + ch8
  #pragma unroll
  for (int it = 0; it < 4; ++it) {
    int task = it * 256 + tid;
    int tok = task >> 4, c = task & 15;
    int hh2 = c >> 2, ch8 = c & 3;
    bf16x8v v = *(const bf16x8v*)&qkv[plane(2, hh2) + (grow(tok) << 5) + ch8 * 8];
    int tsw = tok ^ ((c & 7) << 3);      // bank-spread swizzle (involution)
    #pragma unroll
    for (int u = 0; u < 8; ++u) vt[(c * 8 + u) * 72 + tsw] = v[u];
  }

  int l = tid & 63, h = tid >> 6;
  int lm = l & 15, lg = l >> 4;

  // Q/K frags: token rows are 64B; 16 toks = 2 contiguous 512B runs
  bf16x8v kb[4], qa[4];
  size_t pq = plane(0, h), pk = plane(1, h);
  #pragma unroll
  for (int i = 0; i < 4; ++i) {
    int t = grow(i * 16 + lm);
    qa[i] = *(const bf16x8v*)&qkv[pq + (t << 5) + lg * 8];
    kb[i] = *(const bf16x8v*)&qkv[pk + (t << 5) + lg * 8];
  }
  __syncthreads();   // vt + rl ready

  bf16x4v vb[2][4];
  #pragma unroll
  for (int ni = 0; ni < 2; ++ni)
    #pragma unroll
    for (int ki = 0; ki < 4; ++ki) {
      int row = h * 32 + ni * 16 + lm;
      int col = (ki * 16 + lg * 4) ^ (((row >> 3) & 7) << 3);
      vb[ni][ki] = *(const bf16x4v*)&vt[row * 72 + col];
    }

  bool need_mask = br && (wy == 7 || wx == 7);

  int ekA[16], idkA[16];
  #pragma unroll
  for (int ki = 0; ki < 4; ++ki)
    #pragma unroll
    for (int j = 0; j < 4; ++j) {
      int ik = ki * 16 + lg * 4 + j;
      ekA[ki * 4 + j] = ik + (ik >> 3) * 8;
      int yk = wy * 8 + (ik >> 3), xk = wx * 8 + (ik & 7);
      idkA[ki * 4 + j] = (yk < 56 ? 0 : (yk < 60 ? 1 : 2)) * 3
                       + (xk < 56 ? 0 : (xk < 60 ? 1 : 2));
    }

  #pragma unroll
  for (int qi = 0; qi < 4; ++qi) {
    f32x4 s[4];
    #pragma unroll
    for (int ki = 0; ki < 4; ++ki)
      s[ki] = mfma16(kb[ki], qa[qi], (f32x4){0.f,0.f,0.f,0.f});

    int iq = qi * 16 + lm;
    int eq = iq + (iq >> 3) * 8;
    int yq = wy * 8 + (iq >> 3), xq = wx * 8 + (iq & 7);
    int idq = (yq < 56 ? 0 : (yq < 60 ? 1 : 2)) * 3
            + (xq < 56 ? 0 : (xq < 60 ? 1 : 2));
    const float* fb = &rl[h * 240 + 119 + eq];

    #pragma unroll
    for (int ki = 0; ki < 4; ++ki)
      #pragma unroll
      for (int j = 0; j < 4; ++j) {
        float val = s[ki][j] * 0.17677669529663687f + fb[-ekA[ki * 4 + j]];
        if (need_mask && idq != idkA[ki * 4 + j]) val -= 100.0f;
        s[ki][j] = val;
      }

    float mx = s[0][0];
    #pragma unroll
    for (int ki = 0; ki < 4; ++ki)
      #pragma unroll
      for (int j = 0; j < 4; ++j) mx = fmaxf(mx, s[ki][j]);
    mx = fmaxf(mx, __shfl_xor(mx, 16));
    mx = fmaxf(mx, __shfl_xor(mx, 32));
    float sum = 0.f;
    #pragma unroll
    for (int ki = 0; ki < 4; ++ki)
      #pragma unroll
      for (int j = 0; j < 4; ++j) {
        float e = __expf(s[ki][j] - mx);
        s[ki][j] = e;
        sum += e;
      }
    sum += __shfl_xor(sum, 16);
    sum += __shfl_xor(sum, 32);
    float rs = 1.0f / sum;

    bf16x4v pa[4];
    #pragma unroll
    for (int ki = 0; ki < 4; ++ki)
      #pragma unroll
      for (int j = 0; j < 4; ++j)
        pa[ki][j] = (bf16)(s[ki][j] * rs);

    f32x4 o[2] = {(f32x4){0.f,0.f,0.f,0.f}, (f32x4){0.f,0.f,0.f,0.f}};
    #pragma unroll
    for (int ki = 0; ki < 4; ++ki) {
      o[0] = mfma16x16(pa[ki], vb[0][ki], o[0]);
      o[1] = mfma16x16(pa[ki], vb[1][ki], o[1]);
    }

    #pragma unroll
    for (int ni = 0; ni < 2; ++ni)
      #pragma unroll
      for (int j = 0; j < 4; ++j) {
        int tok = qi * 16 + lg * 4 + j;
        int col = br * 128 + h * 32 + ni * 16 + lm;
        aout[((size_t)b * 4096 + grow(tok)) * 256 + col] = (bf16)o[ni][j];
      }
  }
}

// ---------------- host ------------------------------------------------------
extern "C" void kernel_launch(void* const* d_in, const int* in_sizes, int n_in,
                              void* d_out, int out_size, void* d_ws, size_t ws_size,
                              hipStream_t stream) {
  (void)in_sizes; (void)n_in; (void)out_size; (void)ws_size;
  const float* x      = (const float*)d_in[0];
  const float* style  = (const float*)d_in[1];
  const float* w_qkv  = (const float*)d_in[2];
  const float* b_qkv  = (const float*)d_in[3];
  const float* w_proj = (const float*)d_in[4];
  const float* b_proj = (const float*)d_in[5];
  const float* w_ada1 = (const float*)d_in[6];
  const float* b_ada1 = (const float*)d_in[7];
  const float* w_ada2 = (const float*)d_in[8];
  const float* b_ada2 = (const float*)d_in[9];
  const float* rpb1   = (const float*)d_in[10];
  const float* rpb2   = (const float*)d_in[11];
  const float* w_fc1  = (const float*)d_in[12];
  const float* b_fc1  = (const float*)d_in[13];
  const float* w_fc2  = (const float*)d_in[14];
  const float* b_fc2  = (const float*)d_in[15];

  char* ws = (char*)d_ws;
  float* s1     = (float*)(ws + 0);
  float* s2     = (float*)(ws + 32768);
  float* scale1 = (float*)(ws + 65536);
  float* shift1 = (float*)(ws + 81920);
  float* scale2 = (float*)(ws + 98304);
  float* shift2 = (float*)(ws + 114688);
  bf16* wtqkv   = (bf16*)(ws + 131072);            // 768x256 bf16
  bf16* wtproj  = (bf16*)(ws + 524288);            // 256x256
  bf16* wtfc1   = (bf16*)(ws + 655360);            // 1024x256
  bf16* wtfc2   = (bf16*)(ws + 1179648);           // 256x1024
  float* psum   = (float*)(ws + 1703936);          // 16*16*256 f32
  float* psq    = (float*)(ws + 1966080);
  const size_t BIG = 2228224;
  bf16* xn   = (bf16*)(ws + BIG);                  // 65536x256 bf16 (33.5MB)
  bf16* qkv  = (bf16*)(ws + BIG + 33554432);       // 384 planes x 4096 x 32
  bf16* attn = (bf16*)(ws + BIG + 134217728);      // 65536x256 bf16 (33.5MB)
  bf16* x1   = (bf16*)(ws + BIG + 33554432);       // overlays qkv head
  bf16* xn2  = xn;                                 // reuses xn slot
  bf16* g    = (bf16*)(ws + BIG + 67108864);       // 32768x1024 chunk, qkv tail

  // weight transposes (f32 -> bf16)
  k_tr<<<dim3(24, 8),  256, 0, stream>>>(w_qkv,  wtqkv,  256, 768);
  k_tr<<<dim3(8, 8),   256, 0, stream>>>(w_proj, wtproj, 256, 256);
  k_tr<<<dim3(32, 8),  256, 0, stream>>>(w_fc1,  wtfc1,  256, 1024);
  k_tr<<<dim3(8, 32),  256, 0, stream>>>(w_fc2,  wtfc2,  1024, 256);

  // style projections, adain1 params, adain1 apply
  k_style<<<1024, 256, 0, stream>>>(style, w_ada1, b_ada1, w_ada2, b_ada2, s1, s2);
  k_stats_part<1><<<dim3(16, 16), 256, 0, stream>>>(x, psum, psq);
  k_stats_fin<<<16, 256, 0, stream>>>(psum, psq, s1, scale1, shift1);
  k_adain<1><<<8192, 256, 0, stream>>>(x, scale1, shift1, xn);

  // qkv = xn @ w_qkv + b_qkv  (attention-native output layout)
  k_gemm<0,0,2><<<1536, 512, 0, stream>>>(
      xn, wtqkv, b_qkv, nullptr, qkv, 768, 256, 6);

  // windowed attention (both branches)
  k_attn<<<2048, 256, 0, stream>>>(qkv, rpb1, rpb2, attn);

  // x1 = x + attn @ w_proj + b_proj   (128x128: 512 x 2 = 1024)
  k_gemm4<1,0,0><<<1024, 256, 0, stream>>>(
      attn, wtproj, b_proj, x, x1, 256, 256, 2);

  // adain2 params + apply
  k_stats_part<0><<<dim3(16, 16), 256, 0, stream>>>(x1, psum, psq);
  k_stats_fin<<<16, 256, 0, stream>>>(psum, psq, s2, scale2, shift2);
  k_adain<0><<<8192, 256, 0, stream>>>(x1, scale2, shift2, xn2);

  // MLP in 2 row-chunks of 32768 (g reuses dead qkv tail region)
  for (int ch = 0; ch < 2; ++ch) {
    size_t ro = (size_t)ch * 32768;
    // g = gelu(xn2 @ w_fc1 + b_fc1)   (256x128: 128 x 8 = 1024)
    k_gemm<0,1,0><<<1024, 512, 0, stream>>>(
        xn2 + ro * 256, wtfc1, b_fc1, nullptr, g, 1024, 256, 8);
    // out = x1 + g @ w_fc2 + b_fc2    (128x128: 256 x 2 = 512)
    k_gemm4<2,0,1><<<512, 256, 0, stream>>>(
        g, wtfc2, b_fc2, x1 + ro * 256,
        (float*)d_out + ro * 256, 256, 1024, 2);
  }
}

// Round 17
// 308.149 us; speedup vs baseline: 1.1101x; 1.0453x over previous
//
#include <hip/hip_runtime.h>
#include <hip/hip_bf16.h>

typedef __bf16 bf16;
typedef __bf16 bf16x4v __attribute__((ext_vector_type(4)));
typedef __bf16 bf16x8v __attribute__((ext_vector_type(8)));
typedef float f32x4 __attribute__((ext_vector_type(4)));
typedef short s16x4 __attribute__((ext_vector_type(4)));

#define DEVINL static __device__ __forceinline__
#define AS1 __attribute__((address_space(1)))
#define AS3 __attribute__((address_space(3)))

DEVINL f32x4 mfma16(bf16x8v a, bf16x8v b, f32x4 c) {
  return __builtin_amdgcn_mfma_f32_16x16x32_bf16(a, b, c, 0, 0, 0);
}

DEVINL f32x4 mfma16x16(bf16x4v a, bf16x4v b, f32x4 c) {
#if __has_builtin(__builtin_amdgcn_mfma_f32_16x16x16bf16_1k)
  return __builtin_amdgcn_mfma_f32_16x16x16bf16_1k(
      __builtin_bit_cast(s16x4, a), __builtin_bit_cast(s16x4, b), c, 0, 0, 0);
#else
  f32x4 d;
  asm("v_mfma_f32_16x16x16_bf16 %0, %1, %2, %3"
      : "=v"(d) : "v"(a), "v"(b), "v"(c));
  return d;
#endif
}

// ---------------- style projections: s = style @ w_ada + b_ada (f32) --------
__global__ __launch_bounds__(256) void k_style(
    const float* __restrict__ style,
    const float* __restrict__ wa1, const float* __restrict__ ba1,
    const float* __restrict__ wa2, const float* __restrict__ ba2,
    float* __restrict__ s1, float* __restrict__ s2) {
  int bid = blockIdx.x;
  int ng = bid & 31, b = (bid >> 5) & 15, which = bid >> 9;
  int tid = threadIdx.x;
  int nl = tid & 15, kg = tid >> 4;
  int n = ng * 16 + nl;
  const float* wa = which ? wa2 : wa1;
  const float* ba = which ? ba2 : ba1;
  const float* srow = style + b * 512;
  float acc = 0.f;
  #pragma unroll 8
  for (int kk = 0; kk < 32; ++kk) {
    int k = kg + kk * 16;
    acc += srow[k] * wa[k * 512 + n];
  }
  acc += __shfl_xor(acc, 16);
  acc += __shfl_xor(acc, 32);
  __shared__ float red[4][16];
  int w = tid >> 6;
  if ((tid & 63) < 16) red[w][nl] = acc;
  __syncthreads();
  if (tid < 16) {
    float S = red[0][tid] + red[1][tid] + red[2][tid] + red[3][tid]
            + ba[ng * 16 + tid];
    (which ? s2 : s1)[b * 512 + ng * 16 + tid] = S;
  }
}

// ---------------- stats pass 1: per (b, row-chunk) partial sum/sumsq --------
template<int F32>
__global__ __launch_bounds__(256) void k_stats_part(
    const void* __restrict__ xv, float* __restrict__ psum,
    float* __restrict__ psq) {
  int rc = blockIdx.x, b = blockIdx.y;
  int c = threadIdx.x;
  size_t base = (size_t)b * 4096 * 256 + (size_t)rc * 256 * 256 + c;
  float sm = 0.f, q = 0.f;
  #pragma unroll 4
  for (int r = 0; r < 256; ++r) {
    float f;
    if constexpr (F32) f = ((const float*)xv)[base + (size_t)r * 256];
    else               f = (float)((const bf16*)xv)[base + (size_t)r * 256];
    sm += f; q += f * f;
  }
  int o = (b * 16 + rc) * 256 + c;
  psum[o] = sm; psq[o] = q;
}

// ---------------- stats pass 2: combine + adain scale/shift -----------------
__global__ __launch_bounds__(256) void k_stats_fin(
    const float* __restrict__ psum, const float* __restrict__ psq,
    const float* __restrict__ s,
    float* __restrict__ scale, float* __restrict__ shift) {
  int b = blockIdx.x, c = threadIdx.x;
  float S = 0.f, Q = 0.f;
  #pragma unroll
  for (int rc = 0; rc < 16; ++rc) {
    S += psum[(b * 16 + rc) * 256 + c];
    Q += psq[(b * 16 + rc) * 256 + c];
  }
  float mean = S * (1.0f/4096.0f);
  float var  = Q * (1.0f/4096.0f) - mean * mean;
  float inv  = rsqrtf(var + 1e-5f);
  float mu_s  = s[b * 512 + c];
  float std_s = s[b * 512 + 256 + c];
  float sc = std_s * inv;
  scale[b * 256 + c] = sc;
  shift[b * 256 + c] = mu_s - sc * mean;
}

// ---------------- stats fin from proj-epilogue partials (32 per (b,c)) ------
__global__ __launch_bounds__(256) void k_stats_fin2(
    const float* __restrict__ pS, const float* __restrict__ pQ,
    const float* __restrict__ s,
    float* __restrict__ scale, float* __restrict__ shift) {
  int b = blockIdx.x, c = threadIdx.x;
  float S = 0.f, Q = 0.f;
  #pragma unroll 8
  for (int i = 0; i < 32; ++i) {
    S += pS[(b * 32 + i) * 256 + c];
    Q += pQ[(b * 32 + i) * 256 + c];
  }
  float mean = S * (1.0f/4096.0f);
  float var  = Q * (1.0f/4096.0f) - mean * mean;
  float inv  = rsqrtf(var + 1e-5f);
  float mu_s  = s[b * 512 + c];
  float std_s = s[b * 512 + 256 + c];
  float sc = std_s * inv;
  scale[b * 256 + c] = sc;
  shift[b * 256 + c] = mu_s - sc * mean;
}

// ---------------- adain apply: out_bf16 = shift + scale * in ----------------
template<int F32>
__global__ __launch_bounds__(256) void k_adain(
    const void* __restrict__ in, const float* __restrict__ scale,
    const float* __restrict__ shift, bf16* __restrict__ out) {
  int idx = blockIdx.x * 256 + threadIdx.x;
  int c8 = idx & 31, row = idx >> 5;
  int b = row >> 12, c = c8 * 8;
  const float* scp = &scale[b * 256 + c];
  const float* shp = &shift[b * 256 + c];
  f32x4 sc0 = *(const f32x4*)scp, sc1 = *(const f32x4*)(scp + 4);
  f32x4 sh0 = *(const f32x4*)shp, sh1 = *(const f32x4*)(shp + 4);
  size_t ofs = (size_t)row * 256 + c;
  float f[8];
  if constexpr (F32) {
    f32x4 v0 = *(const f32x4*)&((const float*)in)[ofs];
    f32x4 v1 = *(const f32x4*)&((const float*)in)[ofs + 4];
    f[0]=v0[0]; f[1]=v0[1]; f[2]=v0[2]; f[3]=v0[3];
    f[4]=v1[0]; f[5]=v1[1]; f[6]=v1[2]; f[7]=v1[3];
  } else {
    bf16x8v v = *(const bf16x8v*)&((const bf16*)in)[ofs];
    #pragma unroll
    for (int u = 0; u < 8; ++u) f[u] = (float)v[u];
  }
  bf16x8v o;
  o[0]=(bf16)(sh0[0]+sc0[0]*f[0]); o[1]=(bf16)(sh0[1]+sc0[1]*f[1]);
  o[2]=(bf16)(sh0[2]+sc0[2]*f[2]); o[3]=(bf16)(sh0[3]+sc0[3]*f[3]);
  o[4]=(bf16)(sh1[0]+sc1[0]*f[4]); o[5]=(bf16)(sh1[1]+sc1[1]*f[5]);
  o[6]=(bf16)(sh1[2]+sc1[2]*f[6]); o[7]=(bf16)(sh1[3]+sc1[3]*f[7]);
  *(bf16x8v*)&out[ofs] = o;
}

// ---------------- weight transpose+cvt (K x N f32) -> (N x K bf16) ----------
__global__ __launch_bounds__(256) void k_tr(
    const float* __restrict__ in, bf16* __restrict__ out, int K, int N) {
  __shared__ float t[32][33];
  int bx = blockIdx.x * 32, by = blockIdx.y * 32;
  int tx = threadIdx.x & 31, ty = threadIdx.x >> 5;
  #pragma unroll
  for (int r = 0; r < 32; r += 8)
    t[ty + r][tx] = in[(size_t)(by + ty + r) * N + bx + tx];
  __syncthreads();
  #pragma unroll
  for (int r = 0; r < 32; r += 8)
    out[(size_t)(bx + ty + r) * K + by + tx] = (bf16)t[tx][ty + r];
}

// ---------------- GEMM (8-wave 256x128): out = A@Bt^T + bias (+res,gelu) ----
// OUTMODE: 0 = bf16 row-major, 1 = f32 row-major,
//          2 = bf16 qkv-layout [(b*3+m)*8+hh][tok(4096)][32] (attention-native)
template<int RESMODE, int GELU, int OUTMODE>
__global__ __launch_bounds__(512) void k_gemm(
    const bf16* __restrict__ A, const bf16* __restrict__ Bt,
    const float* __restrict__ bias, const void* __restrict__ resv,
    void* __restrict__ outv, int N, int K, int gx) {
  __shared__ bf16 a_sw[256 * 64];   // 32 KB
  __shared__ bf16 b_sw[128 * 64];   // 16 KB
  int tid = threadIdx.x;
  int l = tid & 63, w = tid >> 6;
  int wr = w >> 1, wc = w & 1;             // 4x2 waves, 64x64 each
  int lm = l & 15, lg = l >> 4;

  int nwg = gridDim.x;
  int lin = blockIdx.x;
  int swz = (lin & 7) * (nwg >> 3) + (lin >> 3);
  int bx = swz % gx, by = swz / gx;
  int m0 = by * 256, n0 = bx * 128;

  f32x4 acc[4][4];
  #pragma unroll
  for (int mi = 0; mi < 4; ++mi)
    #pragma unroll
    for (int ni = 0; ni < 4; ++ni)
      acc[mi][ni] = (f32x4){0.f, 0.f, 0.f, 0.f};

  for (int k0 = 0; k0 < K; k0 += 64) {
    #pragma unroll
    for (int i = 0; i < 4; ++i) {
      int slot = i * 512 + tid;
      int r = slot >> 3, cs = slot & 7;
      int c = cs ^ (r & 7);                // inverse swizzle on SOURCE
      const bf16* g = A + (size_t)(m0 + r) * K + k0 + c * 8;
      __builtin_amdgcn_global_load_lds(
          (const AS1 void*)g, (AS3 void*)(a_sw + (i * 512 + w * 64) * 8),
          16, 0, 0);
    }
    #pragma unroll
    for (int i = 0; i < 2; ++i) {
      int slot = i * 512 + tid;
      int r = slot >> 3, cs = slot & 7;
      int c = cs ^ (r & 7);
      const bf16* g = Bt + (size_t)(n0 + r) * K + k0 + c * 8;
      __builtin_amdgcn_global_load_lds(
          (const AS1 void*)g, (AS3 void*)(b_sw + (i * 512 + w * 64) * 8),
          16, 0, 0);
    }
    __syncthreads();
    #pragma unroll
    for (int kk = 0; kk < 2; ++kk) {
      bf16x8v af[4], bv[4];
      #pragma unroll
      for (int mi = 0; mi < 4; ++mi) {
        int row = wr * 64 + mi * 16 + lm;
        af[mi] = *(const bf16x8v*)&a_sw[row * 64 + (((kk * 4 + lg) ^ (row & 7)) * 8)];
      }
      #pragma unroll
      for (int ni = 0; ni < 4; ++ni) {
        int row = wc * 64 + ni * 16 + lm;
        bv[ni] = *(const bf16x8v*)&b_sw[row * 64 + (((kk * 4 + lg) ^ (row & 7)) * 8)];
      }
      #pragma unroll
      for (int mi = 0; mi < 4; ++mi)
        #pragma unroll
        for (int ni = 0; ni < 4; ++ni)
          acc[mi][ni] = mfma16(af[mi], bv[ni], acc[mi][ni]);
    }
    __syncthreads();
  }
  #pragma unroll
  for (int mi = 0; mi < 4; ++mi) {
    #pragma unroll
    for (int ni = 0; ni < 4; ++ni) {
      int row = m0 + wr * 64 + mi * 16 + lg * 4;
      int col = n0 + wc * 64 + ni * 16 + lm;
      float bv_ = bias[col];
      #pragma unroll
      for (int j = 0; j < 4; ++j) {
        float o = acc[mi][ni][j] + bv_;
        if constexpr (RESMODE == 1)
          o += ((const float*)resv)[(size_t)(row + j) * N + col];
        if constexpr (RESMODE == 2)
          o += (float)((const bf16*)resv)[(size_t)(row + j) * N + col];
        if constexpr (GELU) {
          float z = 1.5957691216057308f * (o + 0.044715f * o * o * o);
          o = o / (1.0f + __expf(-z));
        }
        if constexpr (OUTMODE == 1)
          ((float*)outv)[(size_t)(row + j) * N + col] = o;
        else if constexpr (OUTMODE == 2) {
          int b  = (row + j) >> 12, tok = (row + j) & 4095;
          int m  = col >> 8, c2 = col & 255;
          int hh = c2 >> 5, ch = c2 & 31;
          size_t a_ = ((size_t)((b * 3 + m) * 8 + hh) << 17) + (tok << 5) + ch;
          ((bf16*)outv)[a_] = (bf16)o;
        } else
          ((bf16*)outv)[(size_t)(row + j) * N + col] = (bf16)o;
      }
    }
  }
}

// ---------------- GEMM (4-wave 128x128) — for small grids -------------------
// STATS: emit per-block column partial sum/sumsq of the bf16-rounded output
// (deterministic: each (by,col) written exactly once; LDS-tree reduction).
template<int RESMODE, int GELU, int OUTF32, int STATS>
__global__ __launch_bounds__(256) void k_gemm4(
    const bf16* __restrict__ A, const bf16* __restrict__ Bt,
    const float* __restrict__ bias, const void* __restrict__ resv,
    void* __restrict__ outv, int N, int K, int gx,
    float* __restrict__ pS, float* __restrict__ pQ) {
  __shared__ bf16 a_sw[128 * 64];
  __shared__ bf16 b_sw[128 * 64];
  int tid = threadIdx.x;
  int l = tid & 63, w = tid >> 6;
  int wr = w >> 1, wc = w & 1;
  int lm = l & 15, lg = l >> 4;

  int nwg = gridDim.x;
  int lin = blockIdx.x;
  int swz = (lin & 7) * (nwg >> 3) + (lin >> 3);
  int bx = swz % gx, by = swz / gx;
  int m0 = by * 128, n0 = bx * 128;

  f32x4 acc[4][4];
  #pragma unroll
  for (int mi = 0; mi < 4; ++mi)
    #pragma unroll
    for (int ni = 0; ni < 4; ++ni)
      acc[mi][ni] = (f32x4){0.f, 0.f, 0.f, 0.f};

  for (int k0 = 0; k0 < K; k0 += 64) {
    #pragma unroll
    for (int i = 0; i < 4; ++i) {
      int slot = i * 256 + tid;
      int r = slot >> 3, cs = slot & 7;
      int c = cs ^ (r & 7);
      __builtin_amdgcn_global_load_lds(
          (const AS1 void*)(A + (size_t)(m0 + r) * K + k0 + c * 8),
          (AS3 void*)(a_sw + (i * 256 + w * 64) * 8), 16, 0, 0);
    }
    #pragma unroll
    for (int i = 0; i < 4; ++i) {
      int slot = i * 256 + tid;
      int r = slot >> 3, cs = slot & 7;
      int c = cs ^ (r & 7);
      __builtin_amdgcn_global_load_lds(
          (const AS1 void*)(Bt + (size_t)(n0 + r) * K + k0 + c * 8),
          (AS3 void*)(b_sw + (i * 256 + w * 64) * 8), 16, 0, 0);
    }
    __syncthreads();
    #pragma unroll
    for (int kk = 0; kk < 2; ++kk) {
      bf16x8v af[4], bv[4];
      #pragma unroll
      for (int mi = 0; mi < 4; ++mi) {
        int row = wr * 64 + mi * 16 + lm;
        af[mi] = *(const bf16x8v*)&a_sw[row * 64 + (((kk * 4 + lg) ^ (row & 7)) * 8)];
      }
      #pragma unroll
      for (int ni = 0; ni < 4; ++ni) {
        int row = wc * 64 + ni * 16 + lm;
        bv[ni] = *(const bf16x8v*)&b_sw[row * 64 + (((kk * 4 + lg) ^ (row & 7)) * 8)];
      }
      #pragma unroll
      for (int mi = 0; mi < 4; ++mi)
        #pragma unroll
        for (int ni = 0; ni < 4; ++ni)
          acc[mi][ni] = mfma16(af[mi], bv[ni], acc[mi][ni]);
    }
    __syncthreads();
  }

  float sl[4] = {0.f, 0.f, 0.f, 0.f};
  float sq[4] = {0.f, 0.f, 0.f, 0.f};
  #pragma unroll
  for (int mi = 0; mi < 4; ++mi) {
    #pragma unroll
    for (int ni = 0; ni < 4; ++ni) {
      int row = m0 + wr * 64 + mi * 16 + lg * 4;
      int col = n0 + wc * 64 + ni * 16 + lm;
      float bv_ = bias[col];
      #pragma unroll
      for (int j = 0; j < 4; ++j) {
        float o = acc[mi][ni][j] + bv_;
        if constexpr (RESMODE == 1)
          o += ((const float*)resv)[(size_t)(row + j) * N + col];
        if constexpr (RESMODE == 2)
          o += (float)((const bf16*)resv)[(size_t)(row + j) * N + col];
        if constexpr (GELU) {
          float z = 1.5957691216057308f * (o + 0.044715f * o * o * o);
          o = o / (1.0f + __expf(-z));
        }
        if constexpr (OUTF32)
          ((float*)outv)[(size_t)(row + j) * N + col] = o;
        else
          ((bf16*)outv)[(size_t)(row + j) * N + col] = (bf16)o;
        if constexpr (STATS) {
          float ob = (float)(bf16)o;       // match bf16-x1 stats numerics
          sl[ni] += ob;
          sq[ni] += ob * ob;
        }
      }
    }
  }

  if constexpr (STATS) {
    // reduce 8 contributors (wr x lg) per column via LDS (reuse dead a_sw)
    float* red = (float*)a_sw;             // 2048 f32 = 8 KB
    #pragma unroll
    for (int ni = 0; ni < 4; ++ni) {
      int g = (wc * 4 + ni) * 16 + lm;     // == col_local = wc*64+ni*16+lm
      red[g * 8 + wr * 4 + lg] = sl[ni];
      red[1024 + g * 8 + wr * 4 + lg] = sq[ni];
    }
    __syncthreads();
    if (tid < 128) {
      float S = 0.f, Q = 0.f;
      #pragma unroll
      for (int u = 0; u < 8; ++u) {
        S += red[tid * 8 + u];
        Q += red[1024 + tid * 8 + u];
      }
      pS[by * 256 + bx * 128 + tid] = S;
      pQ[by * 256 + bx * 128 + tid] = Q;
    }
  }
}

// ---------------- windowed attention (both branches) ------------------------
// qkv in attention-native layout [(b*3+m)*8+hh][tok][32]: Q/K fragments read
// contiguous 512B token-row runs; V staged coalesced into swizzled V^T.
__global__ __launch_bounds__(256) void k_attn(
    const bf16* __restrict__ qkv,
    const float* __restrict__ rpb1, const float* __restrict__ rpb2,
    bf16* __restrict__ aout) {
  __shared__ bf16 vt[128 * 72];   // V^T: [hh2*32+ch][token-swizzled(+pad)]
  __shared__ float rl[960];       // rpb: [h][dy][dx] stride 240/16/1

  int tid = threadIdx.x;
  int bx = blockIdx.x;
  int br = bx & 1, widx = (bx >> 1) & 63, b = bx >> 7;
  int wy = widx >> 3, wx = widx & 7;

  const float* rpb = br ? rpb2 : rpb1;
  #pragma unroll
  for (int t = tid; t < 960; t += 256) {
    int h0 = t / 240, r0 = t - h0 * 240, dy = r0 >> 4, dx = r0 & 15;
    rl[t] = (dx < 15) ? rpb[(dy * 15 + dx) * 4 + h0] : 0.f;
  }

  auto grow = [&](int tok) -> int {
    int y = wy * 8 + (tok >> 3), xc = wx * 8 + (tok & 7);
    if (br) { y = (y + 4) & 63; xc = (xc + 4) & 63; }
    return y * 64 + xc;                  // in-batch token index
  };

  auto plane = [&](int m, int hh2) -> size_t {
    return (size_t)((b * 3 + m) * 8 + br * 4 + hh2) << 17;
  };

  // stage V transposed: task = tok*16 + c; c = hh2*4 + ch8
  #pragma unroll
  for (int it = 0; it < 4; ++it) {
    int task = it * 256 + tid;
    int tok = task >> 4, c = task & 15;
    int hh2 = c >> 2, ch8 = c & 3;
    bf16x8v v = *(const bf16x8v*)&qkv[plane(2, hh2) + (grow(tok) << 5) + ch8 * 8];
    int tsw = tok ^ ((c & 7) << 3);      // bank-spread swizzle (involution)
    #pragma unroll
    for (int u = 0; u < 8; ++u) vt[(c * 8 + u) * 72 + tsw] = v[u];
  }

  int l = tid & 63, h = tid >> 6;
  int lm = l & 15, lg = l >> 4;

  // Q/K frags: token rows are 64B; 16 toks = 2 contiguous 512B runs
  bf16x8v kb[4], qa[4];
  size_t pq = plane(0, h), pk = plane(1, h);
  #pragma unroll
  for (int i = 0; i < 4; ++i) {
    int t = grow(i * 16 + lm);
    qa[i] = *(const bf16x8v*)&qkv[pq + (t << 5) + lg * 8];
    kb[i] = *(const bf16x8v*)&qkv[pk + (t << 5) + lg * 8];
  }
  __syncthreads();   // vt + rl ready

  bf16x4v vb[2][4];
  #pragma unroll
  for (int ni = 0; ni < 2; ++ni)
    #pragma unroll
    for (int ki = 0; ki < 4; ++ki) {
      int row = h * 32 + ni * 16 + lm;
      int col = (ki * 16 + lg * 4) ^ (((row >> 3) & 7) << 3);
      vb[ni][ki] = *(const bf16x4v*)&vt[row * 72 + col];
    }

  bool need_mask = br && (wy == 7 || wx == 7);

  int ekA[16], idkA[16];
  #pragma unroll
  for (int ki = 0; ki < 4; ++ki)
    #pragma unroll
    for (int j = 0; j < 4; ++j) {
      int ik = ki * 16 + lg * 4 + j;
      ekA[ki * 4 + j] = ik + (ik >> 3) * 8;
      int yk = wy * 8 + (ik >> 3), xk = wx * 8 + (ik & 7);
      idkA[ki * 4 + j] = (yk < 56 ? 0 : (yk < 60 ? 1 : 2)) * 3
                       + (xk < 56 ? 0 : (xk < 60 ? 1 : 2));
    }

  #pragma unroll
  for (int qi = 0; qi < 4; ++qi) {
    f32x4 s[4];
    #pragma unroll
    for (int ki = 0; ki < 4; ++ki)
      s[ki] = mfma16(kb[ki], qa[qi], (f32x4){0.f,0.f,0.f,0.f});

    int iq = qi * 16 + lm;
    int eq = iq + (iq >> 3) * 8;
    int yq = wy * 8 + (iq >> 3), xq = wx * 8 + (iq & 7);
    int idq = (yq < 56 ? 0 : (yq < 60 ? 1 : 2)) * 3
            + (xq < 56 ? 0 : (xq < 60 ? 1 : 2));
    const float* fb = &rl[h * 240 + 119 + eq];

    #pragma unroll
    for (int ki = 0; ki < 4; ++ki)
      #pragma unroll
      for (int j = 0; j < 4; ++j) {
        float val = s[ki][j] * 0.17677669529663687f + fb[-ekA[ki * 4 + j]];
        if (need_mask && idq != idkA[ki * 4 + j]) val -= 100.0f;
        s[ki][j] = val;
      }

    float mx = s[0][0];
    #pragma unroll
    for (int ki = 0; ki < 4; ++ki)
      #pragma unroll
      for (int j = 0; j < 4; ++j) mx = fmaxf(mx, s[ki][j]);
    mx = fmaxf(mx, __shfl_xor(mx, 16));
    mx = fmaxf(mx, __shfl_xor(mx, 32));
    float sum = 0.f;
    #pragma unroll
    for (int ki = 0; ki < 4; ++ki)
      #pragma unroll
      for (int j = 0; j < 4; ++j) {
        float e = __expf(s[ki][j] - mx);
        s[ki][j] = e;
        sum += e;
      }
    sum += __shfl_xor(sum, 16);
    sum += __shfl_xor(sum, 32);
    float rs = 1.0f / sum;

    bf16x4v pa[4];
    #pragma unroll
    for (int ki = 0; ki < 4; ++ki)
      #pragma unroll
      for (int j = 0; j < 4; ++j)
        pa[ki][j] = (bf16)(s[ki][j] * rs);

    f32x4 o[2] = {(f32x4){0.f,0.f,0.f,0.f}, (f32x4){0.f,0.f,0.f,0.f}};
    #pragma unroll
    for (int ki = 0; ki < 4; ++ki) {
      o[0] = mfma16x16(pa[ki], vb[0][ki], o[0]);
      o[1] = mfma16x16(pa[ki], vb[1][ki], o[1]);
    }

    #pragma unroll
    for (int ni = 0; ni < 2; ++ni)
      #pragma unroll
      for (int j = 0; j < 4; ++j) {
        int tok = qi * 16 + lg * 4 + j;
        int col = br * 128 + h * 32 + ni * 16 + lm;
        aout[((size_t)b * 4096 + grow(tok)) * 256 + col] = (bf16)o[ni][j];
      }
  }
}

// ---------------- host ------------------------------------------------------
extern "C" void kernel_launch(void* const* d_in, const int* in_sizes, int n_in,
                              void* d_out, int out_size, void* d_ws, size_t ws_size,
                              hipStream_t stream) {
  (void)in_sizes; (void)n_in; (void)out_size; (void)ws_size;
  const float* x      = (const float*)d_in[0];
  const float* style  = (const float*)d_in[1];
  const float* w_qkv  = (const float*)d_in[2];
  const float* b_qkv  = (const float*)d_in[3];
  const float* w_proj = (const float*)d_in[4];
  const float* b_proj = (const float*)d_in[5];
  const float* w_ada1 = (const float*)d_in[6];
  const float* b_ada1 = (const float*)d_in[7];
  const float* w_ada2 = (const float*)d_in[8];
  const float* b_ada2 = (const float*)d_in[9];
  const float* rpb1   = (const float*)d_in[10];
  const float* rpb2   = (const float*)d_in[11];
  const float* w_fc1  = (const float*)d_in[12];
  const float* b_fc1  = (const float*)d_in[13];
  const float* w_fc2  = (const float*)d_in[14];
  const float* b_fc2  = (const float*)d_in[15];

  char* ws = (char*)d_ws;
  float* s1     = (float*)(ws + 0);
  float* s2     = (float*)(ws + 32768);
  float* scale1 = (float*)(ws + 65536);
  float* shift1 = (float*)(ws + 81920);
  float* scale2 = (float*)(ws + 98304);
  float* shift2 = (float*)(ws + 114688);
  bf16* wtqkv   = (bf16*)(ws + 131072);            // 768x256 bf16
  bf16* wtproj  = (bf16*)(ws + 524288);            // 256x256
  bf16* wtfc1   = (bf16*)(ws + 655360);            // 1024x256
  bf16* wtfc2   = (bf16*)(ws + 1179648);           // 256x1024
  float* psum   = (float*)(ws + 1703936);          // 16*16*256 f32 (pass 1)
  float* psq    = (float*)(ws + 1966080);
  float* pS     = (float*)(ws + 1703936);          // 512x256 f32 (reuses psum+psq
                                                   //  after pass-1 fin)
  const size_t BIG = 2228224;
  bf16* xn   = (bf16*)(ws + BIG);                  // 65536x256 bf16 (33.5MB)
  bf16* qkv  = (bf16*)(ws + BIG + 33554432);       // 384 planes x 4096 x 32
  bf16* attn = (bf16*)(ws + BIG + 134217728);      // 65536x256 bf16 (33.5MB)
  bf16* x1   = (bf16*)(ws + BIG + 33554432);       // overlays qkv head
  bf16* xn2  = xn;                                 // reuses xn slot
  bf16* g    = (bf16*)(ws + BIG + 67108864);       // 32768x1024 chunk, qkv tail
  float* pQ  = (float*)(ws + BIG + 167772160);     // 512x256 f32 (after attn;
                                                   //  within proven ws bound)

  // weight transposes (f32 -> bf16)
  k_tr<<<dim3(24, 8),  256, 0, stream>>>(w_qkv,  wtqkv,  256, 768);
  k_tr<<<dim3(8, 8),   256, 0, stream>>>(w_proj, wtproj, 256, 256);
  k_tr<<<dim3(32, 8),  256, 0, stream>>>(w_fc1,  wtfc1,  256, 1024);
  k_tr<<<dim3(8, 32),  256, 0, stream>>>(w_fc2,  wtfc2,  1024, 256);

  // style projections, adain1 params, adain1 apply
  k_style<<<1024, 256, 0, stream>>>(style, w_ada1, b_ada1, w_ada2, b_ada2, s1, s2);
  k_stats_part<1><<<dim3(16, 16), 256, 0, stream>>>(x, psum, psq);
  k_stats_fin<<<16, 256, 0, stream>>>(psum, psq, s1, scale1, shift1);
  k_adain<1><<<8192, 256, 0, stream>>>(x, scale1, shift1, xn);

  // qkv = xn @ w_qkv + b_qkv  (attention-native output layout)
  k_gemm<0,0,2><<<1536, 512, 0, stream>>>(
      xn, wtqkv, b_qkv, nullptr, qkv, 768, 256, 6);

  // windowed attention (both branches)
  k_attn<<<2048, 256, 0, stream>>>(qkv, rpb1, rpb2, attn);

  // x1 = x + attn @ w_proj + b_proj  (+ fused x1 column stats partials)
  k_gemm4<1,0,0,1><<<1024, 256, 0, stream>>>(
      attn, wtproj, b_proj, x, x1, 256, 256, 2, pS, pQ);

  // adain2 params from fused partials + apply
  k_stats_fin2<<<16, 256, 0, stream>>>(pS, pQ, s2, scale2, shift2);
  k_adain<0><<<8192, 256, 0, stream>>>(x1, scale2, shift2, xn2);

  // MLP in 2 row-chunks of 32768 (g reuses dead qkv tail region)
  for (int ch = 0; ch < 2; ++ch) {
    size_t ro = (size_t)ch * 32768;
    // g = gelu(xn2 @ w_fc1 + b_fc1)   (256x128: 128 x 8 = 1024)
    k_gemm<0,1,0><<<1024, 512, 0, stream>>>(
        xn2 + ro * 256, wtfc1, b_fc1, nullptr, g, 1024, 256, 8);
    // out = x1 + g @ w_fc2 + b_fc2    (128x128: 256 x 2 = 512)
    k_gemm4<2,0,1,0><<<512, 256, 0, stream>>>(
        g, wtfc2, b_fc2, x1 + ro * 256,
        (float*)d_out + ro * 256, 256, 1024, 2, nullptr, nullptr);
  }
}

// Round 18
// 293.210 us; speedup vs baseline: 1.1667x; 1.0509x over previous
//
#include <hip/hip_runtime.h>
#include <hip/hip_bf16.h>

typedef __bf16 bf16;
typedef __bf16 bf16x4v __attribute__((ext_vector_type(4)));
typedef __bf16 bf16x8v __attribute__((ext_vector_type(8)));
typedef float f32x4 __attribute__((ext_vector_type(4)));
typedef short s16x4 __attribute__((ext_vector_type(4)));

#define DEVINL static __device__ __forceinline__
#define AS1 __attribute__((address_space(1)))
#define AS3 __attribute__((address_space(3)))

DEVINL f32x4 mfma16(bf16x8v a, bf16x8v b, f32x4 c) {
  return __builtin_amdgcn_mfma_f32_16x16x32_bf16(a, b, c, 0, 0, 0);
}

DEVINL f32x4 mfma16x16(bf16x4v a, bf16x4v b, f32x4 c) {
#if __has_builtin(__builtin_amdgcn_mfma_f32_16x16x16bf16_1k)
  return __builtin_amdgcn_mfma_f32_16x16x16bf16_1k(
      __builtin_bit_cast(s16x4, a), __builtin_bit_cast(s16x4, b), c, 0, 0, 0);
#else
  f32x4 d;
  asm("v_mfma_f32_16x16x16_bf16 %0, %1, %2, %3"
      : "=v"(d) : "v"(a), "v"(b), "v"(c));
  return d;
#endif
}

// ---------------- fused prologue: 4 weight transposes + style + x-stats -----
// grid 2048: [0,192) tr w_qkv; [192,256) tr w_proj; [256,512) tr w_fc1;
// [512,768) tr w_fc2; [768,1792) style; [1792,2048) stats_part(x, f32).
__global__ __launch_bounds__(256) void k_prep(
    const float* __restrict__ w_qkv, const float* __restrict__ w_proj,
    const float* __restrict__ w_fc1, const float* __restrict__ w_fc2,
    bf16* __restrict__ wtqkv, bf16* __restrict__ wtproj,
    bf16* __restrict__ wtfc1, bf16* __restrict__ wtfc2,
    const float* __restrict__ style,
    const float* __restrict__ wa1, const float* __restrict__ ba1,
    const float* __restrict__ wa2, const float* __restrict__ ba2,
    float* __restrict__ s1, float* __restrict__ s2,
    const float* __restrict__ x,
    float* __restrict__ psum, float* __restrict__ psq) {
  __shared__ float smem[32 * 33];
  int bid = blockIdx.x;
  int tid = threadIdx.x;

  if (bid < 768) {
    // ---- weight transpose+cvt (K x N f32) -> (N x K bf16), 32x32 tile ----
    const float* in; bf16* out; int K, N, bx, by;
    if (bid < 192)      { in = w_qkv;  out = wtqkv;  K = 256;  N = 768;
                          bx = bid % 24;        by = bid / 24; }
    else if (bid < 256) { in = w_proj; out = wtproj; K = 256;  N = 256;
                          int i = bid - 192; bx = i % 8;  by = i / 8; }
    else if (bid < 512) { in = w_fc1;  out = wtfc1;  K = 256;  N = 1024;
                          int i = bid - 256; bx = i % 32; by = i / 32; }
    else                { in = w_fc2;  out = wtfc2;  K = 1024; N = 256;
                          int i = bid - 512; bx = i % 8;  by = i / 8; }
    float (*t)[33] = (float(*)[33])smem;
    int bx32 = bx * 32, by32 = by * 32;
    int tx = tid & 31, ty = tid >> 5;
    #pragma unroll
    for (int r = 0; r < 32; r += 8)
      t[ty + r][tx] = in[(size_t)(by32 + ty + r) * N + bx32 + tx];
    __syncthreads();
    #pragma unroll
    for (int r = 0; r < 32; r += 8)
      out[(size_t)(bx32 + ty + r) * K + by32 + tx] = (bf16)t[tx][ty + r];
  } else if (bid < 1792) {
    // ---- style projection: s = style @ w_ada + b_ada -----------------------
    int i = bid - 768;
    int ng = i & 31, b = (i >> 5) & 15, which = i >> 9;
    int nl = tid & 15, kg = tid >> 4;
    int n = ng * 16 + nl;
    const float* wa = which ? wa2 : wa1;
    const float* ba = which ? ba2 : ba1;
    const float* srow = style + b * 512;
    float acc = 0.f;
    #pragma unroll 8
    for (int kk = 0; kk < 32; ++kk) {
      int k = kg + kk * 16;
      acc += srow[k] * wa[k * 512 + n];
    }
    acc += __shfl_xor(acc, 16);
    acc += __shfl_xor(acc, 32);
    float (*red)[16] = (float(*)[16])smem;
    int w = tid >> 6;
    if ((tid & 63) < 16) red[w][nl] = acc;
    __syncthreads();
    if (tid < 16) {
      float S = red[0][tid] + red[1][tid] + red[2][tid] + red[3][tid]
              + ba[ng * 16 + tid];
      (which ? s2 : s1)[b * 512 + ng * 16 + tid] = S;
    }
  } else {
    // ---- stats pass 1 on x (f32): per (b, row-chunk) partial sum/sumsq -----
    int i = bid - 1792;
    int rc = i & 15, b = i >> 4;
    int c = tid;
    size_t base = (size_t)b * 4096 * 256 + (size_t)rc * 256 * 256 + c;
    float sm = 0.f, q = 0.f;
    #pragma unroll 4
    for (int r = 0; r < 256; ++r) {
      float f = x[base + (size_t)r * 256];
      sm += f; q += f * f;
    }
    int o = (b * 16 + rc) * 256 + c;
    psum[o] = sm; psq[o] = q;
  }
}

// ---------------- stats pass 2: combine + adain scale/shift -----------------
__global__ __launch_bounds__(256) void k_stats_fin(
    const float* __restrict__ psum, const float* __restrict__ psq,
    const float* __restrict__ s,
    float* __restrict__ scale, float* __restrict__ shift) {
  int b = blockIdx.x, c = threadIdx.x;
  float S = 0.f, Q = 0.f;
  #pragma unroll
  for (int rc = 0; rc < 16; ++rc) {
    S += psum[(b * 16 + rc) * 256 + c];
    Q += psq[(b * 16 + rc) * 256 + c];
  }
  float mean = S * (1.0f/4096.0f);
  float var  = Q * (1.0f/4096.0f) - mean * mean;
  float inv  = rsqrtf(var + 1e-5f);
  float mu_s  = s[b * 512 + c];
  float std_s = s[b * 512 + 256 + c];
  float sc = std_s * inv;
  scale[b * 256 + c] = sc;
  shift[b * 256 + c] = mu_s - sc * mean;
}

// ---------------- stats fin from proj-epilogue partials (32 per (b,c)) ------
__global__ __launch_bounds__(256) void k_stats_fin2(
    const float* __restrict__ pS, const float* __restrict__ pQ,
    const float* __restrict__ s,
    float* __restrict__ scale, float* __restrict__ shift) {
  int b = blockIdx.x, c = threadIdx.x;
  float S = 0.f, Q = 0.f;
  #pragma unroll 8
  for (int i = 0; i < 32; ++i) {
    S += pS[(b * 32 + i) * 256 + c];
    Q += pQ[(b * 32 + i) * 256 + c];
  }
  float mean = S * (1.0f/4096.0f);
  float var  = Q * (1.0f/4096.0f) - mean * mean;
  float inv  = rsqrtf(var + 1e-5f);
  float mu_s  = s[b * 512 + c];
  float std_s = s[b * 512 + 256 + c];
  float sc = std_s * inv;
  scale[b * 256 + c] = sc;
  shift[b * 256 + c] = mu_s - sc * mean;
}

// ---------------- adain apply: out_bf16 = shift + scale * in ----------------
template<int F32>
__global__ __launch_bounds__(256) void k_adain(
    const void* __restrict__ in, const float* __restrict__ scale,
    const float* __restrict__ shift, bf16* __restrict__ out) {
  int idx = blockIdx.x * 256 + threadIdx.x;
  int c8 = idx & 31, row = idx >> 5;
  int b = row >> 12, c = c8 * 8;
  const float* scp = &scale[b * 256 + c];
  const float* shp = &shift[b * 256 + c];
  f32x4 sc0 = *(const f32x4*)scp, sc1 = *(const f32x4*)(scp + 4);
  f32x4 sh0 = *(const f32x4*)shp, sh1 = *(const f32x4*)(shp + 4);
  size_t ofs = (size_t)row * 256 + c;
  float f[8];
  if constexpr (F32) {
    f32x4 v0 = *(const f32x4*)&((const float*)in)[ofs];
    f32x4 v1 = *(const f32x4*)&((const float*)in)[ofs + 4];
    f[0]=v0[0]; f[1]=v0[1]; f[2]=v0[2]; f[3]=v0[3];
    f[4]=v1[0]; f[5]=v1[1]; f[6]=v1[2]; f[7]=v1[3];
  } else {
    bf16x8v v = *(const bf16x8v*)&((const bf16*)in)[ofs];
    #pragma unroll
    for (int u = 0; u < 8; ++u) f[u] = (float)v[u];
  }
  bf16x8v o;
  o[0]=(bf16)(sh0[0]+sc0[0]*f[0]); o[1]=(bf16)(sh0[1]+sc0[1]*f[1]);
  o[2]=(bf16)(sh0[2]+sc0[2]*f[2]); o[3]=(bf16)(sh0[3]+sc0[3]*f[3]);
  o[4]=(bf16)(sh1[0]+sc1[0]*f[4]); o[5]=(bf16)(sh1[1]+sc1[1]*f[5]);
  o[6]=(bf16)(sh1[2]+sc1[2]*f[6]); o[7]=(bf16)(sh1[3]+sc1[7-3]*f[7]);
  // fix: index typo guard (sc1[3])
  o[7]=(bf16)(sh1[3]+sc1[3]*f[7]);
  *(bf16x8v*)&out[ofs] = o;
}

// ---------------- GEMM (8-wave 256x128): out = A@Bt^T + bias (+res,gelu) ----
// OUTMODE: 0 = bf16 row-major, 1 = f32 row-major,
//          2 = bf16 qkv-layout [(b*3+m)*8+hh][tok(4096)][32] (attention-native)
template<int RESMODE, int GELU, int OUTMODE>
__global__ __launch_bounds__(512) void k_gemm(
    const bf16* __restrict__ A, const bf16* __restrict__ Bt,
    const float* __restrict__ bias, const void* __restrict__ resv,
    void* __restrict__ outv, int N, int K, int gx) {
  __shared__ bf16 a_sw[256 * 64];   // 32 KB
  __shared__ bf16 b_sw[128 * 64];   // 16 KB
  int tid = threadIdx.x;
  int l = tid & 63, w = tid >> 6;
  int wr = w >> 1, wc = w & 1;             // 4x2 waves, 64x64 each
  int lm = l & 15, lg = l >> 4;

  int nwg = gridDim.x;
  int lin = blockIdx.x;
  int swz = (lin & 7) * (nwg >> 3) + (lin >> 3);
  int bx = swz % gx, by = swz / gx;
  int m0 = by * 256, n0 = bx * 128;

  f32x4 acc[4][4];
  #pragma unroll
  for (int mi = 0; mi < 4; ++mi)
    #pragma unroll
    for (int ni = 0; ni < 4; ++ni)
      acc[mi][ni] = (f32x4){0.f, 0.f, 0.f, 0.f};

  for (int k0 = 0; k0 < K; k0 += 64) {
    #pragma unroll
    for (int i = 0; i < 4; ++i) {
      int slot = i * 512 + tid;
      int r = slot >> 3, cs = slot & 7;
      int c = cs ^ (r & 7);                // inverse swizzle on SOURCE
      const bf16* g = A + (size_t)(m0 + r) * K + k0 + c * 8;
      __builtin_amdgcn_global_load_lds(
          (const AS1 void*)g, (AS3 void*)(a_sw + (i * 512 + w * 64) * 8),
          16, 0, 0);
    }
    #pragma unroll
    for (int i = 0; i < 2; ++i) {
      int slot = i * 512 + tid;
      int r = slot >> 3, cs = slot & 7;
      int c = cs ^ (r & 7);
      const bf16* g = Bt + (size_t)(n0 + r) * K + k0 + c * 8;
      __builtin_amdgcn_global_load_lds(
          (const AS1 void*)g, (AS3 void*)(b_sw + (i * 512 + w * 64) * 8),
          16, 0, 0);
    }
    __syncthreads();
    #pragma unroll
    for (int kk = 0; kk < 2; ++kk) {
      bf16x8v af[4], bv[4];
      #pragma unroll
      for (int mi = 0; mi < 4; ++mi) {
        int row = wr * 64 + mi * 16 + lm;
        af[mi] = *(const bf16x8v*)&a_sw[row * 64 + (((kk * 4 + lg) ^ (row & 7)) * 8)];
      }
      #pragma unroll
      for (int ni = 0; ni < 4; ++ni) {
        int row = wc * 64 + ni * 16 + lm;
        bv[ni] = *(const bf16x8v*)&b_sw[row * 64 + (((kk * 4 + lg) ^ (row & 7)) * 8)];
      }
      #pragma unroll
      for (int mi = 0; mi < 4; ++mi)
        #pragma unroll
        for (int ni = 0; ni < 4; ++ni)
          acc[mi][ni] = mfma16(af[mi], bv[ni], acc[mi][ni]);
    }
    __syncthreads();
  }
  #pragma unroll
  for (int mi = 0; mi < 4; ++mi) {
    #pragma unroll
    for (int ni = 0; ni < 4; ++ni) {
      int row = m0 + wr * 64 + mi * 16 + lg * 4;
      int col = n0 + wc * 64 + ni * 16 + lm;
      float bv_ = bias[col];
      #pragma unroll
      for (int j = 0; j < 4; ++j) {
        float o = acc[mi][ni][j] + bv_;
        if constexpr (RESMODE == 1)
          o += ((const float*)resv)[(size_t)(row + j) * N + col];
        if constexpr (RESMODE == 2)
          o += (float)((const bf16*)resv)[(size_t)(row + j) * N + col];
        if constexpr (GELU) {
          float z = 1.5957691216057308f * (o + 0.044715f * o * o * o);
          o = o / (1.0f + __expf(-z));
        }
        if constexpr (OUTMODE == 1)
          ((float*)outv)[(size_t)(row + j) * N + col] = o;
        else if constexpr (OUTMODE == 2) {
          int b  = (row + j) >> 12, tok = (row + j) & 4095;
          int m  = col >> 8, c2 = col & 255;
          int hh = c2 >> 5, ch = c2 & 31;
          size_t a_ = ((size_t)((b * 3 + m) * 8 + hh) << 17) + (tok << 5) + ch;
          ((bf16*)outv)[a_] = (bf16)o;
        } else
          ((bf16*)outv)[(size_t)(row + j) * N + col] = (bf16)o;
      }
    }
  }
}

// ---------------- GEMM (4-wave 128x128) — for small grids -------------------
// STATS: emit per-block column partial sum/sumsq of the bf16-rounded output
// (deterministic: each (by,col) written exactly once; LDS-tree reduction).
template<int RESMODE, int GELU, int OUTF32, int STATS>
__global__ __launch_bounds__(256) void k_gemm4(
    const bf16* __restrict__ A, const bf16* __restrict__ Bt,
    const float* __restrict__ bias, const void* __restrict__ resv,
    void* __restrict__ outv, int N, int K, int gx,
    float* __restrict__ pS, float* __restrict__ pQ) {
  __shared__ bf16 a_sw[128 * 64];
  __shared__ bf16 b_sw[128 * 64];
  int tid = threadIdx.x;
  int l = tid & 63, w = tid >> 6;
  int wr = w >> 1, wc = w & 1;
  int lm = l & 15, lg = l >> 4;

  int nwg = gridDim.x;
  int lin = blockIdx.x;
  int swz = (lin & 7) * (nwg >> 3) + (lin >> 3);
  int bx = swz % gx, by = swz / gx;
  int m0 = by * 128, n0 = bx * 128;

  f32x4 acc[4][4];
  #pragma unroll
  for (int mi = 0; mi < 4; ++mi)
    #pragma unroll
    for (int ni = 0; ni < 4; ++ni)
      acc[mi][ni] = (f32x4){0.f, 0.f, 0.f, 0.f};

  for (int k0 = 0; k0 < K; k0 += 64) {
    #pragma unroll
    for (int i = 0; i < 4; ++i) {
      int slot = i * 256 + tid;
      int r = slot >> 3, cs = slot & 7;
      int c = cs ^ (r & 7);
      __builtin_amdgcn_global_load_lds(
          (const AS1 void*)(A + (size_t)(m0 + r) * K + k0 + c * 8),
          (AS3 void*)(a_sw + (i * 256 + w * 64) * 8), 16, 0, 0);
    }
    #pragma unroll
    for (int i = 0; i < 4; ++i) {
      int slot = i * 256 + tid;
      int r = slot >> 3, cs = slot & 7;
      int c = cs ^ (r & 7);
      __builtin_amdgcn_global_load_lds(
          (const AS1 void*)(Bt + (size_t)(n0 + r) * K + k0 + c * 8),
          (AS3 void*)(b_sw + (i * 256 + w * 64) * 8), 16, 0, 0);
    }
    __syncthreads();
    #pragma unroll
    for (int kk = 0; kk < 2; ++kk) {
      bf16x8v af[4], bv[4];
      #pragma unroll
      for (int mi = 0; mi < 4; ++mi) {
        int row = wr * 64 + mi * 16 + lm;
        af[mi] = *(const bf16x8v*)&a_sw[row * 64 + (((kk * 4 + lg) ^ (row & 7)) * 8)];
      }
      #pragma unroll
      for (int ni = 0; ni < 4; ++ni) {
        int row = wc * 64 + ni * 16 + lm;
        bv[ni] = *(const bf16x8v*)&b_sw[row * 64 + (((kk * 4 + lg) ^ (row & 7)) * 8)];
      }
      #pragma unroll
      for (int mi = 0; mi < 4; ++mi)
        #pragma unroll
        for (int ni = 0; ni < 4; ++ni)
          acc[mi][ni] = mfma16(af[mi], bv[ni], acc[mi][ni]);
    }
    __syncthreads();
  }

  float sl[4] = {0.f, 0.f, 0.f, 0.f};
  float sq[4] = {0.f, 0.f, 0.f, 0.f};
  #pragma unroll
  for (int mi = 0; mi < 4; ++mi) {
    #pragma unroll
    for (int ni = 0; ni < 4; ++ni) {
      int row = m0 + wr * 64 + mi * 16 + lg * 4;
      int col = n0 + wc * 64 + ni * 16 + lm;
      float bv_ = bias[col];
      #pragma unroll
      for (int j = 0; j < 4; ++j) {
        float o = acc[mi][ni][j] + bv_;
        if constexpr (RESMODE == 1)
          o += ((const float*)resv)[(size_t)(row + j) * N + col];
        if constexpr (RESMODE == 2)
          o += (float)((const bf16*)resv)[(size_t)(row + j) * N + col];
        if constexpr (GELU) {
          float z = 1.5957691216057308f * (o + 0.044715f * o * o * o);
          o = o / (1.0f + __expf(-z));
        }
        if constexpr (OUTF32)
          ((float*)outv)[(size_t)(row + j) * N + col] = o;
        else
          ((bf16*)outv)[(size_t)(row + j) * N + col] = (bf16)o;
        if constexpr (STATS) {
          float ob = (float)(bf16)o;       // match bf16-x1 stats numerics
          sl[ni] += ob;
          sq[ni] += ob * ob;
        }
      }
    }
  }

  if constexpr (STATS) {
    // reduce 8 contributors (wr x lg) per column via LDS (reuse dead a_sw)
    float* red = (float*)a_sw;             // 2048 f32 = 8 KB
    #pragma unroll
    for (int ni = 0; ni < 4; ++ni) {
      int g = (wc * 4 + ni) * 16 + lm;     // == col_local = wc*64+ni*16+lm
      red[g * 8 + wr * 4 + lg] = sl[ni];
      red[1024 + g * 8 + wr * 4 + lg] = sq[ni];
    }
    __syncthreads();
    if (tid < 128) {
      float S = 0.f, Q = 0.f;
      #pragma unroll
      for (int u = 0; u < 8; ++u) {
        S += red[tid * 8 + u];
        Q += red[1024 + tid * 8 + u];
      }
      pS[by * 256 + bx * 128 + tid] = S;
      pQ[by * 256 + bx * 128 + tid] = Q;
    }
  }
}

// ---------------- windowed attention (both branches) ------------------------
// qkv in attention-native layout [(b*3+m)*8+hh][tok][32]: Q/K fragments read
// contiguous 512B token-row runs; V staged coalesced into swizzled V^T.
__global__ __launch_bounds__(256) void k_attn(
    const bf16* __restrict__ qkv,
    const float* __restrict__ rpb1, const float* __restrict__ rpb2,
    bf16* __restrict__ aout) {
  __shared__ bf16 vt[128 * 72];   // V^T: [hh2*32+ch][token-swizzled(+pad)]
  __shared__ float rl[960];       // rpb: [h][dy][dx] stride 240/16/1

  int tid = threadIdx.x;
  int bx = blockIdx.x;
  int br = bx & 1, widx = (bx >> 1) & 63, b = bx >> 7;
  int wy = widx >> 3, wx = widx & 7;

  const float* rpb = br ? rpb2 : rpb1;
  #pragma unroll
  for (int t = tid; t < 960; t += 256) {
    int h0 = t / 240, r0 = t - h0 * 240, dy = r0 >> 4, dx = r0 & 15;
    rl[t] = (dx < 15) ? rpb[(dy * 15 + dx) * 4 + h0] : 0.f;
  }

  auto grow = [&](int tok) -> int {
    int y = wy * 8 + (tok >> 3), xc = wx * 8 + (tok & 7);
    if (br) { y = (y + 4) & 63; xc = (xc + 4) & 63; }
    return y * 64 + xc;                  // in-batch token index
  };

  auto plane = [&](int m, int hh2) -> size_t {
    return (size_t)((b * 3 + m) * 8 + br * 4 + hh2) << 17;
  };

  // stage V transposed: task = tok*16 + c; c = hh2*4 + ch8
  #pragma unroll
  for (int it = 0; it < 4; ++it) {
    int task = it * 256 + tid;
    int tok = task >> 4, c = task & 15;
    int hh2 = c >> 2, ch8 = c & 3;
    bf16x8v v = *(const bf16x8v*)&qkv[plane(2, hh2) + (grow(tok) << 5) + ch8 * 8];
    int tsw = tok ^ ((c & 7) << 3);      // bank-spread swizzle (involution)
    #pragma unroll
    for (int u = 0; u < 8; ++u) vt[(c * 8 + u) * 72 + tsw] = v[u];
  }

  int l = tid & 63, h = tid >> 6;
  int lm = l & 15, lg = l >> 4;

  // Q/K frags: token rows are 64B; 16 toks = 2 contiguous 512B runs
  bf16x8v kb[4], qa[4];
  size_t pq = plane(0, h), pk = plane(1, h);
  #pragma unroll
  for (int i = 0; i < 4; ++i) {
    int t = grow(i * 16 + lm);
    qa[i] = *(const bf16x8v*)&qkv[pq + (t << 5) + lg * 8];
    kb[i] = *(const bf16x8v*)&qkv[pk + (t << 5) + lg * 8];
  }
  __syncthreads();   // vt + rl ready

  bf16x4v vb[2][4];
  #pragma unroll
  for (int ni = 0; ni < 2; ++ni)
    #pragma unroll
    for (int ki = 0; ki < 4; ++ki) {
      int row = h * 32 + ni * 16 + lm;
      int col = (ki * 16 + lg * 4) ^ (((row >> 3) & 7) << 3);
      vb[ni][ki] = *(const bf16x4v*)&vt[row * 72 + col];
    }

  bool need_mask = br && (wy == 7 || wx == 7);

  int ekA[16], idkA[16];
  #pragma unroll
  for (int ki = 0; ki < 4; ++ki)
    #pragma unroll
    for (int j = 0; j < 4; ++j) {
      int ik = ki * 16 + lg * 4 + j;
      ekA[ki * 4 + j] = ik + (ik >> 3) * 8;
      int yk = wy * 8 + (ik >> 3), xk = wx * 8 + (ik & 7);
      idkA[ki * 4 + j] = (yk < 56 ? 0 : (yk < 60 ? 1 : 2)) * 3
                       + (xk < 56 ? 0 : (xk < 60 ? 1 : 2));
    }

  #pragma unroll
  for (int qi = 0; qi < 4; ++qi) {
    f32x4 s[4];
    #pragma unroll
    for (int ki = 0; ki < 4; ++ki)
      s[ki] = mfma16(kb[ki], qa[qi], (f32x4){0.f,0.f,0.f,0.f});

    int iq = qi * 16 + lm;
    int eq = iq + (iq >> 3) * 8;
    int yq = wy * 8 + (iq >> 3), xq = wx * 8 + (iq & 7);
    int idq = (yq < 56 ? 0 : (yq < 60 ? 1 : 2)) * 3
            + (xq < 56 ? 0 : (xq < 60 ? 1 : 2));
    const float* fb = &rl[h * 240 + 119 + eq];

    #pragma unroll
    for (int ki = 0; ki < 4; ++ki)
      #pragma unroll
      for (int j = 0; j < 4; ++j) {
        float val = s[ki][j] * 0.17677669529663687f + fb[-ekA[ki * 4 + j]];
        if (need_mask && idq != idkA[ki * 4 + j]) val -= 100.0f;
        s[ki][j] = val;
      }

    float mx = s[0][0];
    #pragma unroll
    for (int ki = 0; ki < 4; ++ki)
      #pragma unroll
      for (int j = 0; j < 4; ++j) mx = fmaxf(mx, s[ki][j]);
    mx = fmaxf(mx, __shfl_xor(mx, 16));
    mx = fmaxf(mx, __shfl_xor(mx, 32));
    float sum = 0.f;
    #pragma unroll
    for (int ki = 0; ki < 4; ++ki)
      #pragma unroll
      for (int j = 0; j < 4; ++j) {
        float e = __expf(s[ki][j] - mx);
        s[ki][j] = e;
        sum += e;
      }
    sum += __shfl_xor(sum, 16);
    sum += __shfl_xor(sum, 32);
    float rs = 1.0f / sum;

    bf16x4v pa[4];
    #pragma unroll
    for (int ki = 0; ki < 4; ++ki)
      #pragma unroll
      for (int j = 0; j < 4; ++j)
        pa[ki][j] = (bf16)(s[ki][j] * rs);

    f32x4 o[2] = {(f32x4){0.f,0.f,0.f,0.f}, (f32x4){0.f,0.f,0.f,0.f}};
    #pragma unroll
    for (int ki = 0; ki < 4; ++ki) {
      o[0] = mfma16x16(pa[ki], vb[0][ki], o[0]);
      o[1] = mfma16x16(pa[ki], vb[1][ki], o[1]);
    }

    #pragma unroll
    for (int ni = 0; ni < 2; ++ni)
      #pragma unroll
      for (int j = 0; j < 4; ++j) {
        int tok = qi * 16 + lg * 4 + j;
        int col = br * 128 + h * 32 + ni * 16 + lm;
        aout[((size_t)b * 4096 + grow(tok)) * 256 + col] = (bf16)o[ni][j];
      }
  }
}

// ---------------- host ------------------------------------------------------
extern "C" void kernel_launch(void* const* d_in, const int* in_sizes, int n_in,
                              void* d_out, int out_size, void* d_ws, size_t ws_size,
                              hipStream_t stream) {
  (void)in_sizes; (void)n_in; (void)out_size; (void)ws_size;
  const float* x      = (const float*)d_in[0];
  const float* style  = (const float*)d_in[1];
  const float* w_qkv  = (const float*)d_in[2];
  const float* b_qkv  = (const float*)d_in[3];
  const float* w_proj = (const float*)d_in[4];
  const float* b_proj = (const float*)d_in[5];
  const float* w_ada1 = (const float*)d_in[6];
  const float* b_ada1 = (const float*)d_in[7];
  const float* w_ada2 = (const float*)d_in[8];
  const float* b_ada2 = (const float*)d_in[9];
  const float* rpb1   = (const float*)d_in[10];
  const float* rpb2   = (const float*)d_in[11];
  const float* w_fc1  = (const float*)d_in[12];
  const float* b_fc1  = (const float*)d_in[13];
  const float* w_fc2  = (const float*)d_in[14];
  const float* b_fc2  = (const float*)d_in[15];

  char* ws = (char*)d_ws;
  float* s1     = (float*)(ws + 0);
  float* s2     = (float*)(ws + 32768);
  float* scale1 = (float*)(ws + 65536);
  float* shift1 = (float*)(ws + 81920);
  float* scale2 = (float*)(ws + 98304);
  float* shift2 = (float*)(ws + 114688);
  bf16* wtqkv   = (bf16*)(ws + 131072);            // 768x256 bf16
  bf16* wtproj  = (bf16*)(ws + 524288);            // 256x256
  bf16* wtfc1   = (bf16*)(ws + 655360);            // 1024x256
  bf16* wtfc2   = (bf16*)(ws + 1179648);           // 256x1024
  float* psum   = (float*)(ws + 1703936);          // 16*16*256 f32 (pass 1)
  float* psq    = (float*)(ws + 1966080);
  float* pS     = (float*)(ws + 1703936);          // 512x256 f32 (reuses psum+psq)
  const size_t BIG = 2228224;
  bf16* xn   = (bf16*)(ws + BIG);                  // 65536x256 bf16 (33.5MB)
  bf16* qkv  = (bf16*)(ws + BIG + 33554432);       // 384 planes x 4096 x 32
  bf16* attn = (bf16*)(ws + BIG + 134217728);      // 65536x256 bf16 (33.5MB)
  bf16* x1   = (bf16*)(ws + BIG + 33554432);       // overlays qkv head
  bf16* xn2  = xn;                                 // reuses xn slot
  bf16* g    = (bf16*)(ws + BIG + 67108864);       // 32768x1024 chunk, qkv tail
  float* pQ  = (float*)(ws + BIG + 167772160);     // 512x256 f32 (after attn)

  // fused prologue: 4 weight transposes + style + x-stats (one dispatch)
  k_prep<<<2048, 256, 0, stream>>>(
      w_qkv, w_proj, w_fc1, w_fc2, wtqkv, wtproj, wtfc1, wtfc2,
      style, w_ada1, b_ada1, w_ada2, b_ada2, s1, s2, x, psum, psq);

  k_stats_fin<<<16, 256, 0, stream>>>(psum, psq, s1, scale1, shift1);
  k_adain<1><<<8192, 256, 0, stream>>>(x, scale1, shift1, xn);

  // qkv = xn @ w_qkv + b_qkv  (attention-native output layout)
  k_gemm<0,0,2><<<1536, 512, 0, stream>>>(
      xn, wtqkv, b_qkv, nullptr, qkv, 768, 256, 6);

  // windowed attention (both branches)
  k_attn<<<2048, 256, 0, stream>>>(qkv, rpb1, rpb2, attn);

  // x1 = x + attn @ w_proj + b_proj  (+ fused x1 column stats partials)
  k_gemm4<1,0,0,1><<<1024, 256, 0, stream>>>(
      attn, wtproj, b_proj, x, x1, 256, 256, 2, pS, pQ);

  // adain2 params from fused partials + apply
  k_stats_fin2<<<16, 256, 0, stream>>>(pS, pQ, s2, scale2, shift2);
  k_adain<0><<<8192, 256, 0, stream>>>(x1, scale2, shift2, xn2);

  // MLP in 2 row-chunks of 32768 (g reuses dead qkv tail region)
  for (int ch = 0; ch < 2; ++ch) {
    size_t ro = (size_t)ch * 32768;
    // g = gelu(xn2 @ w_fc1 + b_fc1)   (256x128: 128 x 8 = 1024)
    k_gemm<0,1,0><<<1024, 512, 0, stream>>>(
        xn2 + ro * 256, wtfc1, b_fc1, nullptr, g, 1024, 256, 8);
    // out = x1 + g @ w_fc2 + b_fc2    (128x128: 256 x 2 = 512)
    k_gemm4<2,0,1,0><<<512, 256, 0, stream>>>(
        g, wtfc2, b_fc2, x1 + ro * 256,
        (float*)d_out + ro * 256, 256, 1024, 2, nullptr, nullptr);
  }
}

// Round 19
// 285.396 us; speedup vs baseline: 1.1986x; 1.0274x over previous
//
#include <hip/hip_runtime.h>
#include <hip/hip_bf16.h>

typedef __bf16 bf16;
typedef __bf16 bf16x4v __attribute__((ext_vector_type(4)));
typedef __bf16 bf16x8v __attribute__((ext_vector_type(8)));
typedef float f32x4 __attribute__((ext_vector_type(4)));
typedef short s16x4 __attribute__((ext_vector_type(4)));

#define DEVINL static __device__ __forceinline__
#define AS1 __attribute__((address_space(1)))
#define AS3 __attribute__((address_space(3)))

DEVINL f32x4 mfma16(bf16x8v a, bf16x8v b, f32x4 c) {
  return __builtin_amdgcn_mfma_f32_16x16x32_bf16(a, b, c, 0, 0, 0);
}

DEVINL f32x4 mfma16x16(bf16x4v a, bf16x4v b, f32x4 c) {
#if __has_builtin(__builtin_amdgcn_mfma_f32_16x16x16bf16_1k)
  return __builtin_amdgcn_mfma_f32_16x16x16bf16_1k(
      __builtin_bit_cast(s16x4, a), __builtin_bit_cast(s16x4, b), c, 0, 0, 0);
#else
  f32x4 d;
  asm("v_mfma_f32_16x16x16_bf16 %0, %1, %2, %3"
      : "=v"(d) : "v"(a), "v"(b), "v"(c));
  return d;
#endif
}

// ---------------- fused prologue: 4 weight transposes + style + x-stats -----
// grid 2816: [0,192) tr w_qkv; [192,256) tr w_proj; [256,512) tr w_fc1;
// [512,768) tr w_fc2; [768,1792) style; [1792,2816) stats_part(x, 64 chunks).
__global__ __launch_bounds__(256) void k_prep(
    const float* __restrict__ w_qkv, const float* __restrict__ w_proj,
    const float* __restrict__ w_fc1, const float* __restrict__ w_fc2,
    bf16* __restrict__ wtqkv, bf16* __restrict__ wtproj,
    bf16* __restrict__ wtfc1, bf16* __restrict__ wtfc2,
    const float* __restrict__ style,
    const float* __restrict__ wa1, const float* __restrict__ ba1,
    const float* __restrict__ wa2, const float* __restrict__ ba2,
    float* __restrict__ s1, float* __restrict__ s2,
    const float* __restrict__ x,
    float* __restrict__ psum, float* __restrict__ psq) {
  __shared__ float smem[32 * 33];
  int bid = blockIdx.x;
  int tid = threadIdx.x;

  if (bid < 768) {
    // ---- weight transpose+cvt (K x N f32) -> (N x K bf16), 32x32 tile ----
    const float* in; bf16* out; int K, N, bx, by;
    if (bid < 192)      { in = w_qkv;  out = wtqkv;  K = 256;  N = 768;
                          bx = bid % 24;        by = bid / 24; }
    else if (bid < 256) { in = w_proj; out = wtproj; K = 256;  N = 256;
                          int i = bid - 192; bx = i % 8;  by = i / 8; }
    else if (bid < 512) { in = w_fc1;  out = wtfc1;  K = 256;  N = 1024;
                          int i = bid - 256; bx = i % 32; by = i / 32; }
    else                { in = w_fc2;  out = wtfc2;  K = 1024; N = 256;
                          int i = bid - 512; bx = i % 8;  by = i / 8; }
    float (*t)[33] = (float(*)[33])smem;
    int bx32 = bx * 32, by32 = by * 32;
    int tx = tid & 31, ty = tid >> 5;
    #pragma unroll
    for (int r = 0; r < 32; r += 8)
      t[ty + r][tx] = in[(size_t)(by32 + ty + r) * N + bx32 + tx];
    __syncthreads();
    #pragma unroll
    for (int r = 0; r < 32; r += 8)
      out[(size_t)(bx32 + ty + r) * K + by32 + tx] = (bf16)t[tx][ty + r];
  } else if (bid < 1792) {
    // ---- style projection: s = style @ w_ada + b_ada -----------------------
    int i = bid - 768;
    int ng = i & 31, b = (i >> 5) & 15, which = i >> 9;
    int nl = tid & 15, kg = tid >> 4;
    int n = ng * 16 + nl;
    const float* wa = which ? wa2 : wa1;
    const float* ba = which ? ba2 : ba1;
    const float* srow = style + b * 512;
    float acc = 0.f;
    #pragma unroll 8
    for (int kk = 0; kk < 32; ++kk) {
      int k = kg + kk * 16;
      acc += srow[k] * wa[k * 512 + n];
    }
    acc += __shfl_xor(acc, 16);
    acc += __shfl_xor(acc, 32);
    float (*red)[16] = (float(*)[16])smem;
    int w = tid >> 6;
    if ((tid & 63) < 16) red[w][nl] = acc;
    __syncthreads();
    if (tid < 16) {
      float S = red[0][tid] + red[1][tid] + red[2][tid] + red[3][tid]
              + ba[ng * 16 + tid];
      (which ? s2 : s1)[b * 512 + ng * 16 + tid] = S;
    }
  } else {
    // ---- stats pass 1 on x (f32): 64 row-chunks x 16 batches, 64 rows each -
    int i = bid - 1792;
    int rc = i & 63, b = i >> 6;
    int c = tid;
    size_t base = (size_t)b * 4096 * 256 + (size_t)rc * 64 * 256 + c;
    float sm = 0.f, q = 0.f;
    #pragma unroll 4
    for (int r = 0; r < 64; ++r) {
      float f = x[base + (size_t)r * 256];
      sm += f; q += f * f;
    }
    int o = (b * 64 + rc) * 256 + c;
    psum[o] = sm; psq[o] = q;
  }
}

// ---------------- stats pass 2: combine 64 chunks + adain scale/shift -------
__global__ __launch_bounds__(256) void k_stats_fin(
    const float* __restrict__ psum, const float* __restrict__ psq,
    const float* __restrict__ s,
    float* __restrict__ scale, float* __restrict__ shift) {
  int b = blockIdx.x, c = threadIdx.x;
  float S = 0.f, Q = 0.f;
  #pragma unroll 8
  for (int rc = 0; rc < 64; ++rc) {
    S += psum[(b * 64 + rc) * 256 + c];
    Q += psq[(b * 64 + rc) * 256 + c];
  }
  float mean = S * (1.0f/4096.0f);
  float var  = Q * (1.0f/4096.0f) - mean * mean;
  float inv  = rsqrtf(var + 1e-5f);
  float mu_s  = s[b * 512 + c];
  float std_s = s[b * 512 + 256 + c];
  float sc = std_s * inv;
  scale[b * 256 + c] = sc;
  shift[b * 256 + c] = mu_s - sc * mean;
}

// ---------------- stats fin from proj-epilogue partials (32 per (b,c)) ------
__global__ __launch_bounds__(256) void k_stats_fin2(
    const float* __restrict__ pS, const float* __restrict__ pQ,
    const float* __restrict__ s,
    float* __restrict__ scale, float* __restrict__ shift) {
  int b = blockIdx.x, c = threadIdx.x;
  float S = 0.f, Q = 0.f;
  #pragma unroll 8
  for (int i = 0; i < 32; ++i) {
    S += pS[(b * 32 + i) * 256 + c];
    Q += pQ[(b * 32 + i) * 256 + c];
  }
  float mean = S * (1.0f/4096.0f);
  float var  = Q * (1.0f/4096.0f) - mean * mean;
  float inv  = rsqrtf(var + 1e-5f);
  float mu_s  = s[b * 512 + c];
  float std_s = s[b * 512 + 256 + c];
  float sc = std_s * inv;
  scale[b * 256 + c] = sc;
  shift[b * 256 + c] = mu_s - sc * mean;
}

// ---------------- adain apply: out_bf16 = shift + scale * in ----------------
template<int F32>
__global__ __launch_bounds__(256) void k_adain(
    const void* __restrict__ in, const float* __restrict__ scale,
    const float* __restrict__ shift, bf16* __restrict__ out) {
  int idx = blockIdx.x * 256 + threadIdx.x;
  int c8 = idx & 31, row = idx >> 5;
  int b = row >> 12, c = c8 * 8;
  const float* scp = &scale[b * 256 + c];
  const float* shp = &shift[b * 256 + c];
  f32x4 sc0 = *(const f32x4*)scp, sc1 = *(const f32x4*)(scp + 4);
  f32x4 sh0 = *(const f32x4*)shp, sh1 = *(const f32x4*)(shp + 4);
  size_t ofs = (size_t)row * 256 + c;
  float f[8];
  if constexpr (F32) {
    f32x4 v0 = *(const f32x4*)&((const float*)in)[ofs];
    f32x4 v1 = *(const f32x4*)&((const float*)in)[ofs + 4];
    f[0]=v0[0]; f[1]=v0[1]; f[2]=v0[2]; f[3]=v0[3];
    f[4]=v1[0]; f[5]=v1[1]; f[6]=v1[2]; f[7]=v1[3];
  } else {
    bf16x8v v = *(const bf16x8v*)&((const bf16*)in)[ofs];
    #pragma unroll
    for (int u = 0; u < 8; ++u) f[u] = (float)v[u];
  }
  bf16x8v o;
  o[0]=(bf16)(sh0[0]+sc0[0]*f[0]); o[1]=(bf16)(sh0[1]+sc0[1]*f[1]);
  o[2]=(bf16)(sh0[2]+sc0[2]*f[2]); o[3]=(bf16)(sh0[3]+sc0[3]*f[3]);
  o[4]=(bf16)(sh1[0]+sc1[0]*f[4]); o[5]=(bf16)(sh1[1]+sc1[1]*f[5]);
  o[6]=(bf16)(sh1[2]+sc1[2]*f[6]); o[7]=(bf16)(sh1[3]+sc1[3]*f[7]);
  *(bf16x8v*)&out[ofs] = o;
}

// ---------------- GEMM (8-wave 256x128): out = A@Bt^T + bias (+res,gelu) ----
// OUTMODE: 0 = bf16 row-major, 1 = f32 row-major,
//          2 = bf16 qkv-layout [(b*3+m)*8+hh][tok(4096)][32] (attention-native)
template<int RESMODE, int GELU, int OUTMODE>
__global__ __launch_bounds__(512) void k_gemm(
    const bf16* __restrict__ A, const bf16* __restrict__ Bt,
    const float* __restrict__ bias, const void* __restrict__ resv,
    void* __restrict__ outv, int N, int K, int gx) {
  __shared__ bf16 a_sw[256 * 64];   // 32 KB
  __shared__ bf16 b_sw[128 * 64];   // 16 KB
  int tid = threadIdx.x;
  int l = tid & 63, w = tid >> 6;
  int wr = w >> 1, wc = w & 1;             // 4x2 waves, 64x64 each
  int lm = l & 15, lg = l >> 4;

  int nwg = gridDim.x;
  int lin = blockIdx.x;
  int swz = (lin & 7) * (nwg >> 3) + (lin >> 3);
  int bx = swz % gx, by = swz / gx;
  int m0 = by * 256, n0 = bx * 128;

  f32x4 acc[4][4];
  #pragma unroll
  for (int mi = 0; mi < 4; ++mi)
    #pragma unroll
    for (int ni = 0; ni < 4; ++ni)
      acc[mi][ni] = (f32x4){0.f, 0.f, 0.f, 0.f};

  for (int k0 = 0; k0 < K; k0 += 64) {
    #pragma unroll
    for (int i = 0; i < 4; ++i) {
      int slot = i * 512 + tid;
      int r = slot >> 3, cs = slot & 7;
      int c = cs ^ (r & 7);                // inverse swizzle on SOURCE
      const bf16* g = A + (size_t)(m0 + r) * K + k0 + c * 8;
      __builtin_amdgcn_global_load_lds(
          (const AS1 void*)g, (AS3 void*)(a_sw + (i * 512 + w * 64) * 8),
          16, 0, 0);
    }
    #pragma unroll
    for (int i = 0; i < 2; ++i) {
      int slot = i * 512 + tid;
      int r = slot >> 3, cs = slot & 7;
      int c = cs ^ (r & 7);
      const bf16* g = Bt + (size_t)(n0 + r) * K + k0 + c * 8;
      __builtin_amdgcn_global_load_lds(
          (const AS1 void*)g, (AS3 void*)(b_sw + (i * 512 + w * 64) * 8),
          16, 0, 0);
    }
    __syncthreads();
    #pragma unroll
    for (int kk = 0; kk < 2; ++kk) {
      bf16x8v af[4], bv[4];
      #pragma unroll
      for (int mi = 0; mi < 4; ++mi) {
        int row = wr * 64 + mi * 16 + lm;
        af[mi] = *(const bf16x8v*)&a_sw[row * 64 + (((kk * 4 + lg) ^ (row & 7)) * 8)];
      }
      #pragma unroll
      for (int ni = 0; ni < 4; ++ni) {
        int row = wc * 64 + ni * 16 + lm;
        bv[ni] = *(const bf16x8v*)&b_sw[row * 64 + (((kk * 4 + lg) ^ (row & 7)) * 8)];
      }
      #pragma unroll
      for (int mi = 0; mi < 4; ++mi)
        #pragma unroll
        for (int ni = 0; ni < 4; ++ni)
          acc[mi][ni] = mfma16(af[mi], bv[ni], acc[mi][ni]);
    }
    __syncthreads();
  }
  #pragma unroll
  for (int mi = 0; mi < 4; ++mi) {
    #pragma unroll
    for (int ni = 0; ni < 4; ++ni) {
      int row = m0 + wr * 64 + mi * 16 + lg * 4;
      int col = n0 + wc * 64 + ni * 16 + lm;
      float bv_ = bias[col];
      #pragma unroll
      for (int j = 0; j < 4; ++j) {
        float o = acc[mi][ni][j] + bv_;
        if constexpr (RESMODE == 1)
          o += ((const float*)resv)[(size_t)(row + j) * N + col];
        if constexpr (RESMODE == 2)
          o += (float)((const bf16*)resv)[(size_t)(row + j) * N + col];
        if constexpr (GELU) {
          float z = 1.5957691216057308f * (o + 0.044715f * o * o * o);
          o = o / (1.0f + __expf(-z));
        }
        if constexpr (OUTMODE == 1)
          ((float*)outv)[(size_t)(row + j) * N + col] = o;
        else if constexpr (OUTMODE == 2) {
          int b  = (row + j) >> 12, tok = (row + j) & 4095;
          int m  = col >> 8, c2 = col & 255;
          int hh = c2 >> 5, ch = c2 & 31;
          size_t a_ = ((size_t)((b * 3 + m) * 8 + hh) << 17) + (tok << 5) + ch;
          ((bf16*)outv)[a_] = (bf16)o;
        } else
          ((bf16*)outv)[(size_t)(row + j) * N + col] = (bf16)o;
      }
    }
  }
}

// ---------------- GEMM (4-wave 128x128) — for small grids -------------------
// STATS: emit per-block column partial sum/sumsq of the bf16-rounded output
// (deterministic: each (by,col) written exactly once; LDS-tree reduction).
template<int RESMODE, int GELU, int OUTF32, int STATS>
__global__ __launch_bounds__(256) void k_gemm4(
    const bf16* __restrict__ A, const bf16* __restrict__ Bt,
    const float* __restrict__ bias, const void* __restrict__ resv,
    void* __restrict__ outv, int N, int K, int gx,
    float* __restrict__ pS, float* __restrict__ pQ) {
  __shared__ bf16 a_sw[128 * 64];
  __shared__ bf16 b_sw[128 * 64];
  int tid = threadIdx.x;
  int l = tid & 63, w = tid >> 6;
  int wr = w >> 1, wc = w & 1;
  int lm = l & 15, lg = l >> 4;

  int nwg = gridDim.x;
  int lin = blockIdx.x;
  int swz = (lin & 7) * (nwg >> 3) + (lin >> 3);
  int bx = swz % gx, by = swz / gx;
  int m0 = by * 128, n0 = bx * 128;

  f32x4 acc[4][4];
  #pragma unroll
  for (int mi = 0; mi < 4; ++mi)
    #pragma unroll
    for (int ni = 0; ni < 4; ++ni)
      acc[mi][ni] = (f32x4){0.f, 0.f, 0.f, 0.f};

  for (int k0 = 0; k0 < K; k0 += 64) {
    #pragma unroll
    for (int i = 0; i < 4; ++i) {
      int slot = i * 256 + tid;
      int r = slot >> 3, cs = slot & 7;
      int c = cs ^ (r & 7);
      __builtin_amdgcn_global_load_lds(
          (const AS1 void*)(A + (size_t)(m0 + r) * K + k0 + c * 8),
          (AS3 void*)(a_sw + (i * 256 + w * 64) * 8), 16, 0, 0);
    }
    #pragma unroll
    for (int i = 0; i < 4; ++i) {
      int slot = i * 256 + tid;
      int r = slot >> 3, cs = slot & 7;
      int c = cs ^ (r & 7);
      __builtin_amdgcn_global_load_lds(
          (const AS1 void*)(Bt + (size_t)(n0 + r) * K + k0 + c * 8),
          (AS3 void*)(b_sw + (i * 256 + w * 64) * 8), 16, 0, 0);
    }
    __syncthreads();
    #pragma unroll
    for (int kk = 0; kk < 2; ++kk) {
      bf16x8v af[4], bv[4];
      #pragma unroll
      for (int mi = 0; mi < 4; ++mi) {
        int row = wr * 64 + mi * 16 + lm;
        af[mi] = *(const bf16x8v*)&a_sw[row * 64 + (((kk * 4 + lg) ^ (row & 7)) * 8)];
      }
      #pragma unroll
      for (int ni = 0; ni < 4; ++ni) {
        int row = wc * 64 + ni * 16 + lm;
        bv[ni] = *(const bf16x8v*)&b_sw[row * 64 + (((kk * 4 + lg) ^ (row & 7)) * 8)];
      }
      #pragma unroll
      for (int mi = 0; mi < 4; ++mi)
        #pragma unroll
        for (int ni = 0; ni < 4; ++ni)
          acc[mi][ni] = mfma16(af[mi], bv[ni], acc[mi][ni]);
    }
    __syncthreads();
  }

  float sl[4] = {0.f, 0.f, 0.f, 0.f};
  float sq[4] = {0.f, 0.f, 0.f, 0.f};
  #pragma unroll
  for (int mi = 0; mi < 4; ++mi) {
    #pragma unroll
    for (int ni = 0; ni < 4; ++ni) {
      int row = m0 + wr * 64 + mi * 16 + lg * 4;
      int col = n0 + wc * 64 + ni * 16 + lm;
      float bv_ = bias[col];
      #pragma unroll
      for (int j = 0; j < 4; ++j) {
        float o = acc[mi][ni][j] + bv_;
        if constexpr (RESMODE == 1)
          o += ((const float*)resv)[(size_t)(row + j) * N + col];
        if constexpr (RESMODE == 2)
          o += (float)((const bf16*)resv)[(size_t)(row + j) * N + col];
        if constexpr (GELU) {
          float z = 1.5957691216057308f * (o + 0.044715f * o * o * o);
          o = o / (1.0f + __expf(-z));
        }
        if constexpr (OUTF32)
          ((float*)outv)[(size_t)(row + j) * N + col] = o;
        else
          ((bf16*)outv)[(size_t)(row + j) * N + col] = (bf16)o;
        if constexpr (STATS) {
          float ob = (float)(bf16)o;       // match bf16-x1 stats numerics
          sl[ni] += ob;
          sq[ni] += ob * ob;
        }
      }
    }
  }

  if constexpr (STATS) {
    // reduce 8 contributors (wr x lg) per column via LDS (reuse dead a_sw)
    float* red = (float*)a_sw;             // 2048 f32 = 8 KB
    #pragma unroll
    for (int ni = 0; ni < 4; ++ni) {
      int g = (wc * 4 + ni) * 16 + lm;     // == col_local = wc*64+ni*16+lm
      red[g * 8 + wr * 4 + lg] = sl[ni];
      red[1024 + g * 8 + wr * 4 + lg] = sq[ni];
    }
    __syncthreads();
    if (tid < 128) {
      float S = 0.f, Q = 0.f;
      #pragma unroll
      for (int u = 0; u < 8; ++u) {
        S += red[tid * 8 + u];
        Q += red[1024 + tid * 8 + u];
      }
      pS[by * 256 + bx * 128 + tid] = S;
      pQ[by * 256 + bx * 128 + tid] = Q;
    }
  }
}

// ---------------- windowed attention (both branches) ------------------------
// qkv in attention-native layout [(b*3+m)*8+hh][tok][32]: Q/K fragments read
// contiguous 512B token-row runs; V staged coalesced into swizzled V^T.
__global__ __launch_bounds__(256) void k_attn(
    const bf16* __restrict__ qkv,
    const float* __restrict__ rpb1, const float* __restrict__ rpb2,
    bf16* __restrict__ aout) {
  __shared__ bf16 vt[128 * 72];   // V^T: [hh2*32+ch][token-swizzled(+pad)]
  __shared__ float rl[960];       // rpb: [h][dy][dx] stride 240/16/1

  int tid = threadIdx.x;
  int bx = blockIdx.x;
  int br = bx & 1, widx = (bx >> 1) & 63, b = bx >> 7;
  int wy = widx >> 3, wx = widx & 7;

  const float* rpb = br ? rpb2 : rpb1;
  #pragma unroll
  for (int t = tid; t < 960; t += 256) {
    int h0 = t / 240, r0 = t - h0 * 240, dy = r0 >> 4, dx = r0 & 15;
    rl[t] = (dx < 15) ? rpb[(dy * 15 + dx) * 4 + h0] : 0.f;
  }

  auto grow = [&](int tok) -> int {
    int y = wy * 8 + (tok >> 3), xc = wx * 8 + (tok & 7);
    if (br) { y = (y + 4) & 63; xc = (xc + 4) & 63; }
    return y * 64 + xc;                  // in-batch token index
  };

  auto plane = [&](int m, int hh2) -> size_t {
    return (size_t)((b * 3 + m) * 8 + br * 4 + hh2) << 17;
  };

  // stage V transposed: task = tok*16 + c; c = hh2*4 + ch8
  #pragma unroll
  for (int it = 0; it < 4; ++it) {
    int task = it * 256 + tid;
    int tok = task >> 4, c = task & 15;
    int hh2 = c >> 2, ch8 = c & 3;
    bf16x8v v = *(const bf16x8v*)&qkv[plane(2, hh2) + (grow(tok) << 5) + ch8 * 8];
    int tsw = tok ^ ((c & 7) << 3);      // bank-spread swizzle (involution)
    #pragma unroll
    for (int u = 0; u < 8; ++u) vt[(c * 8 + u) * 72 + tsw] = v[u];
  }

  int l = tid & 63, h = tid >> 6;
  int lm = l & 15, lg = l >> 4;

  // Q/K frags: token rows are 64B; 16 toks = 2 contiguous 512B runs
  bf16x8v kb[4], qa[4];
  size_t pq = plane(0, h), pk = plane(1, h);
  #pragma unroll
  for (int i = 0; i < 4; ++i) {
    int t = grow(i * 16 + lm);
    qa[i] = *(const bf16x8v*)&qkv[pq + (t << 5) + lg * 8];
    kb[i] = *(const bf16x8v*)&qkv[pk + (t << 5) + lg * 8];
  }
  __syncthreads();   // vt + rl ready

  bf16x4v vb[2][4];
  #pragma unroll
  for (int ni = 0; ni < 2; ++ni)
    #pragma unroll
    for (int ki = 0; ki < 4; ++ki) {
      int row = h * 32 + ni * 16 + lm;
      int col = (ki * 16 + lg * 4) ^ (((row >> 3) & 7) << 3);
      vb[ni][ki] = *(const bf16x4v*)&vt[row * 72 + col];
    }

  bool need_mask = br && (wy == 7 || wx == 7);

  int ekA[16], idkA[16];
  #pragma unroll
  for (int ki = 0; ki < 4; ++ki)
    #pragma unroll
    for (int j = 0; j < 4; ++j) {
      int ik = ki * 16 + lg * 4 + j;
      ekA[ki * 4 + j] = ik + (ik >> 3) * 8;
      int yk = wy * 8 + (ik >> 3), xk = wx * 8 + (ik & 7);
      idkA[ki * 4 + j] = (yk < 56 ? 0 : (yk < 60 ? 1 : 2)) * 3
                       + (xk < 56 ? 0 : (xk < 60 ? 1 : 2));
    }

  #pragma unroll
  for (int qi = 0; qi < 4; ++qi) {
    f32x4 s[4];
    #pragma unroll
    for (int ki = 0; ki < 4; ++ki)
      s[ki] = mfma16(kb[ki], qa[qi], (f32x4){0.f,0.f,0.f,0.f});

    int iq = qi * 16 + lm;
    int eq = iq + (iq >> 3) * 8;
    int yq = wy * 8 + (iq >> 3), xq = wx * 8 + (iq & 7);
    int idq = (yq < 56 ? 0 : (yq < 60 ? 1 : 2)) * 3
            + (xq < 56 ? 0 : (xq < 60 ? 1 : 2));
    const float* fb = &rl[h * 240 + 119 + eq];

    #pragma unroll
    for (int ki = 0; ki < 4; ++ki)
      #pragma unroll
      for (int j = 0; j < 4; ++j) {
        float val = s[ki][j] * 0.17677669529663687f + fb[-ekA[ki * 4 + j]];
        if (need_mask && idq != idkA[ki * 4 + j]) val -= 100.0f;
        s[ki][j] = val;
      }

    float mx = s[0][0];
    #pragma unroll
    for (int ki = 0; ki < 4; ++ki)
      #pragma unroll
      for (int j = 0; j < 4; ++j) mx = fmaxf(mx, s[ki][j]);
    mx = fmaxf(mx, __shfl_xor(mx, 16));
    mx = fmaxf(mx, __shfl_xor(mx, 32));
    float sum = 0.f;
    #pragma unroll
    for (int ki = 0; ki < 4; ++ki)
      #pragma unroll
      for (int j = 0; j < 4; ++j) {
        float e = __expf(s[ki][j] - mx);
        s[ki][j] = e;
        sum += e;
      }
    sum += __shfl_xor(sum, 16);
    sum += __shfl_xor(sum, 32);
    float rs = 1.0f / sum;

    bf16x4v pa[4];
    #pragma unroll
    for (int ki = 0; ki < 4; ++ki)
      #pragma unroll
      for (int j = 0; j < 4; ++j)
        pa[ki][j] = (bf16)(s[ki][j] * rs);

    f32x4 o[2] = {(f32x4){0.f,0.f,0.f,0.f}, (f32x4){0.f,0.f,0.f,0.f}};
    #pragma unroll
    for (int ki = 0; ki < 4; ++ki) {
      o[0] = mfma16x16(pa[ki], vb[0][ki], o[0]);
      o[1] = mfma16x16(pa[ki], vb[1][ki], o[1]);
    }

    #pragma unroll
    for (int ni = 0; ni < 2; ++ni)
      #pragma unroll
      for (int j = 0; j < 4; ++j) {
        int tok = qi * 16 + lg * 4 + j;
        int col = br * 128 + h * 32 + ni * 16 + lm;
        aout[((size_t)b * 4096 + grow(tok)) * 256 + col] = (bf16)o[ni][j];
      }
  }
}

// ---------------- host ------------------------------------------------------
extern "C" void kernel_launch(void* const* d_in, const int* in_sizes, int n_in,
                              void* d_out, int out_size, void* d_ws, size_t ws_size,
                              hipStream_t stream) {
  (void)in_sizes; (void)n_in; (void)out_size; (void)ws_size;
  const float* x      = (const float*)d_in[0];
  const float* style  = (const float*)d_in[1];
  const float* w_qkv  = (const float*)d_in[2];
  const float* b_qkv  = (const float*)d_in[3];
  const float* w_proj = (const float*)d_in[4];
  const float* b_proj = (const float*)d_in[5];
  const float* w_ada1 = (const float*)d_in[6];
  const float* b_ada1 = (const float*)d_in[7];
  const float* w_ada2 = (const float*)d_in[8];
  const float* b_ada2 = (const float*)d_in[9];
  const float* rpb1   = (const float*)d_in[10];
  const float* rpb2   = (const float*)d_in[11];
  const float* w_fc1  = (const float*)d_in[12];
  const float* b_fc1  = (const float*)d_in[13];
  const float* w_fc2  = (const float*)d_in[14];
  const float* b_fc2  = (const float*)d_in[15];

  char* ws = (char*)d_ws;
  float* s1     = (float*)(ws + 0);
  float* s2     = (float*)(ws + 32768);
  float* scale1 = (float*)(ws + 65536);
  float* shift1 = (float*)(ws + 81920);
  float* scale2 = (float*)(ws + 98304);
  float* shift2 = (float*)(ws + 114688);
  bf16* wtqkv   = (bf16*)(ws + 131072);            // 768x256 bf16
  bf16* wtproj  = (bf16*)(ws + 524288);            // 256x256
  bf16* wtfc1   = (bf16*)(ws + 655360);            // 1024x256
  bf16* wtfc2   = (bf16*)(ws + 1179648);           // 256x1024
  float* psum   = (float*)(ws + 1703936);          // 16*64*256 f32 = 1MB
  float* psq    = (float*)(ws + 2752512);          // 1MB
  float* pS     = (float*)(ws + 1703936);          // 512x256 f32 (reuses psum
                                                   //  after adain1 params done)
  const size_t BIG = 4194304;
  bf16* xn   = (bf16*)(ws + BIG);                  // 65536x256 bf16 (33.5MB)
  bf16* qkv  = (bf16*)(ws + BIG + 33554432);       // 384 planes x 4096 x 32
  bf16* attn = (bf16*)(ws + BIG + 134217728);      // 65536x256 bf16 (33.5MB)
  bf16* x1   = (bf16*)(ws + BIG + 33554432);       // overlays qkv head
  bf16* xn2  = xn;                                 // reuses xn slot
  bf16* g    = (bf16*)(ws + BIG + 67108864);       // 32768x1024 chunk, qkv tail
  float* pQ  = (float*)(ws + BIG + 167772160);     // 512x256 f32 (after attn)

  // fused prologue: 4 weight transposes + style + x-stats (one dispatch)
  k_prep<<<2816, 256, 0, stream>>>(
      w_qkv, w_proj, w_fc1, w_fc2, wtqkv, wtproj, wtfc1, wtfc2,
      style, w_ada1, b_ada1, w_ada2, b_ada2, s1, s2, x, psum, psq);

  k_stats_fin<<<16, 256, 0, stream>>>(psum, psq, s1, scale1, shift1);
  k_adain<1><<<8192, 256, 0, stream>>>(x, scale1, shift1, xn);

  // qkv = xn @ w_qkv + b_qkv  (attention-native output layout)
  k_gemm<0,0,2><<<1536, 512, 0, stream>>>(
      xn, wtqkv, b_qkv, nullptr, qkv, 768, 256, 6);

  // windowed attention (both branches)
  k_attn<<<2048, 256, 0, stream>>>(qkv, rpb1, rpb2, attn);

  // x1 = x + attn @ w_proj + b_proj  (+ fused x1 column stats partials)
  k_gemm4<1,0,0,1><<<1024, 256, 0, stream>>>(
      attn, wtproj, b_proj, x, x1, 256, 256, 2, pS, pQ);

  // adain2 params from fused partials + apply
  k_stats_fin2<<<16, 256, 0, stream>>>(pS, pQ, s2, scale2, shift2);
  k_adain<0><<<8192, 256, 0, stream>>>(x1, scale2, shift2, xn2);

  // MLP in 2 row-chunks of 32768 (g reuses dead qkv tail region)
  for (int ch = 0; ch < 2; ++ch) {
    size_t ro = (size_t)ch * 32768;
    // g = gelu(xn2 @ w_fc1 + b_fc1)   (256x128: 128 x 8 = 1024)
    k_gemm<0,1,0><<<1024, 512, 0, stream>>>(
        xn2 + ro * 256, wtfc1, b_fc1, nullptr, g, 1024, 256, 8);
    // out = x1 + g @ w_fc2 + b_fc2    (128x128: 256 x 2 = 512)
    k_gemm4<2,0,1,0><<<512, 256, 0, stream>>>(
        g, wtfc2, b_fc2, x1 + ro * 256,
        (float*)d_out + ro * 256, 256, 1024, 2, nullptr, nullptr);
  }
}

// Round 20
// 280.283 us; speedup vs baseline: 1.2205x; 1.0182x over previous
//
#include <hip/hip_runtime.h>
#include <hip/hip_bf16.h>

typedef __bf16 bf16;
typedef __bf16 bf16x4v __attribute__((ext_vector_type(4)));
typedef __bf16 bf16x8v __attribute__((ext_vector_type(8)));
typedef float f32x4 __attribute__((ext_vector_type(4)));
typedef short s16x4 __attribute__((ext_vector_type(4)));

#define DEVINL static __device__ __forceinline__
#define AS1 __attribute__((address_space(1)))
#define AS3 __attribute__((address_space(3)))

DEVINL f32x4 mfma16(bf16x8v a, bf16x8v b, f32x4 c) {
  return __builtin_amdgcn_mfma_f32_16x16x32_bf16(a, b, c, 0, 0, 0);
}

DEVINL f32x4 mfma16x16(bf16x4v a, bf16x4v b, f32x4 c) {
#if __has_builtin(__builtin_amdgcn_mfma_f32_16x16x16bf16_1k)
  return __builtin_amdgcn_mfma_f32_16x16x16bf16_1k(
      __builtin_bit_cast(s16x4, a), __builtin_bit_cast(s16x4, b), c, 0, 0, 0);
#else
  f32x4 d;
  asm("v_mfma_f32_16x16x16_bf16 %0, %1, %2, %3"
      : "=v"(d) : "v"(a), "v"(b), "v"(c));
  return d;
#endif
}

// ---------------- fused prologue: 4 weight transposes + style + x-stats -----
// grid 2816: [0,192) tr w_qkv; [192,256) tr w_proj; [256,512) tr w_fc1;
// [512,768) tr w_fc2; [768,1792) style; [1792,2816) stats_part(x, 64 chunks).
__global__ __launch_bounds__(256) void k_prep(
    const float* __restrict__ w_qkv, const float* __restrict__ w_proj,
    const float* __restrict__ w_fc1, const float* __restrict__ w_fc2,
    bf16* __restrict__ wtqkv, bf16* __restrict__ wtproj,
    bf16* __restrict__ wtfc1, bf16* __restrict__ wtfc2,
    const float* __restrict__ style,
    const float* __restrict__ wa1, const float* __restrict__ ba1,
    const float* __restrict__ wa2, const float* __restrict__ ba2,
    float* __restrict__ s1, float* __restrict__ s2,
    const float* __restrict__ x,
    float* __restrict__ psum, float* __restrict__ psq) {
  __shared__ float smem[32 * 33];
  int bid = blockIdx.x;
  int tid = threadIdx.x;

  if (bid < 768) {
    const float* in; bf16* out; int K, N, bx, by;
    if (bid < 192)      { in = w_qkv;  out = wtqkv;  K = 256;  N = 768;
                          bx = bid % 24;        by = bid / 24; }
    else if (bid < 256) { in = w_proj; out = wtproj; K = 256;  N = 256;
                          int i = bid - 192; bx = i % 8;  by = i / 8; }
    else if (bid < 512) { in = w_fc1;  out = wtfc1;  K = 256;  N = 1024;
                          int i = bid - 256; bx = i % 32; by = i / 32; }
    else                { in = w_fc2;  out = wtfc2;  K = 1024; N = 256;
                          int i = bid - 512; bx = i % 8;  by = i / 8; }
    float (*t)[33] = (float(*)[33])smem;
    int bx32 = bx * 32, by32 = by * 32;
    int tx = tid & 31, ty = tid >> 5;
    #pragma unroll
    for (int r = 0; r < 32; r += 8)
      t[ty + r][tx] = in[(size_t)(by32 + ty + r) * N + bx32 + tx];
    __syncthreads();
    #pragma unroll
    for (int r = 0; r < 32; r += 8)
      out[(size_t)(bx32 + ty + r) * K + by32 + tx] = (bf16)t[tx][ty + r];
  } else if (bid < 1792) {
    int i = bid - 768;
    int ng = i & 31, b = (i >> 5) & 15, which = i >> 9;
    int nl = tid & 15, kg = tid >> 4;
    int n = ng * 16 + nl;
    const float* wa = which ? wa2 : wa1;
    const float* ba = which ? ba2 : ba1;
    const float* srow = style + b * 512;
    float acc = 0.f;
    #pragma unroll 8
    for (int kk = 0; kk < 32; ++kk) {
      int k = kg + kk * 16;
      acc += srow[k] * wa[k * 512 + n];
    }
    acc += __shfl_xor(acc, 16);
    acc += __shfl_xor(acc, 32);
    float (*red)[16] = (float(*)[16])smem;
    int w = tid >> 6;
    if ((tid & 63) < 16) red[w][nl] = acc;
    __syncthreads();
    if (tid < 16) {
      float S = red[0][tid] + red[1][tid] + red[2][tid] + red[3][tid]
              + ba[ng * 16 + tid];
      (which ? s2 : s1)[b * 512 + ng * 16 + tid] = S;
    }
  } else {
    int i = bid - 1792;
    int rc = i & 63, b = i >> 6;
    int c = tid;
    size_t base = (size_t)b * 4096 * 256 + (size_t)rc * 64 * 256 + c;
    float sm = 0.f, q = 0.f;
    #pragma unroll 4
    for (int r = 0; r < 64; ++r) {
      float f = x[base + (size_t)r * 256];
      sm += f; q += f * f;
    }
    int o = (b * 64 + rc) * 256 + c;
    psum[o] = sm; psq[o] = q;
  }
}

// ---------------- stats pass 2: combine 64 chunks + adain scale/shift -------
__global__ __launch_bounds__(256) void k_stats_fin(
    const float* __restrict__ psum, const float* __restrict__ psq,
    const float* __restrict__ s,
    float* __restrict__ scale, float* __restrict__ shift) {
  int b = blockIdx.x, c = threadIdx.x;
  float S = 0.f, Q = 0.f;
  #pragma unroll 8
  for (int rc = 0; rc < 64; ++rc) {
    S += psum[(b * 64 + rc) * 256 + c];
    Q += psq[(b * 64 + rc) * 256 + c];
  }
  float mean = S * (1.0f/4096.0f);
  float var  = Q * (1.0f/4096.0f) - mean * mean;
  float inv  = rsqrtf(var + 1e-5f);
  float mu_s  = s[b * 512 + c];
  float std_s = s[b * 512 + 256 + c];
  float sc = std_s * inv;
  scale[b * 256 + c] = sc;
  shift[b * 256 + c] = mu_s - sc * mean;
}

// ---------------- stats fin from proj-epilogue partials (32 per (b,c)) ------
__global__ __launch_bounds__(256) void k_stats_fin2(
    const float* __restrict__ pS, const float* __restrict__ pQ,
    const float* __restrict__ s,
    float* __restrict__ scale, float* __restrict__ shift) {
  int b = blockIdx.x, c = threadIdx.x;
  float S = 0.f, Q = 0.f;
  #pragma unroll 8
  for (int i = 0; i < 32; ++i) {
    S += pS[(b * 32 + i) * 256 + c];
    Q += pQ[(b * 32 + i) * 256 + c];
  }
  float mean = S * (1.0f/4096.0f);
  float var  = Q * (1.0f/4096.0f) - mean * mean;
  float inv  = rsqrtf(var + 1e-5f);
  float mu_s  = s[b * 512 + c];
  float std_s = s[b * 512 + 256 + c];
  float sc = std_s * inv;
  scale[b * 256 + c] = sc;
  shift[b * 256 + c] = mu_s - sc * mean;
}

// ---------------- fold adain2 into fc1 weights ------------------------------
// wout[b][n][k] = bf16(scale[b][k] * wt[n][k]);
// bout[b][n]    = bias[n] + sum_k shift[b][k] * wt[n][k].  grid (64,16).
__global__ __launch_bounds__(256) void k_scalew(
    const bf16* __restrict__ wt, const float* __restrict__ bias,
    const float* __restrict__ scale, const float* __restrict__ shift,
    bf16* __restrict__ wout, float* __restrict__ bout, int N) {
  int b = blockIdx.y;
  int n = blockIdx.x * 16 + (threadIdx.x >> 4);
  int kg = threadIdx.x & 15;
  const bf16* wrow = wt + (size_t)n * 256 + kg * 16;
  const float* sc = scale + b * 256 + kg * 16;
  const float* sh = shift + b * 256 + kg * 16;
  bf16* orow = wout + ((size_t)b * N + n) * 256 + kg * 16;
  float dot = 0.f;
  bf16x8v w0 = *(const bf16x8v*)wrow;
  bf16x8v w1 = *(const bf16x8v*)(wrow + 8);
  bf16x8v o0, o1;
  #pragma unroll
  for (int u = 0; u < 8; ++u) {
    float wv = (float)w0[u];
    o0[u] = (bf16)(sc[u] * wv);
    dot += sh[u] * wv;
  }
  #pragma unroll
  for (int u = 0; u < 8; ++u) {
    float wv = (float)w1[u];
    o1[u] = (bf16)(sc[8 + u] * wv);
    dot += sh[8 + u] * wv;
  }
  *(bf16x8v*)orow = o0;
  *(bf16x8v*)(orow + 8) = o1;
  #pragma unroll
  for (int m = 1; m <= 8; m <<= 1) dot += __shfl_xor(dot, m);
  if (kg == 0) bout[b * N + n] = bias[n] + dot;
}

// ---------------- adain apply: out_bf16 = shift + scale * in (f32 in) -------
__global__ __launch_bounds__(256) void k_adain(
    const float* __restrict__ in, const float* __restrict__ scale,
    const float* __restrict__ shift, bf16* __restrict__ out) {
  int idx = blockIdx.x * 256 + threadIdx.x;
  int c8 = idx & 31, row = idx >> 5;
  int b = row >> 12, c = c8 * 8;
  const float* scp = &scale[b * 256 + c];
  const float* shp = &shift[b * 256 + c];
  f32x4 sc0 = *(const f32x4*)scp, sc1 = *(const f32x4*)(scp + 4);
  f32x4 sh0 = *(const f32x4*)shp, sh1 = *(const f32x4*)(shp + 4);
  size_t ofs = (size_t)row * 256 + c;
  f32x4 v0 = *(const f32x4*)&in[ofs];
  f32x4 v1 = *(const f32x4*)&in[ofs + 4];
  bf16x8v o;
  o[0]=(bf16)(sh0[0]+sc0[0]*v0[0]); o[1]=(bf16)(sh0[1]+sc0[1]*v0[1]);
  o[2]=(bf16)(sh0[2]+sc0[2]*v0[2]); o[3]=(bf16)(sh0[3]+sc0[3]*v0[3]);
  o[4]=(bf16)(sh1[0]+sc1[0]*v1[0]); o[5]=(bf16)(sh1[1]+sc1[1]*v1[1]);
  o[6]=(bf16)(sh1[2]+sc1[2]*v1[2]); o[7]=(bf16)(sh1[3]+sc1[3]*v1[3]);
  *(bf16x8v*)&out[ofs] = o;
}

// ---------------- GEMM (8-wave 256x128): out = A@Bt^T + bias (+gelu) --------
// OUTMODE: 0 = bf16 row-major, 2 = bf16 qkv-layout [(b*3+m)*8+hh][tok][32].
// BPERB: Bt/bias are per-batch arrays selected by bb = (m0+row_off)>>12.
template<int GELU, int OUTMODE, int BPERB>
__global__ __launch_bounds__(512) void k_gemm(
    const bf16* __restrict__ A, const bf16* __restrict__ Bt,
    const float* __restrict__ bias,
    void* __restrict__ outv, int N, int K, int gx, int row_off) {
  __shared__ bf16 a_sw[256 * 64];   // 32 KB
  __shared__ bf16 b_sw[128 * 64];   // 16 KB
  int tid = threadIdx.x;
  int l = tid & 63, w = tid >> 6;
  int wr = w >> 1, wc = w & 1;             // 4x2 waves, 64x64 each
  int lm = l & 15, lg = l >> 4;

  int nwg = gridDim.x;
  int lin = blockIdx.x;
  int swz = (lin & 7) * (nwg >> 3) + (lin >> 3);
  int bx = swz % gx, by = swz / gx;
  int m0 = by * 256, n0 = bx * 128;

  int bb = 0;
  if constexpr (BPERB) bb = (m0 + row_off) >> 12;
  const bf16* BtX = Bt + (size_t)bb * ((size_t)N * K);
  const float* biasX = bias + bb * N;

  f32x4 acc[4][4];
  #pragma unroll
  for (int mi = 0; mi < 4; ++mi)
    #pragma unroll
    for (int ni = 0; ni < 4; ++ni)
      acc[mi][ni] = (f32x4){0.f, 0.f, 0.f, 0.f};

  for (int k0 = 0; k0 < K; k0 += 64) {
    #pragma unroll
    for (int i = 0; i < 4; ++i) {
      int slot = i * 512 + tid;
      int r = slot >> 3, cs = slot & 7;
      int c = cs ^ (r & 7);                // inverse swizzle on SOURCE
      const bf16* g = A + (size_t)(m0 + r) * K + k0 + c * 8;
      __builtin_amdgcn_global_load_lds(
          (const AS1 void*)g, (AS3 void*)(a_sw + (i * 512 + w * 64) * 8),
          16, 0, 0);
    }
    #pragma unroll
    for (int i = 0; i < 2; ++i) {
      int slot = i * 512 + tid;
      int r = slot >> 3, cs = slot & 7;
      int c = cs ^ (r & 7);
      const bf16* g = BtX + (size_t)(n0 + r) * K + k0 + c * 8;
      __builtin_amdgcn_global_load_lds(
          (const AS1 void*)g, (AS3 void*)(b_sw + (i * 512 + w * 64) * 8),
          16, 0, 0);
    }
    __syncthreads();
    #pragma unroll
    for (int kk = 0; kk < 2; ++kk) {
      bf16x8v af[4], bv[4];
      #pragma unroll
      for (int mi = 0; mi < 4; ++mi) {
        int row = wr * 64 + mi * 16 + lm;
        af[mi] = *(const bf16x8v*)&a_sw[row * 64 + (((kk * 4 + lg) ^ (row & 7)) * 8)];
      }
      #pragma unroll
      for (int ni = 0; ni < 4; ++ni) {
        int row = wc * 64 + ni * 16 + lm;
        bv[ni] = *(const bf16x8v*)&b_sw[row * 64 + (((kk * 4 + lg) ^ (row & 7)) * 8)];
      }
      #pragma unroll
      for (int mi = 0; mi < 4; ++mi)
        #pragma unroll
        for (int ni = 0; ni < 4; ++ni)
          acc[mi][ni] = mfma16(af[mi], bv[ni], acc[mi][ni]);
    }
    __syncthreads();
  }
  #pragma unroll
  for (int mi = 0; mi < 4; ++mi) {
    #pragma unroll
    for (int ni = 0; ni < 4; ++ni) {
      int row = m0 + wr * 64 + mi * 16 + lg * 4;
      int col = n0 + wc * 64 + ni * 16 + lm;
      float bv_ = biasX[col];
      #pragma unroll
      for (int j = 0; j < 4; ++j) {
        float o = acc[mi][ni][j] + bv_;
        if constexpr (GELU) {
          float z = 1.5957691216057308f * (o + 0.044715f * o * o * o);
          o = o / (1.0f + __expf(-z));
        }
        if constexpr (OUTMODE == 2) {
          int b  = (row + j) >> 12, tok = (row + j) & 4095;
          int m  = col >> 8, c2 = col & 255;
          int hh = c2 >> 5, ch = c2 & 31;
          size_t a_ = ((size_t)((b * 3 + m) * 8 + hh) << 17) + (tok << 5) + ch;
          ((bf16*)outv)[a_] = (bf16)o;
        } else
          ((bf16*)outv)[(size_t)(row + j) * N + col] = (bf16)o;
      }
    }
  }
}

// ---------------- GEMM (4-wave 128x128) — for small grids -------------------
// STATS: emit per-block column partial sum/sumsq of the bf16-rounded output.
template<int RESMODE, int GELU, int OUTF32, int STATS>
__global__ __launch_bounds__(256) void k_gemm4(
    const bf16* __restrict__ A, const bf16* __restrict__ Bt,
    const float* __restrict__ bias, const void* __restrict__ resv,
    void* __restrict__ outv, int N, int K, int gx,
    float* __restrict__ pS, float* __restrict__ pQ) {
  __shared__ bf16 a_sw[128 * 64];
  __shared__ bf16 b_sw[128 * 64];
  int tid = threadIdx.x;
  int l = tid & 63, w = tid >> 6;
  int wr = w >> 1, wc = w & 1;
  int lm = l & 15, lg = l >> 4;

  int nwg = gridDim.x;
  int lin = blockIdx.x;
  int swz = (lin & 7) * (nwg >> 3) + (lin >> 3);
  int bx = swz % gx, by = swz / gx;
  int m0 = by * 128, n0 = bx * 128;

  f32x4 acc[4][4];
  #pragma unroll
  for (int mi = 0; mi < 4; ++mi)
    #pragma unroll
    for (int ni = 0; ni < 4; ++ni)
      acc[mi][ni] = (f32x4){0.f, 0.f, 0.f, 0.f};

  for (int k0 = 0; k0 < K; k0 += 64) {
    #pragma unroll
    for (int i = 0; i < 4; ++i) {
      int slot = i * 256 + tid;
      int r = slot >> 3, cs = slot & 7;
      int c = cs ^ (r & 7);
      __builtin_amdgcn_global_load_lds(
          (const AS1 void*)(A + (size_t)(m0 + r) * K + k0 + c * 8),
          (AS3 void*)(a_sw + (i * 256 + w * 64) * 8), 16, 0, 0);
    }
    #pragma unroll
    for (int i = 0; i < 4; ++i) {
      int slot = i * 256 + tid;
      int r = slot >> 3, cs = slot & 7;
      int c = cs ^ (r & 7);
      __builtin_amdgcn_global_load_lds(
          (const AS1 void*)(Bt + (size_t)(n0 + r) * K + k0 + c * 8),
          (AS3 void*)(b_sw + (i * 256 + w * 64) * 8), 16, 0, 0);
    }
    __syncthreads();
    #pragma unroll
    for (int kk = 0; kk < 2; ++kk) {
      bf16x8v af[4], bv[4];
      #pragma unroll
      for (int mi = 0; mi < 4; ++mi) {
        int row = wr * 64 + mi * 16 + lm;
        af[mi] = *(const bf16x8v*)&a_sw[row * 64 + (((kk * 4 + lg) ^ (row & 7)) * 8)];
      }
      #pragma unroll
      for (int ni = 0; ni < 4; ++ni) {
        int row = wc * 64 + ni * 16 + lm;
        bv[ni] = *(const bf16x8v*)&b_sw[row * 64 + (((kk * 4 + lg) ^ (row & 7)) * 8)];
      }
      #pragma unroll
      for (int mi = 0; mi < 4; ++mi)
        #pragma unroll
        for (int ni = 0; ni < 4; ++ni)
          acc[mi][ni] = mfma16(af[mi], bv[ni], acc[mi][ni]);
    }
    __syncthreads();
  }

  float sl[4] = {0.f, 0.f, 0.f, 0.f};
  float sq[4] = {0.f, 0.f, 0.f, 0.f};
  #pragma unroll
  for (int mi = 0; mi < 4; ++mi) {
    #pragma unroll
    for (int ni = 0; ni < 4; ++ni) {
      int row = m0 + wr * 64 + mi * 16 + lg * 4;
      int col = n0 + wc * 64 + ni * 16 + lm;
      float bv_ = bias[col];
      #pragma unroll
      for (int j = 0; j < 4; ++j) {
        float o = acc[mi][ni][j] + bv_;
        if constexpr (RESMODE == 1)
          o += ((const float*)resv)[(size_t)(row + j) * N + col];
        if constexpr (RESMODE == 2)
          o += (float)((const bf16*)resv)[(size_t)(row + j) * N + col];
        if constexpr (GELU) {
          float z = 1.5957691216057308f * (o + 0.044715f * o * o * o);
          o = o / (1.0f + __expf(-z));
        }
        if constexpr (OUTF32)
          ((float*)outv)[(size_t)(row + j) * N + col] = o;
        else
          ((bf16*)outv)[(size_t)(row + j) * N + col] = (bf16)o;
        if constexpr (STATS) {
          float ob = (float)(bf16)o;       // match bf16-x1 stats numerics
          sl[ni] += ob;
          sq[ni] += ob * ob;
        }
      }
    }
  }

  if constexpr (STATS) {
    float* red = (float*)a_sw;             // 2048 f32 = 8 KB
    #pragma unroll
    for (int ni = 0; ni < 4; ++ni) {
      int g = (wc * 4 + ni) * 16 + lm;     // == col_local
      red[g * 8 + wr * 4 + lg] = sl[ni];
      red[1024 + g * 8 + wr * 4 + lg] = sq[ni];
    }
    __syncthreads();
    if (tid < 128) {
      float S = 0.f, Q = 0.f;
      #pragma unroll
      for (int u = 0; u < 8; ++u) {
        S += red[tid * 8 + u];
        Q += red[1024 + tid * 8 + u];
      }
      pS[by * 256 + bx * 128 + tid] = S;
      pQ[by * 256 + bx * 128 + tid] = Q;
    }
  }
}

// ---------------- windowed attention (both branches) ------------------------
__global__ __launch_bounds__(256) void k_attn(
    const bf16* __restrict__ qkv,
    const float* __restrict__ rpb1, const float* __restrict__ rpb2,
    bf16* __restrict__ aout) {
  __shared__ bf16 vt[128 * 72];   // V^T: [hh2*32+ch][token-swizzled(+pad)]
  __shared__ float rl[960];       // rpb: [h][dy][dx] stride 240/16/1

  int tid = threadIdx.x;
  int bx = blockIdx.x;
  int br = bx & 1, widx = (bx >> 1) & 63, b = bx >> 7;
  int wy = widx >> 3, wx = widx & 7;

  const float* rpb = br ? rpb2 : rpb1;
  #pragma unroll
  for (int t = tid; t < 960; t += 256) {
    int h0 = t / 240, r0 = t - h0 * 240, dy = r0 >> 4, dx = r0 & 15;
    rl[t] = (dx < 15) ? rpb[(dy * 15 + dx) * 4 + h0] : 0.f;
  }

  auto grow = [&](int tok) -> int {
    int y = wy * 8 + (tok >> 3), xc = wx * 8 + (tok & 7);
    if (br) { y = (y + 4) & 63; xc = (xc + 4) & 63; }
    return y * 64 + xc;
  };

  auto plane = [&](int m, int hh2) -> size_t {
    return (size_t)((b * 3 + m) * 8 + br * 4 + hh2) << 17;
  };

  #pragma unroll
  for (int it = 0; it < 4; ++it) {
    int task = it * 256 + tid;
    int tok = task >> 4, c = task & 15;
    int hh2 = c >> 2, ch8 = c & 3;
    bf16x8v v = *(const bf16x8v*)&qkv[plane(2, hh2) + (grow(tok) << 5) + ch8 * 8];
    int tsw = tok ^ ((c & 7) << 3);
    #pragma unroll
    for (int u = 0; u < 8; ++u) vt[(c * 8 + u) * 72 + tsw] = v[u];
  }

  int l = tid & 63, h = tid >> 6;
  int lm = l & 15, lg = l >> 4;

  bf16x8v kb[4], qa[4];
  size_t pq = plane(0, h), pk = plane(1, h);
  #pragma unroll
  for (int i = 0; i < 4; ++i) {
    int t = grow(i * 16 + lm);
    qa[i] = *(const bf16x8v*)&qkv[pq + (t << 5) + lg * 8];
    kb[i] = *(const bf16x8v*)&qkv[pk + (t << 5) + lg * 8];
  }
  __syncthreads();

  bf16x4v vb[2][4];
  #pragma unroll
  for (int ni = 0; ni < 2; ++ni)
    #pragma unroll
    for (int ki = 0; ki < 4; ++ki) {
      int row = h * 32 + ni * 16 + lm;
      int col = (ki * 16 + lg * 4) ^ (((row >> 3) & 7) << 3);
      vb[ni][ki] = *(const bf16x4v*)&vt[row * 72 + col];
    }

  bool need_mask = br && (wy == 7 || wx == 7);

  int ekA[16], idkA[16];
  #pragma unroll
  for (int ki = 0; ki < 4; ++ki)
    #pragma unroll
    for (int j = 0; j < 4; ++j) {
      int ik = ki * 16 + lg * 4 + j;
      ekA[ki * 4 + j] = ik + (ik >> 3) * 8;
      int yk = wy * 8 + (ik >> 3), xk = wx * 8 + (ik & 7);
      idkA[ki * 4 + j] = (yk < 56 ? 0 : (yk < 60 ? 1 : 2)) * 3
                       + (xk < 56 ? 0 : (xk < 60 ? 1 : 2));
    }

  #pragma unroll
  for (int qi = 0; qi < 4; ++qi) {
    f32x4 s[4];
    #pragma unroll
    for (int ki = 0; ki < 4; ++ki)
      s[ki] = mfma16(kb[ki], qa[qi], (f32x4){0.f,0.f,0.f,0.f});

    int iq = qi * 16 + lm;
    int eq = iq + (iq >> 3) * 8;
    int yq = wy * 8 + (iq >> 3), xq = wx * 8 + (iq & 7);
    int idq = (yq < 56 ? 0 : (yq < 60 ? 1 : 2)) * 3
            + (xq < 56 ? 0 : (xq < 60 ? 1 : 2));
    const float* fb = &rl[h * 240 + 119 + eq];

    #pragma unroll
    for (int ki = 0; ki < 4; ++ki)
      #pragma unroll
      for (int j = 0; j < 4; ++j) {
        float val = s[ki][j] * 0.17677669529663687f + fb[-ekA[ki * 4 + j]];
        if (need_mask && idq != idkA[ki * 4 + j]) val -= 100.0f;
        s[ki][j] = val;
      }

    float mx = s[0][0];
    #pragma unroll
    for (int ki = 0; ki < 4; ++ki)
      #pragma unroll
      for (int j = 0; j < 4; ++j) mx = fmaxf(mx, s[ki][j]);
    mx = fmaxf(mx, __shfl_xor(mx, 16));
    mx = fmaxf(mx, __shfl_xor(mx, 32));
    float sum = 0.f;
    #pragma unroll
    for (int ki = 0; ki < 4; ++ki)
      #pragma unroll
      for (int j = 0; j < 4; ++j) {
        float e = __expf(s[ki][j] - mx);
        s[ki][j] = e;
        sum += e;
      }
    sum += __shfl_xor(sum, 16);
    sum += __shfl_xor(sum, 32);
    float rs = 1.0f / sum;

    bf16x4v pa[4];
    #pragma unroll
    for (int ki = 0; ki < 4; ++ki)
      #pragma unroll
      for (int j = 0; j < 4; ++j)
        pa[ki][j] = (bf16)(s[ki][j] * rs);

    f32x4 o[2] = {(f32x4){0.f,0.f,0.f,0.f}, (f32x4){0.f,0.f,0.f,0.f}};
    #pragma unroll
    for (int ki = 0; ki < 4; ++ki) {
      o[0] = mfma16x16(pa[ki], vb[0][ki], o[0]);
      o[1] = mfma16x16(pa[ki], vb[1][ki], o[1]);
    }

    #pragma unroll
    for (int ni = 0; ni < 2; ++ni)
      #pragma unroll
      for (int j = 0; j < 4; ++j) {
        int tok = qi * 16 + lg * 4 + j;
        int col = br * 128 + h * 32 + ni * 16 + lm;
        aout[((size_t)b * 4096 + grow(tok)) * 256 + col] = (bf16)o[ni][j];
      }
  }
}

// ---------------- host ------------------------------------------------------
extern "C" void kernel_launch(void* const* d_in, const int* in_sizes, int n_in,
                              void* d_out, int out_size, void* d_ws, size_t ws_size,
                              hipStream_t stream) {
  (void)in_sizes; (void)n_in; (void)out_size; (void)ws_size;
  const float* x      = (const float*)d_in[0];
  const float* style  = (const float*)d_in[1];
  const float* w_qkv  = (const float*)d_in[2];
  const float* b_qkv  = (const float*)d_in[3];
  const float* w_proj = (const float*)d_in[4];
  const float* b_proj = (const float*)d_in[5];
  const float* w_ada1 = (const float*)d_in[6];
  const float* b_ada1 = (const float*)d_in[7];
  const float* w_ada2 = (const float*)d_in[8];
  const float* b_ada2 = (const float*)d_in[9];
  const float* rpb1   = (const float*)d_in[10];
  const float* rpb2   = (const float*)d_in[11];
  const float* w_fc1  = (const float*)d_in[12];
  const float* b_fc1  = (const float*)d_in[13];
  const float* w_fc2  = (const float*)d_in[14];
  const float* b_fc2  = (const float*)d_in[15];

  char* ws = (char*)d_ws;
  float* s1     = (float*)(ws + 0);
  float* s2     = (float*)(ws + 32768);
  float* scale1 = (float*)(ws + 65536);
  float* shift1 = (float*)(ws + 81920);
  float* scale2 = (float*)(ws + 98304);
  float* shift2 = (float*)(ws + 114688);
  bf16* wtqkv   = (bf16*)(ws + 131072);            // 768x256 bf16
  bf16* wtproj  = (bf16*)(ws + 524288);            // 256x256
  bf16* wtfc1   = (bf16*)(ws + 655360);            // 1024x256
  bf16* wtfc2   = (bf16*)(ws + 1179648);           // 256x1024
  float* psum   = (float*)(ws + 1703936);          // 16*64*256 f32 = 1MB
  float* psq    = (float*)(ws + 2752512);          // 1MB
  float* pS     = (float*)(ws + 1703936);          // 512KB (reuses psum)
  float* bfc1s  = (float*)(ws + 2752512);          // 16x1024 f32 (reuses psq)
  const size_t BIG = 4194304;
  bf16* xn    = (bf16*)(ws + BIG);                 // 65536x256 bf16 (33.5MB)
  bf16* wfc1s = (bf16*)(ws + BIG);                 // 16x1024x256 bf16 (8MB,
                                                   //  reuses dead xn slot)
  bf16* qkv  = (bf16*)(ws + BIG + 33554432);       // 384 planes x 4096 x 32
  bf16* attn = (bf16*)(ws + BIG + 134217728);      // 65536x256 bf16 (33.5MB)
  bf16* x1   = (bf16*)(ws + BIG + 33554432);       // overlays qkv head
  bf16* g    = (bf16*)(ws + BIG + 67108864);       // 32768x1024 chunk, qkv tail
  float* pQ  = (float*)(ws + BIG + 167772160);     // 512x256 f32 (after attn)

  // fused prologue: 4 weight transposes + style + x-stats (one dispatch)
  k_prep<<<2816, 256, 0, stream>>>(
      w_qkv, w_proj, w_fc1, w_fc2, wtqkv, wtproj, wtfc1, wtfc2,
      style, w_ada1, b_ada1, w_ada2, b_ada2, s1, s2, x, psum, psq);

  k_stats_fin<<<16, 256, 0, stream>>>(psum, psq, s1, scale1, shift1);
  k_adain<<<8192, 256, 0, stream>>>(x, scale1, shift1, xn);

  // qkv = xn @ w_qkv + b_qkv  (attention-native output layout)
  k_gemm<0,2,0><<<1536, 512, 0, stream>>>(
      xn, wtqkv, b_qkv, qkv, 768, 256, 6, 0);

  // windowed attention (both branches)
  k_attn<<<2048, 256, 0, stream>>>(qkv, rpb1, rpb2, attn);

  // x1 = x + attn @ w_proj + b_proj  (+ fused x1 column stats partials)
  k_gemm4<1,0,0,1><<<1024, 256, 0, stream>>>(
      attn, wtproj, b_proj, x, x1, 256, 256, 2, pS, pQ);

  // adain2 params from fused partials; fold adain2 into fc1 weights
  k_stats_fin2<<<16, 256, 0, stream>>>(pS, pQ, s2, scale2, shift2);
  k_scalew<<<dim3(64, 16), 256, 0, stream>>>(
      wtfc1, b_fc1, scale2, shift2, wfc1s, bfc1s, 1024);

  // MLP in 2 row-chunks of 32768 (g reuses dead qkv tail region)
  for (int ch = 0; ch < 2; ++ch) {
    size_t ro = (size_t)ch * 32768;
    // g = gelu(x1 @ (scale*w_fc1)_b + folded bias)   (per-batch weights)
    k_gemm<1,0,1><<<1024, 512, 0, stream>>>(
        x1 + ro * 256, wfc1s, bfc1s, g, 1024, 256, 8, (int)ro);
    // out = x1 + g @ w_fc2 + b_fc2    (128x128: 256 x 2 = 512)
    k_gemm4<2,0,1,0><<<512, 256, 0, stream>>>(
        g, wtfc2, b_fc2, x1 + ro * 256,
        (float*)d_out + ro * 256, 256, 1024, 2, nullptr, nullptr);
  }
}